// Round 2
// baseline (4879.274 us; speedup 1.0000x reference)
//
#include <hip/hip_runtime.h>

#define NRUNS 4
#define NAU 50000
#define NPP 100000
#define NEDGE 500000
#define HD 128
#define INV_KEEP 1.25f
#define BN_EPS 1e-5f

// gemm modes
#define M_PROJ 0
#define M_GIN1 1
#define M_GIN2 2

typedef unsigned short bf16r;   // raw bf16 storage

__device__ inline float bf2f(bf16r u) {
    return __uint_as_float(((unsigned)u) << 16);
}
__device__ inline bf16r f2bf(float f) {
    unsigned x = __float_as_uint(f);
    return (bf16r)((x + 0x7fffu + ((x >> 16) & 1u)) >> 16);  // RNE
}

template<typename ST> __device__ inline float4 load4(const ST* p);
template<> __device__ inline float4 load4<float>(const float* p) {
    return *(const float4*)p;
}
template<> __device__ inline float4 load4<bf16r>(const bf16r* p) {
    ushort4 u = *(const ushort4*)p;
    return make_float4(bf2f(u.x), bf2f(u.y), bf2f(u.z), bf2f(u.w));
}
template<typename ST> __device__ inline void store4(ST* p, float4 v);
template<> __device__ inline void store4<float>(float* p, float4 v) {
    *(float4*)p = v;
}
template<> __device__ inline void store4<bf16r>(bf16r* p, float4 v) {
    ushort4 u;
    u.x = f2bf(v.x); u.y = f2bf(v.y); u.z = f2bf(v.z); u.w = f2bf(v.w);
    *(ushort4*)p = u;
}
template<typename ST> __device__ inline float load1(const ST* p);
template<> __device__ inline float load1<float>(const float* p) { return *p; }
template<> __device__ inline float load1<bf16r>(const bf16r* p) { return bf2f(*p); }

// grid-stride float4 zero fill
__global__ __launch_bounds__(256)
void zero_k(float* p, long n4) {
    long i = (long)blockIdx.x * 256 + threadIdx.x;
    long stride = (long)gridDim.x * 256;
    float4 z = make_float4(0.f, 0.f, 0.f, 0.f);
    for (; i < n4; i += stride) ((float4*)p)[i] = z;
}

// 64-row x 128-col x K=128 GEMM, fused per-mode prologue/epilogue.
//  PROJ : out gets R copies of (x@W+b), each scaled by mask[r][node]*1.25
//  GIN1 : z = (1+eps)*h + (row<Nn ? agg[row] : 0); out = z@W+b (IN PLACE ok);
//         accumulates per-column sum/sumsq into gsum/gsumsq
//  GIN2 : t = relu(h*scale+shift); out = relu(t@W+b), IN PLACE
// In-place safety: whole 64-row tile staged to LDS + __syncthreads before any
// global write; row i output depends only on row i input.
template<int MODE, typename ST>
__global__ __launch_bounds__(256)
void gemm128(const ST* in, const float* __restrict__ Wm,
             const float* __restrict__ bias, ST* out,
             int M, int Nn,
             const float* __restrict__ agg, const float* __restrict__ epsp,
             float* gsum, float* gsumsq,
             const float* __restrict__ scale, const float* __restrict__ shift,
             const float* __restrict__ mask)
{
    __shared__ float zt[64][HD];
    const int tid = threadIdx.x;
    const int m0 = blockIdx.x * 64;

    float epsv = 1.0f;
    if (MODE == M_GIN1) epsv = 1.0f + epsp[0];

    // ---- stage input tile (with per-mode transform) ----
    #pragma unroll
    for (int p = 0; p < 8; ++p) {
        int flat = p * 1024 + tid * 4;
        int row = flat >> 7, col = flat & 127;
        int gr = m0 + row;
        float4 v = make_float4(0.f, 0.f, 0.f, 0.f);
        if (gr < M) {
            v = load4<ST>(in + (size_t)gr * HD + col);
            if (MODE == M_GIN1) {
                v.x *= epsv; v.y *= epsv; v.z *= epsv; v.w *= epsv;
                if (gr < Nn) {
                    float4 a = *(const float4*)(agg + (size_t)gr * HD + col);
                    v.x += a.x; v.y += a.y; v.z += a.z; v.w += a.w;
                }
            } else if (MODE == M_GIN2) {
                float4 sc = *(const float4*)(scale + col);
                float4 sh = *(const float4*)(shift + col);
                v.x = fmaxf(v.x * sc.x + sh.x, 0.f);
                v.y = fmaxf(v.y * sc.y + sh.y, 0.f);
                v.z = fmaxf(v.z * sc.z + sh.z, 0.f);
                v.w = fmaxf(v.w * sc.w + sh.w, 0.f);
            }
        }
        *(float4*)&zt[row][col] = v;
    }
    __syncthreads();

    // ---- compute: each thread 8 rows x 4 cols ----
    const int cg = tid & 31, rg = tid >> 5;
    const int c0 = cg * 4, r0 = rg * 8;
    float acc[8][4];
    #pragma unroll
    for (int i = 0; i < 8; ++i)
        #pragma unroll
        for (int j = 0; j < 4; ++j) acc[i][j] = 0.f;

    const float4* W4 = (const float4*)Wm;
    #pragma unroll 4
    for (int k = 0; k < HD; k += 4) {
        float4 w0 = W4[(k + 0) * 32 + cg];
        float4 w1 = W4[(k + 1) * 32 + cg];
        float4 w2 = W4[(k + 2) * 32 + cg];
        float4 w3 = W4[(k + 3) * 32 + cg];
        #pragma unroll
        for (int i = 0; i < 8; ++i) {
            float4 z = *(const float4*)&zt[r0 + i][k];
            acc[i][0] += z.x * w0.x + z.y * w1.x + z.z * w2.x + z.w * w3.x;
            acc[i][1] += z.x * w0.y + z.y * w1.y + z.z * w2.y + z.w * w3.y;
            acc[i][2] += z.x * w0.z + z.y * w1.z + z.z * w2.z + z.w * w3.z;
            acc[i][3] += z.x * w0.w + z.y * w1.w + z.z * w2.w + z.w * w3.w;
        }
    }

    float4 b = *(const float4*)(bias + c0);
    float vv[8][4];
    #pragma unroll
    for (int i = 0; i < 8; ++i) {
        vv[i][0] = acc[i][0] + b.x;
        vv[i][1] = acc[i][1] + b.y;
        vv[i][2] = acc[i][2] + b.z;
        vv[i][3] = acc[i][3] + b.w;
    }

    // ---- epilogue ----
    if (MODE == M_PROJ) {
        #pragma unroll
        for (int i = 0; i < 8; ++i) {
            int gi = m0 + r0 + i;
            if (gi < M) {
                #pragma unroll
                for (int r = 0; r < NRUNS; ++r) {
                    float w = mask[(size_t)r * Nn + gi] * INV_KEEP;
                    store4<ST>(out + ((size_t)r * Nn + gi) * HD + c0,
                               make_float4(vv[i][0] * w, vv[i][1] * w,
                                           vv[i][2] * w, vv[i][3] * w));
                }
            }
        }
    } else if (MODE == M_GIN1) {
        #pragma unroll
        for (int i = 0; i < 8; ++i) {
            int gi = m0 + r0 + i;
            if (gi < M)
                store4<ST>(out + (size_t)gi * HD + c0,
                           make_float4(vv[i][0], vv[i][1], vv[i][2], vv[i][3]));
        }
        // per-column stats (M is a multiple of 64 in GIN passes)
        float s[4] = {0.f, 0.f, 0.f, 0.f}, q[4] = {0.f, 0.f, 0.f, 0.f};
        #pragma unroll
        for (int i = 0; i < 8; ++i)
            #pragma unroll
            for (int j = 0; j < 4; ++j) {
                s[j] += vv[i][j];
                q[j] += vv[i][j] * vv[i][j];
            }
        __syncthreads();               // done reading zt; reuse as reduction buf
        float (*red)[HD] = (float(*)[HD])zt;
        #pragma unroll
        for (int j = 0; j < 4; ++j) red[rg][c0 + j] = s[j];
        __syncthreads();
        if (tid < HD) {
            float t = 0.f;
            #pragma unroll
            for (int g = 0; g < 8; ++g) t += red[g][tid];
            unsafeAtomicAdd(gsum + tid, t);
        }
        __syncthreads();
        #pragma unroll
        for (int j = 0; j < 4; ++j) red[rg][c0 + j] = q[j];
        __syncthreads();
        if (tid < HD) {
            float t = 0.f;
            #pragma unroll
            for (int g = 0; g < 8; ++g) t += red[g][tid];
            unsafeAtomicAdd(gsumsq + tid, t);
        }
    } else {  // M_GIN2
        #pragma unroll
        for (int i = 0; i < 8; ++i) {
            int gi = m0 + r0 + i;
            if (gi < M)
                store4<ST>(out + (size_t)gi * HD + c0,
                           make_float4(fmaxf(vv[i][0], 0.f), fmaxf(vv[i][1], 0.f),
                                       fmaxf(vv[i][2], 0.f), fmaxf(vv[i][3], 0.f)));
        }
    }
}

// scatter-add: 32 lanes per edge, float4 gather from src row, 4 f32 atomics
template<typename ST>
__global__ __launch_bounds__(256)
void scatter_k(const ST* __restrict__ src, float* dst,
               const int* __restrict__ ei, int E)
{
    int g = blockIdx.x * 256 + threadIdx.x;
    int e = g >> 5, lane = g & 31;
    if (e >= E) return;
    int s = ei[e], d = ei[E + e];
    float4 v = load4<ST>(src + (size_t)s * HD + lane * 4);
    float* dp = dst + (size_t)d * HD + lane * 4;
    unsafeAtomicAdd(dp + 0, v.x);
    unsafeAtomicAdd(dp + 1, v.y);
    unsafeAtomicAdd(dp + 2, v.z);
    unsafeAtomicAdd(dp + 3, v.w);
}

// BN stats -> scale/shift; re-zeros accumulators (deterministic replay)
__global__ void finalize_k(float* gsum, float* gsumsq,
                           const float* __restrict__ gamma,
                           const float* __restrict__ beta,
                           float* scale, float* shift, float invN)
{
    int c = threadIdx.x;
    float mu = gsum[c] * invN;
    float var = gsumsq[c] * invN - mu * mu;
    float sc = gamma[c] * rsqrtf(var + BN_EPS);
    scale[c] = sc;
    shift[c] = beta[c] - mu * sc;
    gsum[c] = 0.f;
    gsumsq[c] = 0.f;
}

// mean over runs + [128]x[128,4] matmul; one wave per author node
template<typename ST>
__global__ __launch_bounds__(256)
void final_k(const ST* __restrict__ ha, const float* __restrict__ fw,
             const float* __restrict__ fb, float* __restrict__ out)
{
    int g = blockIdx.x * 256 + threadIdx.x;
    int node = g >> 6, lane = g & 63;
    if (node >= NAU) return;
    float m0 = 0.f, m1 = 0.f;
    #pragma unroll
    for (int r = 0; r < NRUNS; ++r) {
        size_t base = ((size_t)r * NAU + node) * HD;
        m0 += load1<ST>(ha + base + lane);
        m1 += load1<ST>(ha + base + 64 + lane);
    }
    m0 *= 0.25f;
    m1 *= 0.25f;
    float p[4];
    #pragma unroll
    for (int c = 0; c < 4; ++c)
        p[c] = m0 * fw[lane * 4 + c] + m1 * fw[(lane + 64) * 4 + c];
    #pragma unroll
    for (int off = 32; off >= 1; off >>= 1)
        #pragma unroll
        for (int c = 0; c < 4; ++c) p[c] += __shfl_down(p[c], off);
    if (lane == 0) {
        #pragma unroll
        for (int c = 0; c < 4; ++c) out[(size_t)node * 4 + c] = p[c] + fb[c];
    }
}

template<typename ST>
static void run_all(void* const* d_in, void* d_out, void* d_ws, hipStream_t stream)
{
    const float* x_author = (const float*)d_in[0];
    const float* x_paper  = (const float*)d_in[1];
    const int*   ei_ap    = (const int*)d_in[2];
    const int*   ei_pa    = (const int*)d_in[3];
    const float* drop_a   = (const float*)d_in[4];
    const float* drop_p   = (const float*)d_in[5];
    const float* lin_a_w  = (const float*)d_in[6];
    const float* lin_a_b  = (const float*)d_in[7];
    const float* lin_p_w  = (const float*)d_in[8];
    const float* lin_p_b  = (const float*)d_in[9];
    const float* W1       = (const float*)d_in[10];
    const float* B1       = (const float*)d_in[11];
    const float* G        = (const float*)d_in[12];
    const float* BT       = (const float*)d_in[13];
    const float* W2       = (const float*)d_in[14];
    const float* B2       = (const float*)d_in[15];
    const float* EPS      = (const float*)d_in[16];
    const float* fw       = (const float*)d_in[17];
    const float* fb       = (const float*)d_in[18];

    // ws layout: [stats(4*HD f32)][agg_a][agg_p][h_a(ST)][h_p(ST)]
    float* gsum   = (float*)d_ws;
    float* gsumsq = gsum + HD;
    float* scalev = gsumsq + HD;
    float* shiftv = scalev + HD;
    float* agg_a  = shiftv + HD;
    float* agg_p  = agg_a + (size_t)NAU * HD;
    ST* h_a = (ST*)(agg_p + (size_t)NPP * HD);
    ST* h_p = h_a + (size_t)NRUNS * NAU * HD;

    zero_k<<<1, 256, 0, stream>>>(gsum, (4 * HD) / 4);

    // input projections + dropout expansion
    gemm128<M_PROJ, ST><<<(NAU + 63) / 64, 256, 0, stream>>>(
        (const ST*)x_author, lin_a_w, lin_a_b, h_a, NAU, NAU,
        nullptr, nullptr, nullptr, nullptr, nullptr, nullptr, drop_a);
    gemm128<M_PROJ, ST><<<(NPP + 63) / 64, 256, 0, stream>>>(
        (const ST*)x_paper, lin_p_w, lin_p_b, h_p, NPP, NPP,
        nullptr, nullptr, nullptr, nullptr, nullptr, nullptr, drop_p);

    for (int l = 0; l < 2; ++l) {
        int t0 = l * 2 + 0, t1 = l * 2 + 1;
        // zero both aggs (contiguous), then both scatters (from OLD h)
        zero_k<<<2048, 256, 0, stream>>>(agg_a, ((size_t)(NAU + NPP) * HD) / 4);
        scatter_k<ST><<<(NEDGE * 32) / 256, 256, 0, stream>>>(h_a, agg_p, ei_ap, NEDGE);
        scatter_k<ST><<<(NEDGE * 32) / 256, 256, 0, stream>>>(h_p, agg_a, ei_pa, NEDGE);

        // paper GIN (params [l,0]) — in place on h_p
        gemm128<M_GIN1, ST><<<NRUNS * NPP / 64, 256, 0, stream>>>(
            h_p, W1 + (size_t)t0 * HD * HD, B1 + (size_t)t0 * HD, h_p,
            NRUNS * NPP, NPP, agg_p, EPS + t0, gsum, gsumsq,
            nullptr, nullptr, nullptr);
        finalize_k<<<1, HD, 0, stream>>>(gsum, gsumsq, G + (size_t)t0 * HD,
                                         BT + (size_t)t0 * HD, scalev, shiftv,
                                         1.0f / (NRUNS * NPP));
        gemm128<M_GIN2, ST><<<NRUNS * NPP / 64, 256, 0, stream>>>(
            h_p, W2 + (size_t)t0 * HD * HD, B2 + (size_t)t0 * HD, h_p,
            NRUNS * NPP, NPP, nullptr, nullptr, nullptr, nullptr,
            scalev, shiftv, nullptr);

        // author GIN (params [l,1]) — in place on h_a (reads OLD h_a + agg_a)
        gemm128<M_GIN1, ST><<<NRUNS * NAU / 64, 256, 0, stream>>>(
            h_a, W1 + (size_t)t1 * HD * HD, B1 + (size_t)t1 * HD, h_a,
            NRUNS * NAU, NAU, agg_a, EPS + t1, gsum, gsumsq,
            nullptr, nullptr, nullptr);
        finalize_k<<<1, HD, 0, stream>>>(gsum, gsumsq, G + (size_t)t1 * HD,
                                         BT + (size_t)t1 * HD, scalev, shiftv,
                                         1.0f / (NRUNS * NAU));
        gemm128<M_GIN2, ST><<<NRUNS * NAU / 64, 256, 0, stream>>>(
            h_a, W2 + (size_t)t1 * HD * HD, B2 + (size_t)t1 * HD, h_a,
            NRUNS * NAU, NAU, nullptr, nullptr, nullptr, nullptr,
            scalev, shiftv, nullptr);
    }

    final_k<ST><<<(NAU * 64) / 256, 256, 0, stream>>>(h_a, fw, fb, (float*)d_out);
}

// PROJ-mode input is always f32 (x_author/x_paper); wrap so gemm templating
// stays uniform: specialize the PROJ input load when ST==bf16r by a separate
// first-stage kernel is avoided — instead we give PROJ its own f32-in variant.
__global__ __launch_bounds__(256)
void proj_f32in_bf16out(const float* __restrict__ in, const float* __restrict__ Wm,
                        const float* __restrict__ bias, bf16r* out,
                        int M, int Nn, const float* __restrict__ mask)
{
    __shared__ float zt[64][HD];
    const int tid = threadIdx.x;
    const int m0 = blockIdx.x * 64;
    #pragma unroll
    for (int p = 0; p < 8; ++p) {
        int flat = p * 1024 + tid * 4;
        int row = flat >> 7, col = flat & 127;
        int gr = m0 + row;
        float4 v = make_float4(0.f, 0.f, 0.f, 0.f);
        if (gr < M) v = *(const float4*)(in + (size_t)gr * HD + col);
        *(float4*)&zt[row][col] = v;
    }
    __syncthreads();
    const int cg = tid & 31, rg = tid >> 5;
    const int c0 = cg * 4, r0 = rg * 8;
    float acc[8][4];
    #pragma unroll
    for (int i = 0; i < 8; ++i)
        #pragma unroll
        for (int j = 0; j < 4; ++j) acc[i][j] = 0.f;
    const float4* W4 = (const float4*)Wm;
    #pragma unroll 4
    for (int k = 0; k < HD; k += 4) {
        float4 w0 = W4[(k + 0) * 32 + cg];
        float4 w1 = W4[(k + 1) * 32 + cg];
        float4 w2 = W4[(k + 2) * 32 + cg];
        float4 w3 = W4[(k + 3) * 32 + cg];
        #pragma unroll
        for (int i = 0; i < 8; ++i) {
            float4 z = *(const float4*)&zt[r0 + i][k];
            acc[i][0] += z.x * w0.x + z.y * w1.x + z.z * w2.x + z.w * w3.x;
            acc[i][1] += z.x * w0.y + z.y * w1.y + z.z * w2.y + z.w * w3.y;
            acc[i][2] += z.x * w0.z + z.y * w1.z + z.z * w2.z + z.w * w3.z;
            acc[i][3] += z.x * w0.w + z.y * w1.w + z.z * w2.w + z.w * w3.w;
        }
    }
    float4 b = *(const float4*)(bias + c0);
    #pragma unroll
    for (int i = 0; i < 8; ++i) {
        int gi = m0 + r0 + i;
        if (gi < M) {
            #pragma unroll
            for (int r = 0; r < NRUNS; ++r) {
                float w = mask[(size_t)r * Nn + gi] * INV_KEEP;
                store4<bf16r>(out + ((size_t)r * Nn + gi) * HD + c0,
                              make_float4((acc[i][0] + b.x) * w, (acc[i][1] + b.y) * w,
                                          (acc[i][2] + b.z) * w, (acc[i][3] + b.w) * w));
            }
        }
    }
}

static void run_bf16(void* const* d_in, void* d_out, void* d_ws, hipStream_t stream)
{
    // identical to run_all<bf16r> but with f32-input PROJ kernels
    const float* x_author = (const float*)d_in[0];
    const float* x_paper  = (const float*)d_in[1];
    const int*   ei_ap    = (const int*)d_in[2];
    const int*   ei_pa    = (const int*)d_in[3];
    const float* drop_a   = (const float*)d_in[4];
    const float* drop_p   = (const float*)d_in[5];
    const float* lin_a_w  = (const float*)d_in[6];
    const float* lin_a_b  = (const float*)d_in[7];
    const float* lin_p_w  = (const float*)d_in[8];
    const float* lin_p_b  = (const float*)d_in[9];
    const float* W1       = (const float*)d_in[10];
    const float* B1       = (const float*)d_in[11];
    const float* G        = (const float*)d_in[12];
    const float* BT       = (const float*)d_in[13];
    const float* W2       = (const float*)d_in[14];
    const float* B2       = (const float*)d_in[15];
    const float* EPS      = (const float*)d_in[16];
    const float* fw       = (const float*)d_in[17];
    const float* fb       = (const float*)d_in[18];

    float* gsum   = (float*)d_ws;
    float* gsumsq = gsum + HD;
    float* scalev = gsumsq + HD;
    float* shiftv = scalev + HD;
    float* agg_a  = shiftv + HD;
    float* agg_p  = agg_a + (size_t)NAU * HD;
    bf16r* h_a = (bf16r*)(agg_p + (size_t)NPP * HD);
    bf16r* h_p = h_a + (size_t)NRUNS * NAU * HD;

    zero_k<<<1, 256, 0, stream>>>(gsum, (4 * HD) / 4);

    proj_f32in_bf16out<<<(NAU + 63) / 64, 256, 0, stream>>>(
        x_author, lin_a_w, lin_a_b, h_a, NAU, NAU, drop_a);
    proj_f32in_bf16out<<<(NPP + 63) / 64, 256, 0, stream>>>(
        x_paper, lin_p_w, lin_p_b, h_p, NPP, NPP, drop_p);

    for (int l = 0; l < 2; ++l) {
        int t0 = l * 2 + 0, t1 = l * 2 + 1;
        zero_k<<<2048, 256, 0, stream>>>(agg_a, ((size_t)(NAU + NPP) * HD) / 4);
        scatter_k<bf16r><<<(NEDGE * 32) / 256, 256, 0, stream>>>(h_a, agg_p, ei_ap, NEDGE);
        scatter_k<bf16r><<<(NEDGE * 32) / 256, 256, 0, stream>>>(h_p, agg_a, ei_pa, NEDGE);

        gemm128<M_GIN1, bf16r><<<NRUNS * NPP / 64, 256, 0, stream>>>(
            h_p, W1 + (size_t)t0 * HD * HD, B1 + (size_t)t0 * HD, h_p,
            NRUNS * NPP, NPP, agg_p, EPS + t0, gsum, gsumsq,
            nullptr, nullptr, nullptr);
        finalize_k<<<1, HD, 0, stream>>>(gsum, gsumsq, G + (size_t)t0 * HD,
                                         BT + (size_t)t0 * HD, scalev, shiftv,
                                         1.0f / (NRUNS * NPP));
        gemm128<M_GIN2, bf16r><<<NRUNS * NPP / 64, 256, 0, stream>>>(
            h_p, W2 + (size_t)t0 * HD * HD, B2 + (size_t)t0 * HD, h_p,
            NRUNS * NPP, NPP, nullptr, nullptr, nullptr, nullptr,
            scalev, shiftv, nullptr);

        gemm128<M_GIN1, bf16r><<<NRUNS * NAU / 64, 256, 0, stream>>>(
            h_a, W1 + (size_t)t1 * HD * HD, B1 + (size_t)t1 * HD, h_a,
            NRUNS * NAU, NAU, agg_a, EPS + t1, gsum, gsumsq,
            nullptr, nullptr, nullptr);
        finalize_k<<<1, HD, 0, stream>>>(gsum, gsumsq, G + (size_t)t1 * HD,
                                         BT + (size_t)t1 * HD, scalev, shiftv,
                                         1.0f / (NRUNS * NAU));
        gemm128<M_GIN2, bf16r><<<NRUNS * NAU / 64, 256, 0, stream>>>(
            h_a, W2 + (size_t)t1 * HD * HD, B2 + (size_t)t1 * HD, h_a,
            NRUNS * NAU, NAU, nullptr, nullptr, nullptr, nullptr,
            scalev, shiftv, nullptr);
    }

    final_k<bf16r><<<(NAU * 64) / 256, 256, 0, stream>>>(h_a, fw, fb, (float*)d_out);
}

extern "C" void kernel_launch(void* const* d_in, const int* in_sizes, int n_in,
                              void* d_out, int out_size, void* d_ws, size_t ws_size,
                              hipStream_t stream)
{
    const size_t hN = (size_t)NRUNS * (NAU + NPP) * HD;      // 76.8M elems
    const size_t aggN = (size_t)(NAU + NPP) * HD;            // 19.2M f32
    const size_t statB = 4 * HD * sizeof(float);
    const size_t need_f32  = statB + aggN * 4 + hN * 4;      // ~384.3 MB
    const size_t need_bf16 = statB + aggN * 4 + hN * 2;      // ~230.6 MB

    if (ws_size >= need_f32) {
        run_all<float>(d_in, d_out, d_ws, stream);
    } else {
        (void)need_bf16;
        run_bf16(d_in, d_out, d_ws, stream);
    }
}

// Round 3
// 1761.996 us; speedup vs baseline: 2.7692x; 2.7692x over previous
//
#include <hip/hip_runtime.h>

#define NRUNS 4
#define NAU 50000
#define NPP 100000
#define NEDGE 500000
#define HD 128
#define INV_KEEP 1.25f
#define BN_EPS 1e-5f

#define M_PROJ 0
#define M_GIN1 1
#define M_GIN2 2

typedef unsigned short bf16r;   // raw bf16 storage

__device__ inline float bf2f(bf16r u) {
    return __uint_as_float(((unsigned)u) << 16);
}
__device__ inline bf16r f2bf(float f) {
    unsigned x = __float_as_uint(f);
    return (bf16r)((x + 0x7fffu + ((x >> 16) & 1u)) >> 16);  // RNE
}

template<typename ST> __device__ inline float4 load4(const ST* p);
template<> __device__ inline float4 load4<float>(const float* p) {
    return *(const float4*)p;
}
template<> __device__ inline float4 load4<bf16r>(const bf16r* p) {
    ushort4 u = *(const ushort4*)p;
    return make_float4(bf2f(u.x), bf2f(u.y), bf2f(u.z), bf2f(u.w));
}
template<typename ST> __device__ inline void store4(ST* p, float4 v);
template<> __device__ inline void store4<float>(float* p, float4 v) {
    *(float4*)p = v;
}
template<> __device__ inline void store4<bf16r>(bf16r* p, float4 v) {
    ushort4 u;
    u.x = f2bf(v.x); u.y = f2bf(v.y); u.z = f2bf(v.z); u.w = f2bf(v.w);
    *(ushort4*)p = u;
}
template<typename ST> __device__ inline float2 load2(const ST* p);
template<> __device__ inline float2 load2<float>(const float* p) {
    return *(const float2*)p;
}
template<> __device__ inline float2 load2<bf16r>(const bf16r* p) {
    ushort2 u = *(const ushort2*)p;
    return make_float2(bf2f(u.x), bf2f(u.y));
}
template<typename ST> __device__ inline float load1(const ST* p);
template<> __device__ inline float load1<float>(const float* p) { return *p; }
template<> __device__ inline float load1<bf16r>(const bf16r* p) { return bf2f(*p); }

// grid-stride float4 zero fill
__global__ __launch_bounds__(256)
void zero_k(float* p, long n4) {
    long i = (long)blockIdx.x * 256 + threadIdx.x;
    long stride = (long)gridDim.x * 256;
    float4 z = make_float4(0.f, 0.f, 0.f, 0.f);
    for (; i < n4; i += stride) ((float4*)p)[i] = z;
}

// ================= CSR build (counting sort by dst) =================
__global__ __launch_bounds__(256)
void count_k(const int* __restrict__ ei, int E, int* cnt) {
    int e = blockIdx.x * 256 + threadIdx.x;
    if (e < E) atomicAdd(&cnt[ei[E + e]], 1);
}

// chunked exclusive scan, CHUNK = 1024 (256 thr x 4)
__global__ __launch_bounds__(256)
void scan1_k(const int* __restrict__ in, int* out, int* partial, int n) {
    __shared__ int lds[256];
    int b = blockIdx.x, t = threadIdx.x;
    int base = b * 1024 + t * 4;
    int v0 = 0, v1 = 0, v2 = 0, v3 = 0;
    if (base + 3 < n) {
        int4 x = *(const int4*)(in + base);
        v0 = x.x; v1 = x.y; v2 = x.z; v3 = x.w;
    } else {
        if (base + 0 < n) v0 = in[base + 0];
        if (base + 1 < n) v1 = in[base + 1];
        if (base + 2 < n) v2 = in[base + 2];
        if (base + 3 < n) v3 = in[base + 3];
    }
    int s = v0 + v1 + v2 + v3;
    lds[t] = s;
    __syncthreads();
    for (int d = 1; d < 256; d <<= 1) {
        int x = (t >= d) ? lds[t - d] : 0;
        __syncthreads();
        lds[t] += x;
        __syncthreads();
    }
    int excl = lds[t] - s;
    if (base + 0 < n) out[base + 0] = excl;
    if (base + 1 < n) out[base + 1] = excl + v0;
    if (base + 2 < n) out[base + 2] = excl + v0 + v1;
    if (base + 3 < n) out[base + 3] = excl + v0 + v1 + v2;
    if (t == 255) partial[b] = lds[255];
}

__global__ __launch_bounds__(256)
void scan2_k(int* partial, int n) {   // n <= 256, single block
    __shared__ int lds[256];
    int t = threadIdx.x;
    int s = (t < n) ? partial[t] : 0;
    lds[t] = s;
    __syncthreads();
    for (int d = 1; d < 256; d <<= 1) {
        int x = (t >= d) ? lds[t - d] : 0;
        __syncthreads();
        lds[t] += x;
        __syncthreads();
    }
    if (t < n) partial[t] = lds[t] - s;   // exclusive
}

__global__ __launch_bounds__(256)
void scan3_k(int* off, int* cur, const int* __restrict__ partial, int n, int total) {
    int b = blockIdx.x, t = threadIdx.x;
    int add = partial[b];
    int base = b * 1024 + t * 4;
    #pragma unroll
    for (int j = 0; j < 4; ++j) {
        int i = base + j;
        if (i < n) {
            int v = off[i] + add;
            off[i] = v;
            cur[i] = v;
        }
    }
    if (b == 0 && t == 0) off[n] = total;
}

__global__ __launch_bounds__(256)
void fill_k(const int* __restrict__ ei, int E, int* cur, int* bucket) {
    int e = blockIdx.x * 256 + threadIdx.x;
    if (e < E) {
        int d = ei[E + e];
        int p = atomicAdd(&cur[d], 1);
        bucket[p] = ei[e];
    }
}

static void build_csr(const int* ei, int E, int Nn, int* off, int* cur,
                      int* bucket, int* partial, hipStream_t stream)
{
    int nchunk = (Nn + 1023) / 1024;
    zero_k<<<64, 256, 0, stream>>>((float*)cur, Nn / 4);
    count_k<<<(E + 255) / 256, 256, 0, stream>>>(ei, E, cur);
    scan1_k<<<nchunk, 256, 0, stream>>>(cur, off, partial, Nn);
    scan2_k<<<1, 256, 0, stream>>>(partial, nchunk);
    scan3_k<<<nchunk, 256, 0, stream>>>(off, cur, partial, Nn, E);
    fill_k<<<(E + 255) / 256, 256, 0, stream>>>(ei, E, cur, bucket);
}

// gather: one 64-lane wave per dst node; lane owns 2 columns; agg row
// written exactly once (no atomics).
template<typename ST>
__global__ __launch_bounds__(256)
void gather_k(const ST* __restrict__ src, float* __restrict__ agg,
              const int* __restrict__ off, const int* __restrict__ bucket, int Nn)
{
    int w = (blockIdx.x * 256 + threadIdx.x) >> 6;
    int lane = threadIdx.x & 63;
    if (w >= Nn) return;
    int s0 = off[w], s1 = off[w + 1];
    float a0 = 0.f, a1 = 0.f;
    int e = s0;
    for (; e + 1 < s1; e += 2) {
        int i0 = bucket[e], i1 = bucket[e + 1];
        float2 u = load2<ST>(src + (size_t)i0 * HD + lane * 2);
        float2 v = load2<ST>(src + (size_t)i1 * HD + lane * 2);
        a0 += u.x + v.x;
        a1 += u.y + v.y;
    }
    if (e < s1) {
        float2 u = load2<ST>(src + (size_t)bucket[e] * HD + lane * 2);
        a0 += u.x;
        a1 += u.y;
    }
    *(float2*)(agg + (size_t)w * HD + lane * 2) = make_float2(a0, a1);
}

// fallback scatter (atomics) for tight workspaces
template<typename ST>
__global__ __launch_bounds__(256)
void scatter_k(const ST* __restrict__ src, float* dst,
               const int* __restrict__ ei, int E)
{
    int g = blockIdx.x * 256 + threadIdx.x;
    int e = g >> 5, lane = g & 31;
    if (e >= E) return;
    int s = ei[e], d = ei[E + e];
    float4 v = load4<ST>(src + (size_t)s * HD + lane * 4);
    float* dp = dst + (size_t)d * HD + lane * 4;
    unsafeAtomicAdd(dp + 0, v.x);
    unsafeAtomicAdd(dp + 1, v.y);
    unsafeAtomicAdd(dp + 2, v.z);
    unsafeAtomicAdd(dp + 3, v.w);
}

// ================= fused GEMM =================
// 64-row x 128-col x K=128, fused per-mode prologue/epilogue.
//  PROJ : out gets R copies of (x@W+b), each scaled by mask[r][node]*1.25
//  GIN1 : z = (1+eps)*h + (row<Nn ? agg[row] : 0); out = z@W+b (in place ok);
//         accumulates per-column sum/sumsq into gsum/gsumsq
//  GIN2 : t = relu(h*scale+shift); out = relu(t@W+b), in place
template<int MODE, typename ST, typename IT>
__global__ __launch_bounds__(256)
void gemm128(const IT* in, const float* __restrict__ Wm,
             const float* __restrict__ bias, ST* out,
             int M, int Nn,
             const float* __restrict__ agg, const float* __restrict__ epsp,
             float* gsum, float* gsumsq,
             const float* __restrict__ scale, const float* __restrict__ shift,
             const float* __restrict__ mask)
{
    __shared__ float zt[64][HD];
    const int tid = threadIdx.x;
    const int m0 = blockIdx.x * 64;

    float epsv = 1.0f;
    if (MODE == M_GIN1) epsv = 1.0f + epsp[0];

    #pragma unroll
    for (int p = 0; p < 8; ++p) {
        int flat = p * 1024 + tid * 4;
        int row = flat >> 7, col = flat & 127;
        int gr = m0 + row;
        float4 v = make_float4(0.f, 0.f, 0.f, 0.f);
        if (gr < M) {
            v = load4<IT>(in + (size_t)gr * HD + col);
            if (MODE == M_GIN1) {
                v.x *= epsv; v.y *= epsv; v.z *= epsv; v.w *= epsv;
                if (gr < Nn) {
                    float4 a = *(const float4*)(agg + (size_t)gr * HD + col);
                    v.x += a.x; v.y += a.y; v.z += a.z; v.w += a.w;
                }
            } else if (MODE == M_GIN2) {
                float4 sc = *(const float4*)(scale + col);
                float4 sh = *(const float4*)(shift + col);
                v.x = fmaxf(v.x * sc.x + sh.x, 0.f);
                v.y = fmaxf(v.y * sc.y + sh.y, 0.f);
                v.z = fmaxf(v.z * sc.z + sh.z, 0.f);
                v.w = fmaxf(v.w * sc.w + sh.w, 0.f);
            }
        }
        *(float4*)&zt[row][col] = v;
    }
    __syncthreads();

    const int cg = tid & 31, rg = tid >> 5;
    const int c0 = cg * 4, r0 = rg * 8;
    float acc[8][4];
    #pragma unroll
    for (int i = 0; i < 8; ++i)
        #pragma unroll
        for (int j = 0; j < 4; ++j) acc[i][j] = 0.f;

    const float4* W4 = (const float4*)Wm;
    #pragma unroll 4
    for (int k = 0; k < HD; k += 4) {
        float4 w0 = W4[(k + 0) * 32 + cg];
        float4 w1 = W4[(k + 1) * 32 + cg];
        float4 w2 = W4[(k + 2) * 32 + cg];
        float4 w3 = W4[(k + 3) * 32 + cg];
        #pragma unroll
        for (int i = 0; i < 8; ++i) {
            float4 z = *(const float4*)&zt[r0 + i][k];
            acc[i][0] += z.x * w0.x + z.y * w1.x + z.z * w2.x + z.w * w3.x;
            acc[i][1] += z.x * w0.y + z.y * w1.y + z.z * w2.y + z.w * w3.y;
            acc[i][2] += z.x * w0.z + z.y * w1.z + z.z * w2.z + z.w * w3.z;
            acc[i][3] += z.x * w0.w + z.y * w1.w + z.z * w2.w + z.w * w3.w;
        }
    }

    float4 b = *(const float4*)(bias + c0);
    float vv[8][4];
    #pragma unroll
    for (int i = 0; i < 8; ++i) {
        vv[i][0] = acc[i][0] + b.x;
        vv[i][1] = acc[i][1] + b.y;
        vv[i][2] = acc[i][2] + b.z;
        vv[i][3] = acc[i][3] + b.w;
    }

    if (MODE == M_PROJ) {
        #pragma unroll
        for (int i = 0; i < 8; ++i) {
            int gi = m0 + r0 + i;
            if (gi < M) {
                #pragma unroll
                for (int r = 0; r < NRUNS; ++r) {
                    float w = mask[(size_t)r * Nn + gi] * INV_KEEP;
                    store4<ST>(out + ((size_t)r * Nn + gi) * HD + c0,
                               make_float4(vv[i][0] * w, vv[i][1] * w,
                                           vv[i][2] * w, vv[i][3] * w));
                }
            }
        }
    } else if (MODE == M_GIN1) {
        #pragma unroll
        for (int i = 0; i < 8; ++i) {
            int gi = m0 + r0 + i;
            if (gi < M)
                store4<ST>(out + (size_t)gi * HD + c0,
                           make_float4(vv[i][0], vv[i][1], vv[i][2], vv[i][3]));
        }
        float s[4] = {0.f, 0.f, 0.f, 0.f}, q[4] = {0.f, 0.f, 0.f, 0.f};
        #pragma unroll
        for (int i = 0; i < 8; ++i)
            #pragma unroll
            for (int j = 0; j < 4; ++j) {
                s[j] += vv[i][j];
                q[j] += vv[i][j] * vv[i][j];
            }
        __syncthreads();
        float (*red)[HD] = (float(*)[HD])zt;
        #pragma unroll
        for (int j = 0; j < 4; ++j) red[rg][c0 + j] = s[j];
        __syncthreads();
        if (tid < HD) {
            float t = 0.f;
            #pragma unroll
            for (int g = 0; g < 8; ++g) t += red[g][tid];
            unsafeAtomicAdd(gsum + tid, t);
        }
        __syncthreads();
        #pragma unroll
        for (int j = 0; j < 4; ++j) red[rg][c0 + j] = q[j];
        __syncthreads();
        if (tid < HD) {
            float t = 0.f;
            #pragma unroll
            for (int g = 0; g < 8; ++g) t += red[g][tid];
            unsafeAtomicAdd(gsumsq + tid, t);
        }
    } else {  // M_GIN2
        #pragma unroll
        for (int i = 0; i < 8; ++i) {
            int gi = m0 + r0 + i;
            if (gi < M)
                store4<ST>(out + (size_t)gi * HD + c0,
                           make_float4(fmaxf(vv[i][0], 0.f), fmaxf(vv[i][1], 0.f),
                                       fmaxf(vv[i][2], 0.f), fmaxf(vv[i][3], 0.f)));
        }
    }
}

// BN stats -> scale/shift; re-zeros accumulators (deterministic replay)
__global__ void finalize_k(float* gsum, float* gsumsq,
                           const float* __restrict__ gamma,
                           const float* __restrict__ beta,
                           float* scale, float* shift, float invN)
{
    int c = threadIdx.x;
    float mu = gsum[c] * invN;
    float var = gsumsq[c] * invN - mu * mu;
    float sc = gamma[c] * rsqrtf(var + BN_EPS);
    scale[c] = sc;
    shift[c] = beta[c] - mu * sc;
    gsum[c] = 0.f;
    gsumsq[c] = 0.f;
}

// mean over runs + [128]x[128,4] matmul; one wave per author node
template<typename ST>
__global__ __launch_bounds__(256)
void final_k(const ST* __restrict__ ha, const float* __restrict__ fw,
             const float* __restrict__ fb, float* __restrict__ out)
{
    int g = blockIdx.x * 256 + threadIdx.x;
    int node = g >> 6, lane = g & 63;
    if (node >= NAU) return;
    float m0 = 0.f, m1 = 0.f;
    #pragma unroll
    for (int r = 0; r < NRUNS; ++r) {
        size_t base = ((size_t)r * NAU + node) * HD;
        m0 += load1<ST>(ha + base + lane);
        m1 += load1<ST>(ha + base + 64 + lane);
    }
    m0 *= 0.25f;
    m1 *= 0.25f;
    float p[4];
    #pragma unroll
    for (int c = 0; c < 4; ++c)
        p[c] = m0 * fw[lane * 4 + c] + m1 * fw[(lane + 64) * 4 + c];
    #pragma unroll
    for (int off = 32; off >= 1; off >>= 1)
        #pragma unroll
        for (int c = 0; c < 4; ++c) p[c] += __shfl_down(p[c], off);
    if (lane == 0) {
        #pragma unroll
        for (int c = 0; c < 4; ++c) out[(size_t)node * 4 + c] = p[c] + fb[c];
    }
}

#define CSR_INTS ((size_t)(NPP + 4) + NPP + NEDGE + (NAU + 4) + NAU + NEDGE + 256)

template<typename ST, bool GATHER>
static void run_all(void* const* d_in, void* d_out, void* d_ws, hipStream_t stream)
{
    const float* x_author = (const float*)d_in[0];
    const float* x_paper  = (const float*)d_in[1];
    const int*   ei_ap    = (const int*)d_in[2];
    const int*   ei_pa    = (const int*)d_in[3];
    const float* drop_a   = (const float*)d_in[4];
    const float* drop_p   = (const float*)d_in[5];
    const float* lin_a_w  = (const float*)d_in[6];
    const float* lin_a_b  = (const float*)d_in[7];
    const float* lin_p_w  = (const float*)d_in[8];
    const float* lin_p_b  = (const float*)d_in[9];
    const float* W1       = (const float*)d_in[10];
    const float* B1       = (const float*)d_in[11];
    const float* G        = (const float*)d_in[12];
    const float* BT       = (const float*)d_in[13];
    const float* W2       = (const float*)d_in[14];
    const float* B2       = (const float*)d_in[15];
    const float* EPS      = (const float*)d_in[16];
    const float* fw       = (const float*)d_in[17];
    const float* fb       = (const float*)d_in[18];

    float* gsum   = (float*)d_ws;
    float* gsumsq = gsum + HD;
    float* scalev = gsumsq + HD;
    float* shiftv = scalev + HD;
    float* after_stats = shiftv + HD;

    int *off_ap = nullptr, *cur_ap = nullptr, *bkt_ap = nullptr;
    int *off_pa = nullptr, *cur_pa = nullptr, *bkt_pa = nullptr;
    int *partial = nullptr;
    float* agg_a;
    if (GATHER) {
        int* ip = (int*)after_stats;
        off_ap = ip;               ip += NPP + 4;
        cur_ap = ip;               ip += NPP;
        bkt_ap = ip;               ip += NEDGE;
        off_pa = ip;               ip += NAU + 4;
        cur_pa = ip;               ip += NAU;
        bkt_pa = ip;               ip += NEDGE;
        partial = ip;              ip += 256;
        agg_a = (float*)ip;
    } else {
        agg_a = after_stats;
    }
    float* agg_p = agg_a + (size_t)NAU * HD;
    ST* h_a = (ST*)(agg_p + (size_t)NPP * HD);
    ST* h_p = h_a + (size_t)NRUNS * NAU * HD;

    zero_k<<<1, 256, 0, stream>>>(gsum, (4 * HD) / 4);

    if (GATHER) {
        build_csr(ei_ap, NEDGE, NPP, off_ap, cur_ap, bkt_ap, partial, stream);
        build_csr(ei_pa, NEDGE, NAU, off_pa, cur_pa, bkt_pa, partial, stream);
    }

    // input projections + dropout expansion (input always f32)
    gemm128<M_PROJ, ST, float><<<(NAU + 63) / 64, 256, 0, stream>>>(
        x_author, lin_a_w, lin_a_b, h_a, NAU, NAU,
        nullptr, nullptr, nullptr, nullptr, nullptr, nullptr, drop_a);
    gemm128<M_PROJ, ST, float><<<(NPP + 63) / 64, 256, 0, stream>>>(
        x_paper, lin_p_w, lin_p_b, h_p, NPP, NPP,
        nullptr, nullptr, nullptr, nullptr, nullptr, nullptr, drop_p);

    for (int l = 0; l < 2; ++l) {
        int t0 = l * 2 + 0, t1 = l * 2 + 1;

        if (GATHER) {
            gather_k<ST><<<(NPP * 64) / 256, 256, 0, stream>>>(h_a, agg_p, off_ap, bkt_ap, NPP);
            gather_k<ST><<<(NAU * 64) / 256, 256, 0, stream>>>(h_p, agg_a, off_pa, bkt_pa, NAU);
        } else {
            zero_k<<<2048, 256, 0, stream>>>(agg_a, ((size_t)(NAU + NPP) * HD) / 4);
            scatter_k<ST><<<(NEDGE * 32) / 256, 256, 0, stream>>>(h_a, agg_p, ei_ap, NEDGE);
            scatter_k<ST><<<(NEDGE * 32) / 256, 256, 0, stream>>>(h_p, agg_a, ei_pa, NEDGE);
        }

        // paper GIN (params [l,0]) — in place on h_p
        gemm128<M_GIN1, ST, ST><<<NRUNS * NPP / 64, 256, 0, stream>>>(
            h_p, W1 + (size_t)t0 * HD * HD, B1 + (size_t)t0 * HD, h_p,
            NRUNS * NPP, NPP, agg_p, EPS + t0, gsum, gsumsq,
            nullptr, nullptr, nullptr);
        finalize_k<<<1, HD, 0, stream>>>(gsum, gsumsq, G + (size_t)t0 * HD,
                                         BT + (size_t)t0 * HD, scalev, shiftv,
                                         1.0f / (NRUNS * NPP));
        gemm128<M_GIN2, ST, ST><<<NRUNS * NPP / 64, 256, 0, stream>>>(
            h_p, W2 + (size_t)t0 * HD * HD, B2 + (size_t)t0 * HD, h_p,
            NRUNS * NPP, NPP, nullptr, nullptr, nullptr, nullptr,
            scalev, shiftv, nullptr);

        // author GIN (params [l,1]) — in place on h_a
        gemm128<M_GIN1, ST, ST><<<NRUNS * NAU / 64, 256, 0, stream>>>(
            h_a, W1 + (size_t)t1 * HD * HD, B1 + (size_t)t1 * HD, h_a,
            NRUNS * NAU, NAU, agg_a, EPS + t1, gsum, gsumsq,
            nullptr, nullptr, nullptr);
        finalize_k<<<1, HD, 0, stream>>>(gsum, gsumsq, G + (size_t)t1 * HD,
                                         BT + (size_t)t1 * HD, scalev, shiftv,
                                         1.0f / (NRUNS * NAU));
        gemm128<M_GIN2, ST, ST><<<NRUNS * NAU / 64, 256, 0, stream>>>(
            h_a, W2 + (size_t)t1 * HD * HD, B2 + (size_t)t1 * HD, h_a,
            NRUNS * NAU, NAU, nullptr, nullptr, nullptr, nullptr,
            scalev, shiftv, nullptr);
    }

    final_k<ST><<<(NAU * 64) / 256, 256, 0, stream>>>(h_a, fw, fb, (float*)d_out);
}

extern "C" void kernel_launch(void* const* d_in, const int* in_sizes, int n_in,
                              void* d_out, int out_size, void* d_ws, size_t ws_size,
                              hipStream_t stream)
{
    const size_t hN   = (size_t)NRUNS * (NAU + NPP) * HD;    // h elements
    const size_t aggN = (size_t)(NAU + NPP) * HD;            // agg f32 elements
    const size_t statB = 4 * HD * sizeof(float);
    const size_t csrB  = CSR_INTS * sizeof(int);             // ~5.2 MB

    const size_t need_f32g  = statB + csrB + aggN * 4 + hN * 4;  // ~389.5 MB
    const size_t need_bf16g = statB + csrB + aggN * 4 + hN * 2;  // ~235.8 MB

    if (ws_size >= need_f32g) {
        run_all<float, true>(d_in, d_out, d_ws, stream);
    } else if (ws_size >= need_bf16g) {
        run_all<bf16r, true>(d_in, d_out, d_ws, stream);
    } else {
        run_all<bf16r, false>(d_in, d_out, d_ws, stream);    // atomic fallback
    }
}

// Round 4
// 1471.350 us; speedup vs baseline: 3.3162x; 1.1975x over previous
//
#include <hip/hip_runtime.h>

#define NRUNS 4
#define NAU 50000
#define NPP 100000
#define NEDGE 500000
#define HD 128
#define INV_KEEP 1.25f
#define BN_EPS 1e-5f
#define LDA 136   // padded LDS row (bf16 elems), 272B, keeps 16B alignment

#define M_PROJ 0
#define M_GIN1 1
#define M_GIN2 2

typedef unsigned short bf16r;
typedef __attribute__((ext_vector_type(8))) short v8s;   // 8 bf16 (4 VGPR)
typedef __attribute__((ext_vector_type(4))) float v4f;   // 4 f32 acc

__device__ inline float bf2f(bf16r u) {
    return __uint_as_float(((unsigned)u) << 16);
}
__device__ inline bf16r f2bf(float f) {
    unsigned x = __float_as_uint(f);
    return (bf16r)((x + 0x7fffu + ((x >> 16) & 1u)) >> 16);  // RNE
}

// grid-stride float4 zero fill
__global__ __launch_bounds__(256)
void zero_k(float* p, long n4) {
    long i = (long)blockIdx.x * 256 + threadIdx.x;
    long stride = (long)gridDim.x * 256;
    float4 z = make_float4(0.f, 0.f, 0.f, 0.f);
    for (; i < n4; i += stride) ((float4*)p)[i] = z;
}

// ============ weight convert: f32 [k][n] -> bf16 transposed [n][k] ============
// tables: 0=lin_a, 1=lin_p, 2..5=W1[0..3], 6..9=W2[0..3]
__global__ __launch_bounds__(256)
void convw_k(const float* __restrict__ lin_a_w, const float* __restrict__ lin_p_w,
             const float* __restrict__ W1, const float* __restrict__ W2,
             bf16r* __restrict__ wt)
{
    int t = blockIdx.x >> 6;
    int e = (blockIdx.x & 63) * 256 + threadIdx.x;   // 0..16383
    const float* src;
    if (t == 0) src = lin_a_w;
    else if (t == 1) src = lin_p_w;
    else if (t < 6) src = W1 + (size_t)(t - 2) * HD * HD;
    else src = W2 + (size_t)(t - 6) * HD * HD;
    int n = e >> 7, k = e & 127;
    wt[(size_t)t * HD * HD + e] = f2bf(src[(size_t)k * HD + n]);
}

// ================= CSR build (counting sort by dst) =================
__global__ __launch_bounds__(256)
void count_k(const int* __restrict__ ei, int E, int* cnt) {
    int e = blockIdx.x * 256 + threadIdx.x;
    if (e < E) atomicAdd(&cnt[ei[E + e]], 1);
}

__global__ __launch_bounds__(256)
void scan1_k(const int* __restrict__ in, int* out, int* partial, int n) {
    __shared__ int lds[256];
    int b = blockIdx.x, t = threadIdx.x;
    int base = b * 1024 + t * 4;
    int v0 = 0, v1 = 0, v2 = 0, v3 = 0;
    if (base + 3 < n) {
        int4 x = *(const int4*)(in + base);
        v0 = x.x; v1 = x.y; v2 = x.z; v3 = x.w;
    } else {
        if (base + 0 < n) v0 = in[base + 0];
        if (base + 1 < n) v1 = in[base + 1];
        if (base + 2 < n) v2 = in[base + 2];
        if (base + 3 < n) v3 = in[base + 3];
    }
    int s = v0 + v1 + v2 + v3;
    lds[t] = s;
    __syncthreads();
    for (int d = 1; d < 256; d <<= 1) {
        int x = (t >= d) ? lds[t - d] : 0;
        __syncthreads();
        lds[t] += x;
        __syncthreads();
    }
    int excl = lds[t] - s;
    if (base + 0 < n) out[base + 0] = excl;
    if (base + 1 < n) out[base + 1] = excl + v0;
    if (base + 2 < n) out[base + 2] = excl + v0 + v1;
    if (base + 3 < n) out[base + 3] = excl + v0 + v1 + v2;
    if (t == 255) partial[b] = lds[255];
}

__global__ __launch_bounds__(256)
void scan2_k(int* partial, int n) {
    __shared__ int lds[256];
    int t = threadIdx.x;
    int s = (t < n) ? partial[t] : 0;
    lds[t] = s;
    __syncthreads();
    for (int d = 1; d < 256; d <<= 1) {
        int x = (t >= d) ? lds[t - d] : 0;
        __syncthreads();
        lds[t] += x;
        __syncthreads();
    }
    if (t < n) partial[t] = lds[t] - s;
}

__global__ __launch_bounds__(256)
void scan3_k(int* off, int* cur, const int* __restrict__ partial, int n, int total) {
    int b = blockIdx.x, t = threadIdx.x;
    int add = partial[b];
    int base = b * 1024 + t * 4;
    #pragma unroll
    for (int j = 0; j < 4; ++j) {
        int i = base + j;
        if (i < n) {
            int v = off[i] + add;
            off[i] = v;
            cur[i] = v;
        }
    }
    if (b == 0 && t == 0) off[n] = total;
}

__global__ __launch_bounds__(256)
void fill_k(const int* __restrict__ ei, int E, int* cur, int* bucket) {
    int e = blockIdx.x * 256 + threadIdx.x;
    if (e < E) {
        int d = ei[E + e];
        int p = atomicAdd(&cur[d], 1);
        bucket[p] = ei[e];
    }
}

static void build_csr(const int* ei, int E, int Nn, int* off, int* cur,
                      int* bucket, int* partial, hipStream_t stream)
{
    int nchunk = (Nn + 1023) / 1024;
    zero_k<<<64, 256, 0, stream>>>((float*)cur, Nn / 4);
    count_k<<<(E + 255) / 256, 256, 0, stream>>>(ei, E, cur);
    scan1_k<<<nchunk, 256, 0, stream>>>(cur, off, partial, Nn);
    scan2_k<<<1, 256, 0, stream>>>(partial, nchunk);
    scan3_k<<<nchunk, 256, 0, stream>>>(off, cur, partial, Nn, E);
    fill_k<<<(E + 255) / 256, 256, 0, stream>>>(ei, E, cur, bucket);
}

// gather: one 64-lane wave per dst node; lane owns 2 columns
__global__ __launch_bounds__(256)
void gather_k(const bf16r* __restrict__ src, float* __restrict__ agg,
              const int* __restrict__ off, const int* __restrict__ bucket, int Nn)
{
    int w = (blockIdx.x * 256 + threadIdx.x) >> 6;
    int lane = threadIdx.x & 63;
    if (w >= Nn) return;
    int s0 = off[w], s1 = off[w + 1];
    float a0 = 0.f, a1 = 0.f;
    int e = s0;
    for (; e + 1 < s1; e += 2) {
        int i0 = bucket[e], i1 = bucket[e + 1];
        ushort2 u = *(const ushort2*)(src + (size_t)i0 * HD + lane * 2);
        ushort2 v = *(const ushort2*)(src + (size_t)i1 * HD + lane * 2);
        a0 += bf2f(u.x) + bf2f(v.x);
        a1 += bf2f(u.y) + bf2f(v.y);
    }
    if (e < s1) {
        ushort2 u = *(const ushort2*)(src + (size_t)bucket[e] * HD + lane * 2);
        a0 += bf2f(u.x);
        a1 += bf2f(u.y);
    }
    *(float2*)(agg + (size_t)w * HD + lane * 2) = make_float2(a0, a1);
}

// fallback scatter (atomics) for tight workspaces
__global__ __launch_bounds__(256)
void scatter_k(const bf16r* __restrict__ src, float* dst,
               const int* __restrict__ ei, int E)
{
    int g = blockIdx.x * 256 + threadIdx.x;
    int e = g >> 5, lane = g & 31;
    if (e >= E) return;
    int s = ei[e], d = ei[E + e];
    ushort4 u = *(const ushort4*)(src + (size_t)s * HD + lane * 4);
    float* dp = dst + (size_t)d * HD + lane * 4;
    unsafeAtomicAdd(dp + 0, bf2f(u.x));
    unsafeAtomicAdd(dp + 1, bf2f(u.y));
    unsafeAtomicAdd(dp + 2, bf2f(u.z));
    unsafeAtomicAdd(dp + 3, bf2f(u.w));
}

// ================= MFMA GEMM =================
// 64-row tile x 128 cols x K=128; 4 waves, each wave 16 rows x 128 cols
// (8 fragments x 4 k-steps of 16x16x32 bf16 MFMA). A staged in LDS with fused
// per-mode transform; B read from L1-resident transposed bf16 Wt [n][k].
//  PROJ : A = x (f32->bf16); out gets R copies scaled by mask[r][node]*1.25
//  GIN1 : A = bf16((1+eps)*h + (row<Nn ? agg : 0)); out = A@W+b (in place ok);
//         accumulates per-col sum/sumsq
//  GIN2 : A = bf16(relu(h*scale+shift)); out = relu(A@W+b), in place
template<int MODE, typename IT>
__global__ __launch_bounds__(256)
void mfma_gemm(const IT* __restrict__ in, const bf16r* __restrict__ Wt,
               const float* __restrict__ bias, bf16r* __restrict__ out,
               int M, int Nn,
               const float* __restrict__ agg, const float* __restrict__ epsp,
               float* gsum, float* gsumsq,
               const float* __restrict__ scale, const float* __restrict__ shift,
               const float* __restrict__ mask)
{
    __shared__ bf16r za[64][LDA];
    __shared__ float red[2][4][HD];
    const int tid = threadIdx.x;
    const int m0 = blockIdx.x * 64;

    float epsv = 1.0f;
    if (MODE == M_GIN1) epsv = 1.0f + epsp[0];

    // ---- stage A tile (64x128 bf16), fused transform ----
    #pragma unroll
    for (int i = 0; i < 4; ++i) {
        int c = tid + 256 * i;                 // chunk 0..1023
        int row = c >> 4, col = (c & 15) * 8;
        int gr = m0 + row;
        float v[8];
        if (gr < M) {
            if constexpr (sizeof(IT) == 4) {   // f32 input (PROJ)
                float4 u0 = *(const float4*)((const float*)in + (size_t)gr * HD + col);
                float4 u1 = *(const float4*)((const float*)in + (size_t)gr * HD + col + 4);
                v[0] = u0.x; v[1] = u0.y; v[2] = u0.z; v[3] = u0.w;
                v[4] = u1.x; v[5] = u1.y; v[6] = u1.z; v[7] = u1.w;
            } else {                           // bf16 input
                ushort4 u0 = *(const ushort4*)((const bf16r*)in + (size_t)gr * HD + col);
                ushort4 u1 = *(const ushort4*)((const bf16r*)in + (size_t)gr * HD + col + 4);
                v[0] = bf2f(u0.x); v[1] = bf2f(u0.y); v[2] = bf2f(u0.z); v[3] = bf2f(u0.w);
                v[4] = bf2f(u1.x); v[5] = bf2f(u1.y); v[6] = bf2f(u1.z); v[7] = bf2f(u1.w);
            }
            if (MODE == M_GIN1) {
                #pragma unroll
                for (int j = 0; j < 8; ++j) v[j] *= epsv;
                if (gr < Nn) {
                    float4 a0 = *(const float4*)(agg + (size_t)gr * HD + col);
                    float4 a1 = *(const float4*)(agg + (size_t)gr * HD + col + 4);
                    v[0] += a0.x; v[1] += a0.y; v[2] += a0.z; v[3] += a0.w;
                    v[4] += a1.x; v[5] += a1.y; v[6] += a1.z; v[7] += a1.w;
                }
            } else if (MODE == M_GIN2) {
                float4 sc0 = *(const float4*)(scale + col);
                float4 sc1 = *(const float4*)(scale + col + 4);
                float4 sh0 = *(const float4*)(shift + col);
                float4 sh1 = *(const float4*)(shift + col + 4);
                v[0] = fmaxf(v[0] * sc0.x + sh0.x, 0.f);
                v[1] = fmaxf(v[1] * sc0.y + sh0.y, 0.f);
                v[2] = fmaxf(v[2] * sc0.z + sh0.z, 0.f);
                v[3] = fmaxf(v[3] * sc0.w + sh0.w, 0.f);
                v[4] = fmaxf(v[4] * sc1.x + sh1.x, 0.f);
                v[5] = fmaxf(v[5] * sc1.y + sh1.y, 0.f);
                v[6] = fmaxf(v[6] * sc1.z + sh1.z, 0.f);
                v[7] = fmaxf(v[7] * sc1.w + sh1.w, 0.f);
            }
        } else {
            #pragma unroll
            for (int j = 0; j < 8; ++j) v[j] = 0.f;
        }
        ushort4 o0, o1;
        o0.x = f2bf(v[0]); o0.y = f2bf(v[1]); o0.z = f2bf(v[2]); o0.w = f2bf(v[3]);
        o1.x = f2bf(v[4]); o1.y = f2bf(v[5]); o1.z = f2bf(v[6]); o1.w = f2bf(v[7]);
        *(ushort4*)&za[row][col] = o0;
        *(ushort4*)&za[row][col + 4] = o1;
    }
    __syncthreads();

    // ---- MFMA compute ----
    const int wid = tid >> 6, lane = tid & 63;
    const int lr = lane & 15;          // A row / B col / D col
    const int lk = (lane >> 4) * 8;    // k offset within 32-wide k-step
    const int arow = wid * 16 + lr;

    v4f acc[8];
    #pragma unroll
    for (int n = 0; n < 8; ++n) acc[n] = (v4f){0.f, 0.f, 0.f, 0.f};

    #pragma unroll
    for (int ks = 0; ks < 4; ++ks) {
        v8s a = *(const v8s*)&za[arow][ks * 32 + lk];
        #pragma unroll
        for (int n = 0; n < 8; ++n) {
            v8s b = *(const v8s*)(Wt + (size_t)(n * 16 + lr) * HD + ks * 32 + lk);
            acc[n] = __builtin_amdgcn_mfma_f32_16x16x32_bf16(a, b, acc[n], 0, 0, 0);
        }
    }

    // bias (D: col = n*16 + lr, rows = row0..row0+3)
    #pragma unroll
    for (int n = 0; n < 8; ++n) {
        float bn = bias[n * 16 + lr];
        #pragma unroll
        for (int r = 0; r < 4; ++r) acc[n][r] += bn;
    }
    const int row0 = m0 + wid * 16 + (lane >> 4) * 4;

    // ---- epilogue ----
    if (MODE == M_PROJ) {
        float mk[4][NRUNS];
        #pragma unroll
        for (int r = 0; r < 4; ++r) {
            int gi = row0 + r;
            bool ok = gi < M;
            #pragma unroll
            for (int run = 0; run < NRUNS; ++run)
                mk[r][run] = ok ? mask[(size_t)run * Nn + gi] * INV_KEEP : 0.f;
        }
        #pragma unroll
        for (int n = 0; n < 8; ++n)
            #pragma unroll
            for (int r = 0; r < 4; ++r) {
                int gi = row0 + r;
                if (gi < M) {
                    float v = acc[n][r];
                    #pragma unroll
                    for (int run = 0; run < NRUNS; ++run)
                        out[((size_t)run * Nn + gi) * HD + n * 16 + lr] =
                            f2bf(v * mk[r][run]);
                }
            }
    } else if (MODE == M_GIN1) {
        #pragma unroll
        for (int n = 0; n < 8; ++n)
            #pragma unroll
            for (int r = 0; r < 4; ++r)
                out[(size_t)(row0 + r) * HD + n * 16 + lr] = f2bf(acc[n][r]);
        // per-column stats (M is a multiple of 64 for GIN passes)
        float s[8], q[8];
        #pragma unroll
        for (int n = 0; n < 8; ++n) {
            float ss = 0.f, qq = 0.f;
            #pragma unroll
            for (int r = 0; r < 4; ++r) {
                float v = acc[n][r];
                ss += v;
                qq += v * v;
            }
            ss += __shfl_xor(ss, 16);
            ss += __shfl_xor(ss, 32);
            qq += __shfl_xor(qq, 16);
            qq += __shfl_xor(qq, 32);
            s[n] = ss;
            q[n] = qq;
        }
        if (lane < 16) {
            #pragma unroll
            for (int n = 0; n < 8; ++n) {
                red[0][wid][n * 16 + lane] = s[n];
                red[1][wid][n * 16 + lane] = q[n];
            }
        }
        __syncthreads();
        if (tid < HD) {
            float t0 = red[0][0][tid] + red[0][1][tid] + red[0][2][tid] + red[0][3][tid];
            unsafeAtomicAdd(gsum + tid, t0);
            float t1 = red[1][0][tid] + red[1][1][tid] + red[1][2][tid] + red[1][3][tid];
            unsafeAtomicAdd(gsumsq + tid, t1);
        }
    } else {  // M_GIN2
        #pragma unroll
        for (int n = 0; n < 8; ++n)
            #pragma unroll
            for (int r = 0; r < 4; ++r)
                out[(size_t)(row0 + r) * HD + n * 16 + lr] =
                    f2bf(fmaxf(acc[n][r], 0.f));
    }
}

// BN stats -> scale/shift; re-zeros accumulators (deterministic replay)
__global__ void finalize_k(float* gsum, float* gsumsq,
                           const float* __restrict__ gamma,
                           const float* __restrict__ beta,
                           float* scale, float* shift, float invN)
{
    int c = threadIdx.x;
    float mu = gsum[c] * invN;
    float var = gsumsq[c] * invN - mu * mu;
    float sc = gamma[c] * rsqrtf(var + BN_EPS);
    scale[c] = sc;
    shift[c] = beta[c] - mu * sc;
    gsum[c] = 0.f;
    gsumsq[c] = 0.f;
}

// mean over runs + [128]x[128,4] matmul; one wave per author node
__global__ __launch_bounds__(256)
void final_k(const bf16r* __restrict__ ha, const float* __restrict__ fw,
             const float* __restrict__ fb, float* __restrict__ out)
{
    int g = blockIdx.x * 256 + threadIdx.x;
    int node = g >> 6, lane = g & 63;
    if (node >= NAU) return;
    float m0 = 0.f, m1 = 0.f;
    #pragma unroll
    for (int r = 0; r < NRUNS; ++r) {
        size_t base = ((size_t)r * NAU + node) * HD;
        m0 += bf2f(ha[base + lane]);
        m1 += bf2f(ha[base + 64 + lane]);
    }
    m0 *= 0.25f;
    m1 *= 0.25f;
    float p[4];
    #pragma unroll
    for (int c = 0; c < 4; ++c)
        p[c] = m0 * fw[lane * 4 + c] + m1 * fw[(lane + 64) * 4 + c];
    #pragma unroll
    for (int off = 32; off >= 1; off >>= 1)
        #pragma unroll
        for (int c = 0; c < 4; ++c) p[c] += __shfl_down(p[c], off);
    if (lane == 0) {
        #pragma unroll
        for (int c = 0; c < 4; ++c) out[(size_t)node * 4 + c] = p[c] + fb[c];
    }
}

#define CSR_INTS ((size_t)(NPP + 4) + NEDGE + (NAU + 4) + NEDGE)
#define WT_ELEMS ((size_t)10 * HD * HD)

template<bool GATHER>
static void run_all(void* const* d_in, void* d_out, void* d_ws, hipStream_t stream)
{
    const float* x_author = (const float*)d_in[0];
    const float* x_paper  = (const float*)d_in[1];
    const int*   ei_ap    = (const int*)d_in[2];
    const int*   ei_pa    = (const int*)d_in[3];
    const float* drop_a   = (const float*)d_in[4];
    const float* drop_p   = (const float*)d_in[5];
    const float* lin_a_w  = (const float*)d_in[6];
    const float* lin_a_b  = (const float*)d_in[7];
    const float* lin_p_w  = (const float*)d_in[8];
    const float* lin_p_b  = (const float*)d_in[9];
    const float* W1       = (const float*)d_in[10];
    const float* B1       = (const float*)d_in[11];
    const float* G        = (const float*)d_in[12];
    const float* BT       = (const float*)d_in[13];
    const float* W2       = (const float*)d_in[14];
    const float* B2       = (const float*)d_in[15];
    const float* EPS      = (const float*)d_in[16];
    const float* fw       = (const float*)d_in[17];
    const float* fb       = (const float*)d_in[18];

    // ws: [stats 512 f32][Wt 10x16384 bf16][CSR][agg_a][agg_p][h_a][h_p]
    float* gsum   = (float*)d_ws;
    float* gsumsq = gsum + HD;
    float* scalev = gsumsq + HD;
    float* shiftv = scalev + HD;
    bf16r* wt = (bf16r*)(shiftv + HD);
    int* ip = (int*)(wt + WT_ELEMS);

    int *off_ap = nullptr, *bkt_ap = nullptr, *off_pa = nullptr, *bkt_pa = nullptr;
    if (GATHER) {
        off_ap = ip;  ip += NPP + 4;
        bkt_ap = ip;  ip += NEDGE;
        off_pa = ip;  ip += NAU + 4;
        bkt_pa = ip;  ip += NEDGE;
    }
    float* agg_a = (float*)ip;
    float* agg_p = agg_a + (size_t)NAU * HD;
    bf16r* h_a = (bf16r*)(agg_p + (size_t)NPP * HD);
    bf16r* h_p = h_a + (size_t)NRUNS * NAU * HD;

    const bf16r* wt_lin_a = wt;
    const bf16r* wt_lin_p = wt + (size_t)1 * HD * HD;
    const bf16r* wt_W1    = wt + (size_t)2 * HD * HD;
    const bf16r* wt_W2    = wt + (size_t)6 * HD * HD;

    convw_k<<<640, 256, 0, stream>>>(lin_a_w, lin_p_w, W1, W2, wt);
    zero_k<<<1, 256, 0, stream>>>(gsum, (4 * HD) / 4);

    if (GATHER) {
        // cur/partial alias the (not-yet-used) agg buffers
        int* cur_ap  = (int*)agg_a;
        int* cur_pa  = cur_ap + NPP;
        int* partial = cur_pa + NAU;
        build_csr(ei_ap, NEDGE, NPP, off_ap, cur_ap, bkt_ap, partial, stream);
        build_csr(ei_pa, NEDGE, NAU, off_pa, cur_pa, bkt_pa, partial, stream);
    }

    // input projections + dropout expansion
    mfma_gemm<M_PROJ, float><<<(NAU + 63) / 64, 256, 0, stream>>>(
        x_author, wt_lin_a, lin_a_b, h_a, NAU, NAU,
        nullptr, nullptr, nullptr, nullptr, nullptr, nullptr, drop_a);
    mfma_gemm<M_PROJ, float><<<(NPP + 63) / 64, 256, 0, stream>>>(
        x_paper, wt_lin_p, lin_p_b, h_p, NPP, NPP,
        nullptr, nullptr, nullptr, nullptr, nullptr, nullptr, drop_p);

    for (int l = 0; l < 2; ++l) {
        int t0 = l * 2 + 0, t1 = l * 2 + 1;

        if (GATHER) {
            gather_k<<<(NPP * 64) / 256, 256, 0, stream>>>(h_a, agg_p, off_ap, bkt_ap, NPP);
            gather_k<<<(NAU * 64) / 256, 256, 0, stream>>>(h_p, agg_a, off_pa, bkt_pa, NAU);
        } else {
            zero_k<<<2048, 256, 0, stream>>>(agg_a, ((size_t)(NAU + NPP) * HD) / 4);
            scatter_k<<<(NEDGE * 32) / 256, 256, 0, stream>>>(h_a, agg_p, ei_ap, NEDGE);
            scatter_k<<<(NEDGE * 32) / 256, 256, 0, stream>>>(h_p, agg_a, ei_pa, NEDGE);
        }

        // paper GIN (params [l,0]) — in place on h_p
        mfma_gemm<M_GIN1, bf16r><<<NRUNS * NPP / 64, 256, 0, stream>>>(
            h_p, wt_W1 + (size_t)t0 * HD * HD, B1 + (size_t)t0 * HD, h_p,
            NRUNS * NPP, NPP, agg_p, EPS + t0, gsum, gsumsq,
            nullptr, nullptr, nullptr);
        finalize_k<<<1, HD, 0, stream>>>(gsum, gsumsq, G + (size_t)t0 * HD,
                                         BT + (size_t)t0 * HD, scalev, shiftv,
                                         1.0f / (NRUNS * NPP));
        mfma_gemm<M_GIN2, bf16r><<<NRUNS * NPP / 64, 256, 0, stream>>>(
            h_p, wt_W2 + (size_t)t0 * HD * HD, B2 + (size_t)t0 * HD, h_p,
            NRUNS * NPP, NPP, nullptr, nullptr, nullptr, nullptr,
            scalev, shiftv, nullptr);

        // author GIN (params [l,1]) — in place on h_a
        mfma_gemm<M_GIN1, bf16r><<<NRUNS * NAU / 64, 256, 0, stream>>>(
            h_a, wt_W1 + (size_t)t1 * HD * HD, B1 + (size_t)t1 * HD, h_a,
            NRUNS * NAU, NAU, agg_a, EPS + t1, gsum, gsumsq,
            nullptr, nullptr, nullptr);
        finalize_k<<<1, HD, 0, stream>>>(gsum, gsumsq, G + (size_t)t1 * HD,
                                         BT + (size_t)t1 * HD, scalev, shiftv,
                                         1.0f / (NRUNS * NAU));
        mfma_gemm<M_GIN2, bf16r><<<NRUNS * NAU / 64, 256, 0, stream>>>(
            h_a, wt_W2 + (size_t)t1 * HD * HD, B2 + (size_t)t1 * HD, h_a,
            NRUNS * NAU, NAU, nullptr, nullptr, nullptr, nullptr,
            scalev, shiftv, nullptr);
    }

    final_k<<<(NAU * 64) / 256, 256, 0, stream>>>(h_a, fw, fb, (float*)d_out);
}

extern "C" void kernel_launch(void* const* d_in, const int* in_sizes, int n_in,
                              void* d_out, int out_size, void* d_ws, size_t ws_size,
                              hipStream_t stream)
{
    const size_t hB    = (size_t)NRUNS * (NAU + NPP) * HD * sizeof(bf16r);
    const size_t aggB  = (size_t)(NAU + NPP) * HD * sizeof(float);
    const size_t statB = 4 * HD * sizeof(float);
    const size_t wtB   = WT_ELEMS * sizeof(bf16r);
    const size_t csrB  = CSR_INTS * sizeof(int);

    const size_t need_gather = statB + wtB + csrB + aggB + hB;   // ~235.4 MB
    if (ws_size >= need_gather) {
        run_all<true>(d_in, d_out, d_ws, stream);
    } else {
        run_all<false>(d_in, d_out, d_ws, stream);               // atomic fallback
    }
}

// Round 5
// 1111.500 us; speedup vs baseline: 4.3898x; 1.3238x over previous
//
#include <hip/hip_runtime.h>

#define NRUNS 4
#define NAU 50000
#define NPP 100000
#define NEDGE 500000
#define HD 128
#define INV_KEEP 1.25f
#define BN_EPS 1e-5f
#define LDA 136   // padded LDS row (bf16 elems), 272B, keeps 16B alignment

#define M_PROJ 0
#define M_GIN1 1
#define M_GIN2 2

typedef unsigned short bf16r;
typedef __attribute__((ext_vector_type(8))) short v8s;   // 8 bf16 (4 VGPR)
typedef __attribute__((ext_vector_type(4))) float v4f;   // 4 f32 acc

__device__ inline float bf2f(bf16r u) {
    return __uint_as_float(((unsigned)u) << 16);
}
__device__ inline bf16r f2bf(float f) {
    unsigned x = __float_as_uint(f);
    return (bf16r)((x + 0x7fffu + ((x >> 16) & 1u)) >> 16);  // RNE
}

// grid-stride float4 zero fill
__global__ __launch_bounds__(256)
void zero_k(float* p, long n4) {
    long i = (long)blockIdx.x * 256 + threadIdx.x;
    long stride = (long)gridDim.x * 256;
    float4 z = make_float4(0.f, 0.f, 0.f, 0.f);
    for (; i < n4; i += stride) ((float4*)p)[i] = z;
}

// ============ weight convert: f32 [k][n] -> bf16 transposed [n][k] ============
// tables: 0=lin_a, 1=lin_p, 2..5=W1[0..3], 6..9=W2[0..3]
__global__ __launch_bounds__(256)
void convw_k(const float* __restrict__ lin_a_w, const float* __restrict__ lin_p_w,
             const float* __restrict__ W1, const float* __restrict__ W2,
             bf16r* __restrict__ wt)
{
    int t = blockIdx.x >> 6;
    int e = (blockIdx.x & 63) * 256 + threadIdx.x;   // 0..16383
    const float* src;
    if (t == 0) src = lin_a_w;
    else if (t == 1) src = lin_p_w;
    else if (t < 6) src = W1 + (size_t)(t - 2) * HD * HD;
    else src = W2 + (size_t)(t - 6) * HD * HD;
    int n = e >> 7, k = e & 127;
    wt[(size_t)t * HD * HD + e] = f2bf(src[(size_t)k * HD + n]);
}

// ================= CSR build (counting sort by dst) =================
__global__ __launch_bounds__(256)
void count_k(const int* __restrict__ ei, int E, int* cnt) {
    int e = blockIdx.x * 256 + threadIdx.x;
    if (e < E) atomicAdd(&cnt[ei[E + e]], 1);
}

__global__ __launch_bounds__(256)
void scan1_k(const int* __restrict__ in, int* out, int* partial, int n) {
    __shared__ int lds[256];
    int b = blockIdx.x, t = threadIdx.x;
    int base = b * 1024 + t * 4;
    int v0 = 0, v1 = 0, v2 = 0, v3 = 0;
    if (base + 3 < n) {
        int4 x = *(const int4*)(in + base);
        v0 = x.x; v1 = x.y; v2 = x.z; v3 = x.w;
    } else {
        if (base + 0 < n) v0 = in[base + 0];
        if (base + 1 < n) v1 = in[base + 1];
        if (base + 2 < n) v2 = in[base + 2];
        if (base + 3 < n) v3 = in[base + 3];
    }
    int s = v0 + v1 + v2 + v3;
    lds[t] = s;
    __syncthreads();
    for (int d = 1; d < 256; d <<= 1) {
        int x = (t >= d) ? lds[t - d] : 0;
        __syncthreads();
        lds[t] += x;
        __syncthreads();
    }
    int excl = lds[t] - s;
    if (base + 0 < n) out[base + 0] = excl;
    if (base + 1 < n) out[base + 1] = excl + v0;
    if (base + 2 < n) out[base + 2] = excl + v0 + v1;
    if (base + 3 < n) out[base + 3] = excl + v0 + v1 + v2;
    if (t == 255) partial[b] = lds[255];
}

__global__ __launch_bounds__(256)
void scan2_k(int* partial, int n) {
    __shared__ int lds[256];
    int t = threadIdx.x;
    int s = (t < n) ? partial[t] : 0;
    lds[t] = s;
    __syncthreads();
    for (int d = 1; d < 256; d <<= 1) {
        int x = (t >= d) ? lds[t - d] : 0;
        __syncthreads();
        lds[t] += x;
        __syncthreads();
    }
    if (t < n) partial[t] = lds[t] - s;
}

__global__ __launch_bounds__(256)
void scan3_k(int* off, int* cur, const int* __restrict__ partial, int n, int total) {
    int b = blockIdx.x, t = threadIdx.x;
    int add = partial[b];
    int base = b * 1024 + t * 4;
    #pragma unroll
    for (int j = 0; j < 4; ++j) {
        int i = base + j;
        if (i < n) {
            int v = off[i] + add;
            off[i] = v;
            cur[i] = v;
        }
    }
    if (b == 0 && t == 0) off[n] = total;
}

__global__ __launch_bounds__(256)
void fill_k(const int* __restrict__ ei, int E, int* cur, int* bucket) {
    int e = blockIdx.x * 256 + threadIdx.x;
    if (e < E) {
        int d = ei[E + e];
        int p = atomicAdd(&cur[d], 1);
        bucket[p] = ei[e];
    }
}

// gather: one 64-lane wave per dst node; lane owns 2 columns
__global__ __launch_bounds__(256)
void gather_k(const bf16r* __restrict__ src, float* __restrict__ agg,
              const int* __restrict__ off, const int* __restrict__ bucket, int Nn)
{
    int w = (blockIdx.x * 256 + threadIdx.x) >> 6;
    int lane = threadIdx.x & 63;
    if (w >= Nn) return;
    int s0 = off[w], s1 = off[w + 1];
    float a0 = 0.f, a1 = 0.f;
    int e = s0;
    for (; e + 1 < s1; e += 2) {
        int i0 = bucket[e], i1 = bucket[e + 1];
        ushort2 u = *(const ushort2*)(src + (size_t)i0 * HD + lane * 2);
        ushort2 v = *(const ushort2*)(src + (size_t)i1 * HD + lane * 2);
        a0 += bf2f(u.x) + bf2f(v.x);
        a1 += bf2f(u.y) + bf2f(v.y);
    }
    if (e < s1) {
        ushort2 u = *(const ushort2*)(src + (size_t)bucket[e] * HD + lane * 2);
        a0 += bf2f(u.x);
        a1 += bf2f(u.y);
    }
    *(float2*)(agg + (size_t)w * HD + lane * 2) = make_float2(a0, a1);
}

// fallback scatter (atomics) for tight workspaces
__global__ __launch_bounds__(256)
void scatter_k(const bf16r* __restrict__ src, float* dst,
               const int* __restrict__ ei, int E)
{
    int g = blockIdx.x * 256 + threadIdx.x;
    int e = g >> 5, lane = g & 31;
    if (e >= E) return;
    int s = ei[e], d = ei[E + e];
    ushort4 u = *(const ushort4*)(src + (size_t)s * HD + lane * 4);
    float* dp = dst + (size_t)d * HD + lane * 4;
    unsafeAtomicAdd(dp + 0, bf2f(u.x));
    unsafeAtomicAdd(dp + 1, bf2f(u.y));
    unsafeAtomicAdd(dp + 2, bf2f(u.z));
    unsafeAtomicAdd(dp + 3, bf2f(u.w));
}

// ================= MFMA GEMM =================
// 64-row tile x 128 cols x K=128. 4 waves; wave wid owns a 32-col band
// (2 col-frags) x all 64 rows (4 row-frags). Weight fragments loaded ONCE
// into registers (8 x v8s = 32 VGPR); inner loop is ds_read + MFMA only.
// SWAPPED operands: mfma(w_frag, h_frag) -> D[wcol][hrow]: lane&15 = hrow,
// (lane>>4)*4+reg = 4 CONSECUTIVE out cols -> ushort4 stores.
template<int MODE, typename IT>
__global__ __launch_bounds__(256)
void mfma_gemm(const IT* __restrict__ in, const bf16r* __restrict__ Wt,
               const float* __restrict__ bias, bf16r* __restrict__ out,
               int M, int Nn,
               const float* __restrict__ agg, const float* __restrict__ epsp,
               float* gsum, float* gsumsq,
               const float* __restrict__ scale, const float* __restrict__ shift,
               const float* __restrict__ mask)
{
    __shared__ bf16r za[64][LDA];
    __shared__ float red[2][HD];
    const int tid = threadIdx.x;
    const int m0 = blockIdx.x * 64;

    float epsv = 1.0f;
    if (MODE == M_GIN1) epsv = 1.0f + epsp[0];

    // ---- stage A tile (64x128 bf16), fused transform ----
    #pragma unroll
    for (int i = 0; i < 4; ++i) {
        int c = tid + 256 * i;                 // chunk 0..1023
        int row = c >> 4, col = (c & 15) * 8;
        int gr = m0 + row;
        float v[8];
        if (gr < M) {
            if constexpr (sizeof(IT) == 4) {   // f32 input (PROJ)
                float4 u0 = *(const float4*)((const float*)in + (size_t)gr * HD + col);
                float4 u1 = *(const float4*)((const float*)in + (size_t)gr * HD + col + 4);
                v[0] = u0.x; v[1] = u0.y; v[2] = u0.z; v[3] = u0.w;
                v[4] = u1.x; v[5] = u1.y; v[6] = u1.z; v[7] = u1.w;
            } else {                           // bf16 input
                ushort4 u0 = *(const ushort4*)((const bf16r*)in + (size_t)gr * HD + col);
                ushort4 u1 = *(const ushort4*)((const bf16r*)in + (size_t)gr * HD + col + 4);
                v[0] = bf2f(u0.x); v[1] = bf2f(u0.y); v[2] = bf2f(u0.z); v[3] = bf2f(u0.w);
                v[4] = bf2f(u1.x); v[5] = bf2f(u1.y); v[6] = bf2f(u1.z); v[7] = bf2f(u1.w);
            }
            if (MODE == M_GIN1) {
                #pragma unroll
                for (int j = 0; j < 8; ++j) v[j] *= epsv;
                if (gr < Nn) {
                    float4 a0 = *(const float4*)(agg + (size_t)gr * HD + col);
                    float4 a1 = *(const float4*)(agg + (size_t)gr * HD + col + 4);
                    v[0] += a0.x; v[1] += a0.y; v[2] += a0.z; v[3] += a0.w;
                    v[4] += a1.x; v[5] += a1.y; v[6] += a1.z; v[7] += a1.w;
                }
            } else if (MODE == M_GIN2) {
                float4 sc0 = *(const float4*)(scale + col);
                float4 sc1 = *(const float4*)(scale + col + 4);
                float4 sh0 = *(const float4*)(shift + col);
                float4 sh1 = *(const float4*)(shift + col + 4);
                v[0] = fmaxf(v[0] * sc0.x + sh0.x, 0.f);
                v[1] = fmaxf(v[1] * sc0.y + sh0.y, 0.f);
                v[2] = fmaxf(v[2] * sc0.z + sh0.z, 0.f);
                v[3] = fmaxf(v[3] * sc0.w + sh0.w, 0.f);
                v[4] = fmaxf(v[4] * sc1.x + sh1.x, 0.f);
                v[5] = fmaxf(v[5] * sc1.y + sh1.y, 0.f);
                v[6] = fmaxf(v[6] * sc1.z + sh1.z, 0.f);
                v[7] = fmaxf(v[7] * sc1.w + sh1.w, 0.f);
            }
        } else {
            #pragma unroll
            for (int j = 0; j < 8; ++j) v[j] = 0.f;
        }
        ushort4 o0, o1;
        o0.x = f2bf(v[0]); o0.y = f2bf(v[1]); o0.z = f2bf(v[2]); o0.w = f2bf(v[3]);
        o1.x = f2bf(v[4]); o1.y = f2bf(v[5]); o1.z = f2bf(v[6]); o1.w = f2bf(v[7]);
        *(ushort4*)&za[row][col] = o0;
        *(ushort4*)&za[row][col + 4] = o1;
    }
    __syncthreads();

    // ---- MFMA compute ----
    const int wid = tid >> 6, lane = tid & 63;
    const int lr = lane & 15;          // hrow within frag / Wt row selector
    const int lk = (lane >> 4) * 8;    // k offset within 32-wide k-step
    const int colq = (lane >> 4) * 4;  // out-col quad base within 16-col frag
    const int cb = wid * 32;           // wave's column band

    // weights reg-resident: 2 col-frags x 4 k-steps
    v8s w[2][4];
    #pragma unroll
    for (int cf = 0; cf < 2; ++cf)
        #pragma unroll
        for (int ks = 0; ks < 4; ++ks)
            w[cf][ks] = *(const v8s*)(Wt + (size_t)(cb + cf * 16 + lr) * HD + ks * 32 + lk);

    v4f acc[2][4];
    #pragma unroll
    for (int cf = 0; cf < 2; ++cf)
        #pragma unroll
        for (int rf = 0; rf < 4; ++rf) acc[cf][rf] = (v4f){0.f, 0.f, 0.f, 0.f};

    #pragma unroll
    for (int ks = 0; ks < 4; ++ks)
        #pragma unroll
        for (int rf = 0; rf < 4; ++rf) {
            v8s a = *(const v8s*)&za[rf * 16 + lr][ks * 32 + lk];
            acc[0][rf] = __builtin_amdgcn_mfma_f32_16x16x32_bf16(w[0][ks], a, acc[0][rf], 0, 0, 0);
            acc[1][rf] = __builtin_amdgcn_mfma_f32_16x16x32_bf16(w[1][ks], a, acc[1][rf], 0, 0, 0);
        }

    // bias: 4 consecutive cols per lane per cf
    #pragma unroll
    for (int cf = 0; cf < 2; ++cf) {
        float4 bb = *(const float4*)(bias + cb + cf * 16 + colq);
        #pragma unroll
        for (int rf = 0; rf < 4; ++rf) {
            acc[cf][rf][0] += bb.x;
            acc[cf][rf][1] += bb.y;
            acc[cf][rf][2] += bb.z;
            acc[cf][rf][3] += bb.w;
        }
    }

    // ---- epilogue (vectorized ushort4 stores) ----
    if (MODE == M_PROJ) {
        #pragma unroll
        for (int rf = 0; rf < 4; ++rf) {
            int grow = m0 + rf * 16 + lr;
            if (grow < M) {
                #pragma unroll
                for (int run = 0; run < NRUNS; ++run) {
                    float wm = mask[(size_t)run * Nn + grow] * INV_KEEP;
                    #pragma unroll
                    for (int cf = 0; cf < 2; ++cf) {
                        ushort4 o;
                        o.x = f2bf(acc[cf][rf][0] * wm);
                        o.y = f2bf(acc[cf][rf][1] * wm);
                        o.z = f2bf(acc[cf][rf][2] * wm);
                        o.w = f2bf(acc[cf][rf][3] * wm);
                        *(ushort4*)(out + ((size_t)run * Nn + grow) * HD + cb + cf * 16 + colq) = o;
                    }
                }
            }
        }
    } else if (MODE == M_GIN1) {
        #pragma unroll
        for (int rf = 0; rf < 4; ++rf) {
            int grow = m0 + rf * 16 + lr;
            #pragma unroll
            for (int cf = 0; cf < 2; ++cf) {
                ushort4 o;
                o.x = f2bf(acc[cf][rf][0]);
                o.y = f2bf(acc[cf][rf][1]);
                o.z = f2bf(acc[cf][rf][2]);
                o.w = f2bf(acc[cf][rf][3]);
                *(ushort4*)(out + (size_t)grow * HD + cb + cf * 16 + colq) = o;
            }
        }
        // per-column stats: lane holds 4 cols x 4 row-frags
        #pragma unroll
        for (int cf = 0; cf < 2; ++cf) {
            float s[4], q[4];
            #pragma unroll
            for (int j = 0; j < 4; ++j) {
                float ss = 0.f, qq = 0.f;
                #pragma unroll
                for (int rf = 0; rf < 4; ++rf) {
                    float v = acc[cf][rf][j];
                    ss += v;
                    qq += v * v;
                }
                s[j] = ss;
                q[j] = qq;
            }
            #pragma unroll
            for (int d = 1; d < 16; d <<= 1) {
                #pragma unroll
                for (int j = 0; j < 4; ++j) {
                    s[j] += __shfl_xor(s[j], d);
                    q[j] += __shfl_xor(q[j], d);
                }
            }
            if (lr == 0) {
                #pragma unroll
                for (int j = 0; j < 4; ++j) {
                    red[0][cb + cf * 16 + colq + j] = s[j];
                    red[1][cb + cf * 16 + colq + j] = q[j];
                }
            }
        }
        __syncthreads();
        if (tid < HD) {
            unsafeAtomicAdd(gsum + tid, red[0][tid]);
            unsafeAtomicAdd(gsumsq + tid, red[1][tid]);
        }
    } else {  // M_GIN2
        #pragma unroll
        for (int rf = 0; rf < 4; ++rf) {
            int grow = m0 + rf * 16 + lr;
            #pragma unroll
            for (int cf = 0; cf < 2; ++cf) {
                ushort4 o;
                o.x = f2bf(fmaxf(acc[cf][rf][0], 0.f));
                o.y = f2bf(fmaxf(acc[cf][rf][1], 0.f));
                o.z = f2bf(fmaxf(acc[cf][rf][2], 0.f));
                o.w = f2bf(fmaxf(acc[cf][rf][3], 0.f));
                *(ushort4*)(out + (size_t)grow * HD + cb + cf * 16 + colq) = o;
            }
        }
    }
}

// BN stats -> scale/shift; re-zeros accumulators (deterministic replay)
__global__ void finalize_k(float* gsum, float* gsumsq,
                           const float* __restrict__ gamma,
                           const float* __restrict__ beta,
                           float* scale, float* shift, float invN)
{
    int c = threadIdx.x;
    float mu = gsum[c] * invN;
    float var = gsumsq[c] * invN - mu * mu;
    float sc = gamma[c] * rsqrtf(var + BN_EPS);
    scale[c] = sc;
    shift[c] = beta[c] - mu * sc;
    gsum[c] = 0.f;
    gsumsq[c] = 0.f;
}

// mean over runs + [128]x[128,4] matmul; one wave per author node
__global__ __launch_bounds__(256)
void final_k(const bf16r* __restrict__ ha, const float* __restrict__ fw,
             const float* __restrict__ fb, float* __restrict__ out)
{
    int g = blockIdx.x * 256 + threadIdx.x;
    int node = g >> 6, lane = g & 63;
    if (node >= NAU) return;
    float m0 = 0.f, m1 = 0.f;
    #pragma unroll
    for (int r = 0; r < NRUNS; ++r) {
        size_t base = ((size_t)r * NAU + node) * HD;
        m0 += bf2f(ha[base + lane]);
        m1 += bf2f(ha[base + 64 + lane]);
    }
    m0 *= 0.25f;
    m1 *= 0.25f;
    float p[4];
    #pragma unroll
    for (int c = 0; c < 4; ++c)
        p[c] = m0 * fw[lane * 4 + c] + m1 * fw[(lane + 64) * 4 + c];
    #pragma unroll
    for (int off = 32; off >= 1; off >>= 1)
        #pragma unroll
        for (int c = 0; c < 4; ++c) p[c] += __shfl_down(p[c], off);
    if (lane == 0) {
        #pragma unroll
        for (int c = 0; c < 4; ++c) out[(size_t)node * 4 + c] = p[c] + fb[c];
    }
}

#define CSR_INTS ((size_t)(NPP + 4) + NEDGE + (NAU + 4) + NEDGE)
#define WT_ELEMS ((size_t)10 * HD * HD)

template<bool GATHER>
static void run_all(void* const* d_in, void* d_out, void* d_ws, hipStream_t stream)
{
    const float* x_author = (const float*)d_in[0];
    const float* x_paper  = (const float*)d_in[1];
    const int*   ei_ap    = (const int*)d_in[2];
    const int*   ei_pa    = (const int*)d_in[3];
    const float* drop_a   = (const float*)d_in[4];
    const float* drop_p   = (const float*)d_in[5];
    const float* lin_a_w  = (const float*)d_in[6];
    const float* lin_a_b  = (const float*)d_in[7];
    const float* lin_p_w  = (const float*)d_in[8];
    const float* lin_p_b  = (const float*)d_in[9];
    const float* W1       = (const float*)d_in[10];
    const float* B1       = (const float*)d_in[11];
    const float* G        = (const float*)d_in[12];
    const float* BT       = (const float*)d_in[13];
    const float* W2       = (const float*)d_in[14];
    const float* B2       = (const float*)d_in[15];
    const float* EPS      = (const float*)d_in[16];
    const float* fw       = (const float*)d_in[17];
    const float* fb       = (const float*)d_in[18];

    // ws: [stats 512 f32][Wt 10x16384 bf16][CSR][agg_a][agg_p][h_a][h_p]
    float* gsum   = (float*)d_ws;
    float* gsumsq = gsum + HD;
    float* scalev = gsumsq + HD;
    float* shiftv = scalev + HD;
    bf16r* wt = (bf16r*)(shiftv + HD);
    int* ip = (int*)(wt + WT_ELEMS);

    int *off_ap = nullptr, *bkt_ap = nullptr, *off_pa = nullptr, *bkt_pa = nullptr;
    if (GATHER) {
        off_ap = ip;  ip += NPP + 4;
        bkt_ap = ip;  ip += NEDGE;
        off_pa = ip;  ip += NAU + 4;
        bkt_pa = ip;  ip += NEDGE;
    }
    float* agg_a = (float*)ip;
    float* agg_p = agg_a + (size_t)NAU * HD;
    bf16r* h_a = (bf16r*)(agg_p + (size_t)NPP * HD);
    bf16r* h_p = h_a + (size_t)NRUNS * NAU * HD;

    const bf16r* wt_lin_a = wt;
    const bf16r* wt_lin_p = wt + (size_t)1 * HD * HD;
    const bf16r* wt_W1    = wt + (size_t)2 * HD * HD;
    const bf16r* wt_W2    = wt + (size_t)6 * HD * HD;

    convw_k<<<640, 256, 0, stream>>>(lin_a_w, lin_p_w, W1, W2, wt);
    zero_k<<<1, 256, 0, stream>>>(gsum, (4 * HD) / 4);

    if (GATHER) {
        int* cur_ap  = (int*)agg_a;
        int* cur_pa  = cur_ap + NPP;
        int* partial = cur_pa + NAU;
        {
            int nchunk = (NPP + 1023) / 1024;
            zero_k<<<64, 256, 0, stream>>>((float*)cur_ap, NPP / 4);
            count_k<<<(NEDGE + 255) / 256, 256, 0, stream>>>(ei_ap, NEDGE, cur_ap);
            scan1_k<<<nchunk, 256, 0, stream>>>(cur_ap, off_ap, partial, NPP);
            scan2_k<<<1, 256, 0, stream>>>(partial, nchunk);
            scan3_k<<<nchunk, 256, 0, stream>>>(off_ap, cur_ap, partial, NPP, NEDGE);
            fill_k<<<(NEDGE + 255) / 256, 256, 0, stream>>>(ei_ap, NEDGE, cur_ap, bkt_ap);
        }
        {
            int nchunk = (NAU + 1023) / 1024;
            zero_k<<<64, 256, 0, stream>>>((float*)cur_pa, NAU / 4);
            count_k<<<(NEDGE + 255) / 256, 256, 0, stream>>>(ei_pa, NEDGE, cur_pa);
            scan1_k<<<nchunk, 256, 0, stream>>>(cur_pa, off_pa, partial, NAU);
            scan2_k<<<1, 256, 0, stream>>>(partial, nchunk);
            scan3_k<<<nchunk, 256, 0, stream>>>(off_pa, cur_pa, partial, NAU, NEDGE);
            fill_k<<<(NEDGE + 255) / 256, 256, 0, stream>>>(ei_pa, NEDGE, cur_pa, bkt_pa);
        }
    }

    // input projections + dropout expansion
    mfma_gemm<M_PROJ, float><<<(NAU + 63) / 64, 256, 0, stream>>>(
        x_author, wt_lin_a, lin_a_b, h_a, NAU, NAU,
        nullptr, nullptr, nullptr, nullptr, nullptr, nullptr, drop_a);
    mfma_gemm<M_PROJ, float><<<(NPP + 63) / 64, 256, 0, stream>>>(
        x_paper, wt_lin_p, lin_p_b, h_p, NPP, NPP,
        nullptr, nullptr, nullptr, nullptr, nullptr, nullptr, drop_p);

    for (int l = 0; l < 2; ++l) {
        int t0 = l * 2 + 0, t1 = l * 2 + 1;

        if (GATHER) {
            gather_k<<<(NPP * 64) / 256, 256, 0, stream>>>(h_a, agg_p, off_ap, bkt_ap, NPP);
            gather_k<<<(NAU * 64) / 256, 256, 0, stream>>>(h_p, agg_a, off_pa, bkt_pa, NAU);
        } else {
            zero_k<<<2048, 256, 0, stream>>>(agg_a, ((size_t)(NAU + NPP) * HD) / 4);
            scatter_k<<<(NEDGE * 32) / 256, 256, 0, stream>>>(h_a, agg_p, ei_ap, NEDGE);
            scatter_k<<<(NEDGE * 32) / 256, 256, 0, stream>>>(h_p, agg_a, ei_pa, NEDGE);
        }

        // paper GIN (params [l,0]) — in place on h_p
        mfma_gemm<M_GIN1, bf16r><<<NRUNS * NPP / 64, 256, 0, stream>>>(
            h_p, wt_W1 + (size_t)t0 * HD * HD, B1 + (size_t)t0 * HD, h_p,
            NRUNS * NPP, NPP, agg_p, EPS + t0, gsum, gsumsq,
            nullptr, nullptr, nullptr);
        finalize_k<<<1, HD, 0, stream>>>(gsum, gsumsq, G + (size_t)t0 * HD,
                                         BT + (size_t)t0 * HD, scalev, shiftv,
                                         1.0f / (NRUNS * NPP));
        mfma_gemm<M_GIN2, bf16r><<<NRUNS * NPP / 64, 256, 0, stream>>>(
            h_p, wt_W2 + (size_t)t0 * HD * HD, B2 + (size_t)t0 * HD, h_p,
            NRUNS * NPP, NPP, nullptr, nullptr, nullptr, nullptr,
            scalev, shiftv, nullptr);

        // author GIN (params [l,1]) — in place on h_a
        mfma_gemm<M_GIN1, bf16r><<<NRUNS * NAU / 64, 256, 0, stream>>>(
            h_a, wt_W1 + (size_t)t1 * HD * HD, B1 + (size_t)t1 * HD, h_a,
            NRUNS * NAU, NAU, agg_a, EPS + t1, gsum, gsumsq,
            nullptr, nullptr, nullptr);
        finalize_k<<<1, HD, 0, stream>>>(gsum, gsumsq, G + (size_t)t1 * HD,
                                         BT + (size_t)t1 * HD, scalev, shiftv,
                                         1.0f / (NRUNS * NAU));
        mfma_gemm<M_GIN2, bf16r><<<NRUNS * NAU / 64, 256, 0, stream>>>(
            h_a, wt_W2 + (size_t)t1 * HD * HD, B2 + (size_t)t1 * HD, h_a,
            NRUNS * NAU, NAU, nullptr, nullptr, nullptr, nullptr,
            scalev, shiftv, nullptr);
    }

    final_k<<<(NAU * 64) / 256, 256, 0, stream>>>(h_a, fw, fb, (float*)d_out);
}

extern "C" void kernel_launch(void* const* d_in, const int* in_sizes, int n_in,
                              void* d_out, int out_size, void* d_ws, size_t ws_size,
                              hipStream_t stream)
{
    const size_t hB    = (size_t)NRUNS * (NAU + NPP) * HD * sizeof(bf16r);
    const size_t aggB  = (size_t)(NAU + NPP) * HD * sizeof(float);
    const size_t statB = 4 * HD * sizeof(float);
    const size_t wtB   = WT_ELEMS * sizeof(bf16r);
    const size_t csrB  = CSR_INTS * sizeof(int);

    const size_t need_gather = statB + wtB + csrB + aggB + hB;   // ~235.4 MB
    if (ws_size >= need_gather) {
        run_all<true>(d_in, d_out, d_ws, stream);
    } else {
        run_all<false>(d_in, d_out, d_ws, stream);               // atomic fallback
    }
}

// Round 6
// 709.449 us; speedup vs baseline: 6.8776x; 1.5667x over previous
//
#include <hip/hip_runtime.h>

#define NRUNS 4
#define NAU 50000
#define NPP 100000
#define NEDGE 500000
#define HD 128
#define INV_KEEP 1.25f
#define BN_EPS 1e-5f
#define LDA 136      // padded LDS row (bf16 elems), 272B
#define NB_GEMM 1024 // persistent GEMM grid (4 blocks/CU, LDS-limited)

#define M_PROJ 0
#define M_GIN1 1
#define M_GIN2 2

typedef unsigned short bf16r;
typedef __attribute__((ext_vector_type(8))) short v8s;   // 8 bf16 (4 VGPR)
typedef __attribute__((ext_vector_type(4))) float v4f;   // 4 f32 acc

__device__ inline float bf2f(bf16r u) {
    return __uint_as_float(((unsigned)u) << 16);
}
__device__ inline bf16r f2bf(float f) {
    unsigned x = __float_as_uint(f);
    return (bf16r)((x + 0x7fffu + ((x >> 16) & 1u)) >> 16);  // RNE
}

// grid-stride float4 zero fill
__global__ __launch_bounds__(256)
void zero_k(float* p, long n4) {
    long i = (long)blockIdx.x * 256 + threadIdx.x;
    long stride = (long)gridDim.x * 256;
    float4 z = make_float4(0.f, 0.f, 0.f, 0.f);
    for (; i < n4; i += stride) ((float4*)p)[i] = z;
}

// ============ weight convert: f32 [k][n] -> bf16 transposed [n][k] ============
__global__ __launch_bounds__(256)
void convw_k(const float* __restrict__ lin_a_w, const float* __restrict__ lin_p_w,
             const float* __restrict__ W1, const float* __restrict__ W2,
             bf16r* __restrict__ wt)
{
    int t = blockIdx.x >> 6;
    int e = (blockIdx.x & 63) * 256 + threadIdx.x;   // 0..16383
    const float* src;
    if (t == 0) src = lin_a_w;
    else if (t == 1) src = lin_p_w;
    else if (t < 6) src = W1 + (size_t)(t - 2) * HD * HD;
    else src = W2 + (size_t)(t - 6) * HD * HD;
    int n = e >> 7, k = e & 127;
    wt[(size_t)t * HD * HD + e] = f2bf(src[(size_t)k * HD + n]);
}

// ================= CSR build (counting sort by dst) =================
__global__ __launch_bounds__(256)
void count_k(const int* __restrict__ ei, int E, int* cnt) {
    int e = blockIdx.x * 256 + threadIdx.x;
    if (e < E) atomicAdd(&cnt[ei[E + e]], 1);
}

__global__ __launch_bounds__(256)
void scan1_k(const int* __restrict__ in, int* out, int* partial, int n) {
    __shared__ int lds[256];
    int b = blockIdx.x, t = threadIdx.x;
    int base = b * 1024 + t * 4;
    int v0 = 0, v1 = 0, v2 = 0, v3 = 0;
    if (base + 3 < n) {
        int4 x = *(const int4*)(in + base);
        v0 = x.x; v1 = x.y; v2 = x.z; v3 = x.w;
    } else {
        if (base + 0 < n) v0 = in[base + 0];
        if (base + 1 < n) v1 = in[base + 1];
        if (base + 2 < n) v2 = in[base + 2];
        if (base + 3 < n) v3 = in[base + 3];
    }
    int s = v0 + v1 + v2 + v3;
    lds[t] = s;
    __syncthreads();
    for (int d = 1; d < 256; d <<= 1) {
        int x = (t >= d) ? lds[t - d] : 0;
        __syncthreads();
        lds[t] += x;
        __syncthreads();
    }
    int excl = lds[t] - s;
    if (base + 0 < n) out[base + 0] = excl;
    if (base + 1 < n) out[base + 1] = excl + v0;
    if (base + 2 < n) out[base + 2] = excl + v0 + v1;
    if (base + 3 < n) out[base + 3] = excl + v0 + v1 + v2;
    if (t == 255) partial[b] = lds[255];
}

__global__ __launch_bounds__(256)
void scan2_k(int* partial, int n) {
    __shared__ int lds[256];
    int t = threadIdx.x;
    int s = (t < n) ? partial[t] : 0;
    lds[t] = s;
    __syncthreads();
    for (int d = 1; d < 256; d <<= 1) {
        int x = (t >= d) ? lds[t - d] : 0;
        __syncthreads();
        lds[t] += x;
        __syncthreads();
    }
    if (t < n) partial[t] = lds[t] - s;
}

__global__ __launch_bounds__(256)
void scan3_k(int* off, int* cur, const int* __restrict__ partial, int n, int total) {
    int b = blockIdx.x, t = threadIdx.x;
    int add = partial[b];
    int base = b * 1024 + t * 4;
    #pragma unroll
    for (int j = 0; j < 4; ++j) {
        int i = base + j;
        if (i < n) {
            int v = off[i] + add;
            off[i] = v;
            cur[i] = v;
        }
    }
    if (b == 0 && t == 0) off[n] = total;
}

__global__ __launch_bounds__(256)
void fill_k(const int* __restrict__ ei, int E, int* cur, int* bucket) {
    int e = blockIdx.x * 256 + threadIdx.x;
    if (e < E) {
        int d = ei[E + e];
        int p = atomicAdd(&cur[d], 1);
        bucket[p] = ei[e];
    }
}

// combined gather for both graphs: wave w<NPP gathers h_a->agg_p via CSR(ap);
// else h_p->agg_a via CSR(pa). agg row written exactly once.
__global__ __launch_bounds__(256)
void gather2_k(const bf16r* __restrict__ hA, const bf16r* __restrict__ hP,
               float* __restrict__ aggP, float* __restrict__ aggA,
               const int* __restrict__ offAP, const int* __restrict__ bktAP,
               const int* __restrict__ offPA, const int* __restrict__ bktPA)
{
    int gw = (blockIdx.x * 256 + threadIdx.x) >> 6;
    int lane = threadIdx.x & 63;
    const bf16r* src; float* agg; const int* off; const int* bkt; int w;
    if (gw < NPP) { src = hA; agg = aggP; off = offAP; bkt = bktAP; w = gw; }
    else          { src = hP; agg = aggA; off = offPA; bkt = bktPA; w = gw - NPP; }
    int s0 = off[w], s1 = off[w + 1];
    float a0 = 0.f, a1 = 0.f;
    int e = s0;
    for (; e + 1 < s1; e += 2) {
        int i0 = bkt[e], i1 = bkt[e + 1];
        ushort2 u = *(const ushort2*)(src + (size_t)i0 * HD + lane * 2);
        ushort2 v = *(const ushort2*)(src + (size_t)i1 * HD + lane * 2);
        a0 += bf2f(u.x) + bf2f(v.x);
        a1 += bf2f(u.y) + bf2f(v.y);
    }
    if (e < s1) {
        ushort2 u = *(const ushort2*)(src + (size_t)bkt[e] * HD + lane * 2);
        a0 += bf2f(u.x);
        a1 += bf2f(u.y);
    }
    *(float2*)(agg + (size_t)w * HD + lane * 2) = make_float2(a0, a1);
}

// fallback scatter (atomics) for tight workspaces
__global__ __launch_bounds__(256)
void scatter_k(const bf16r* __restrict__ src, float* dst,
               const int* __restrict__ ei, int E)
{
    int g = blockIdx.x * 256 + threadIdx.x;
    int e = g >> 5, lane = g & 31;
    if (e >= E) return;
    int s = ei[e], d = ei[E + e];
    ushort4 u = *(const ushort4*)(src + (size_t)s * HD + lane * 4);
    float* dp = dst + (size_t)d * HD + lane * 4;
    unsafeAtomicAdd(dp + 0, bf2f(u.x));
    unsafeAtomicAdd(dp + 1, bf2f(u.y));
    unsafeAtomicAdd(dp + 2, bf2f(u.z));
    unsafeAtomicAdd(dp + 3, bf2f(u.w));
}

// ================= persistent pipelined MFMA GEMM =================
struct SideP {
    const void* in;
    bf16r* out;
    const bf16r* wt;
    const float* bias;
    const float* agg;
    const float* epsp;
    float* gsum;
    float* gsumsq;
    const float* scale;
    const float* shift;
    const float* mask;
    int M, Nn, tiles;
};

// Two sides (paper tiles on blocks [0,BP), author on [BP,NB_GEMM)).
// Per block: weights reg-resident once; loop over tiles with double-buffered
// LDS A-tile and 2-phase pipeline: stage(cur) / barrier / prefetch(next)->regs
// / compute(cur). Prefetch issued AFTER the barrier so the compiler's
// vmcnt(0)-at-barrier drain never waits on it; HBM latency hides under MFMA +
// epilogue. GIN1 stats accumulate in registers across tiles; one atomic pass
// per block at the end.
template<int MODE, typename IT>
__global__ __launch_bounds__(256)
void mfma_gemm(SideP P, SideP A, int BP)
{
    __shared__ bf16r za[2][64][LDA];
    __shared__ float red[2][HD];
    const int tid = threadIdx.x;

    SideP S;
    int t, tstride;
    if ((int)blockIdx.x < BP) { S = P; t = blockIdx.x; tstride = BP; }
    else { S = A; t = (int)blockIdx.x - BP; tstride = NB_GEMM - BP; }
    if (t >= S.tiles) return;   // block-uniform exit

    const int wid = tid >> 6, lane = tid & 63;
    const int lr = lane & 15, lk = (lane >> 4) * 8;
    const int colq = (lane >> 4) * 4, cb = wid * 32;

    float epsv = 1.0f;
    if (MODE == M_GIN1) epsv = 1.0f + S.epsp[0];

    // weights reg-resident (once per block)
    v8s w[2][4];
    #pragma unroll
    for (int cf = 0; cf < 2; ++cf)
        #pragma unroll
        for (int ks = 0; ks < 4; ++ks)
            w[cf][ks] = *(const v8s*)(S.wt + (size_t)(cb + cf * 16 + lr) * HD + ks * 32 + lk);

    const float4 bb0 = *(const float4*)(S.bias + cb + colq);
    const float4 bb1 = *(const float4*)(S.bias + cb + 16 + colq);

    float st_s[2][4], st_q[2][4];
    if (MODE == M_GIN1) {
        #pragma unroll
        for (int cf = 0; cf < 2; ++cf)
            #pragma unroll
            for (int j = 0; j < 4; ++j) { st_s[cf][j] = 0.f; st_q[cf][j] = 0.f; }
    }

    constexpr int NV = (sizeof(IT) == 4) ? 2 : 1;
    int4 pre[4][NV];

    // prefetch first tile
    {
        int m0 = t * 64;
        #pragma unroll
        for (int i = 0; i < 4; ++i) {
            int c = tid + 256 * i, row = c >> 4, col = (c & 15) * 8;
            int gr = m0 + row;
            if (gr < S.M) {
                const int4* p = (const int4*)((const IT*)S.in + (size_t)gr * HD + col);
                pre[i][0] = p[0];
                if constexpr (NV == 2) pre[i][1] = p[1];
            } else {
                pre[i][0] = make_int4(0, 0, 0, 0);
                if constexpr (NV == 2) pre[i][1] = make_int4(0, 0, 0, 0);
            }
        }
    }

    int cur = 0;
    for (;;) {
        const int m0 = t * 64;
        // ---- stage: transform pre -> za[cur] ----
        #pragma unroll
        for (int i = 0; i < 4; ++i) {
            int c = tid + 256 * i, row = c >> 4, col = (c & 15) * 8;
            int gr = m0 + row;
            float v[8];
            if constexpr (NV == 2) {
                const float* pf = (const float*)&pre[i][0];
                #pragma unroll
                for (int j = 0; j < 8; ++j) v[j] = pf[j];
            } else {
                const bf16r* pu = (const bf16r*)&pre[i][0];
                #pragma unroll
                for (int j = 0; j < 8; ++j) v[j] = bf2f(pu[j]);
            }
            if (MODE == M_GIN1) {
                #pragma unroll
                for (int j = 0; j < 8; ++j) v[j] *= epsv;
                if (gr < S.Nn) {
                    float4 a0 = *(const float4*)(S.agg + (size_t)gr * HD + col);
                    float4 a1 = *(const float4*)(S.agg + (size_t)gr * HD + col + 4);
                    v[0] += a0.x; v[1] += a0.y; v[2] += a0.z; v[3] += a0.w;
                    v[4] += a1.x; v[5] += a1.y; v[6] += a1.z; v[7] += a1.w;
                }
            } else if (MODE == M_GIN2) {
                float4 sc0 = *(const float4*)(S.scale + col);
                float4 sc1 = *(const float4*)(S.scale + col + 4);
                float4 sh0 = *(const float4*)(S.shift + col);
                float4 sh1 = *(const float4*)(S.shift + col + 4);
                v[0] = fmaxf(v[0] * sc0.x + sh0.x, 0.f);
                v[1] = fmaxf(v[1] * sc0.y + sh0.y, 0.f);
                v[2] = fmaxf(v[2] * sc0.z + sh0.z, 0.f);
                v[3] = fmaxf(v[3] * sc0.w + sh0.w, 0.f);
                v[4] = fmaxf(v[4] * sc1.x + sh1.x, 0.f);
                v[5] = fmaxf(v[5] * sc1.y + sh1.y, 0.f);
                v[6] = fmaxf(v[6] * sc1.z + sh1.z, 0.f);
                v[7] = fmaxf(v[7] * sc1.w + sh1.w, 0.f);
            }
            ushort4 o0, o1;
            o0.x = f2bf(v[0]); o0.y = f2bf(v[1]); o0.z = f2bf(v[2]); o0.w = f2bf(v[3]);
            o1.x = f2bf(v[4]); o1.y = f2bf(v[5]); o1.z = f2bf(v[6]); o1.w = f2bf(v[7]);
            *(ushort4*)&za[cur][row][col] = o0;
            *(ushort4*)&za[cur][row][col + 4] = o1;
        }
        __syncthreads();

        // ---- prefetch next tile (issued after barrier -> stays in flight) ----
        const int tn = t + tstride;
        const bool more = tn < S.tiles;
        if (more) {
            int m0n = tn * 64;
            #pragma unroll
            for (int i = 0; i < 4; ++i) {
                int c = tid + 256 * i, row = c >> 4, col = (c & 15) * 8;
                int gr = m0n + row;
                if (gr < S.M) {
                    const int4* p = (const int4*)((const IT*)S.in + (size_t)gr * HD + col);
                    pre[i][0] = p[0];
                    if constexpr (NV == 2) pre[i][1] = p[1];
                } else {
                    pre[i][0] = make_int4(0, 0, 0, 0);
                    if constexpr (NV == 2) pre[i][1] = make_int4(0, 0, 0, 0);
                }
            }
        }

        // ---- compute ----
        v4f acc[2][4];
        #pragma unroll
        for (int cf = 0; cf < 2; ++cf)
            #pragma unroll
            for (int rf = 0; rf < 4; ++rf) acc[cf][rf] = (v4f){0.f, 0.f, 0.f, 0.f};

        #pragma unroll
        for (int ks = 0; ks < 4; ++ks)
            #pragma unroll
            for (int rf = 0; rf < 4; ++rf) {
                v8s a = *(const v8s*)&za[cur][rf * 16 + lr][ks * 32 + lk];
                acc[0][rf] = __builtin_amdgcn_mfma_f32_16x16x32_bf16(w[0][ks], a, acc[0][rf], 0, 0, 0);
                acc[1][rf] = __builtin_amdgcn_mfma_f32_16x16x32_bf16(w[1][ks], a, acc[1][rf], 0, 0, 0);
            }

        #pragma unroll
        for (int rf = 0; rf < 4; ++rf) {
            acc[0][rf][0] += bb0.x; acc[0][rf][1] += bb0.y;
            acc[0][rf][2] += bb0.z; acc[0][rf][3] += bb0.w;
            acc[1][rf][0] += bb1.x; acc[1][rf][1] += bb1.y;
            acc[1][rf][2] += bb1.z; acc[1][rf][3] += bb1.w;
        }

        if (MODE == M_PROJ) {
            #pragma unroll
            for (int rf = 0; rf < 4; ++rf) {
                int grow = m0 + rf * 16 + lr;
                if (grow < S.M) {
                    #pragma unroll
                    for (int run = 0; run < NRUNS; ++run) {
                        float wm = S.mask[(size_t)run * S.Nn + grow] * INV_KEEP;
                        #pragma unroll
                        for (int cf = 0; cf < 2; ++cf) {
                            ushort4 o;
                            o.x = f2bf(acc[cf][rf][0] * wm);
                            o.y = f2bf(acc[cf][rf][1] * wm);
                            o.z = f2bf(acc[cf][rf][2] * wm);
                            o.w = f2bf(acc[cf][rf][3] * wm);
                            *(ushort4*)(S.out + ((size_t)run * S.Nn + grow) * HD + cb + cf * 16 + colq) = o;
                        }
                    }
                }
            }
        } else if (MODE == M_GIN1) {
            #pragma unroll
            for (int rf = 0; rf < 4; ++rf) {
                int grow = m0 + rf * 16 + lr;
                #pragma unroll
                for (int cf = 0; cf < 2; ++cf) {
                    ushort4 o;
                    o.x = f2bf(acc[cf][rf][0]);
                    o.y = f2bf(acc[cf][rf][1]);
                    o.z = f2bf(acc[cf][rf][2]);
                    o.w = f2bf(acc[cf][rf][3]);
                    *(ushort4*)(S.out + (size_t)grow * HD + cb + cf * 16 + colq) = o;
                }
            }
            #pragma unroll
            for (int cf = 0; cf < 2; ++cf)
                #pragma unroll
                for (int j = 0; j < 4; ++j) {
                    #pragma unroll
                    for (int rf = 0; rf < 4; ++rf) {
                        float vv = acc[cf][rf][j];
                        st_s[cf][j] += vv;
                        st_q[cf][j] += vv * vv;
                    }
                }
        } else {  // M_GIN2
            #pragma unroll
            for (int rf = 0; rf < 4; ++rf) {
                int grow = m0 + rf * 16 + lr;
                #pragma unroll
                for (int cf = 0; cf < 2; ++cf) {
                    ushort4 o;
                    o.x = f2bf(fmaxf(acc[cf][rf][0], 0.f));
                    o.y = f2bf(fmaxf(acc[cf][rf][1], 0.f));
                    o.z = f2bf(fmaxf(acc[cf][rf][2], 0.f));
                    o.w = f2bf(fmaxf(acc[cf][rf][3], 0.f));
                    *(ushort4*)(S.out + (size_t)grow * HD + cb + cf * 16 + colq) = o;
                }
            }
        }

        if (!more) break;
        t = tn;
        cur ^= 1;
        // single barrier per iteration is sufficient with double buffer:
        // writers of za[cur] at iter k+2 passed the iter-k+1 barrier, by which
        // time readers of the same buffer (iter k) had completed (lgkmcnt).
    }

    if (MODE == M_GIN1) {
        // reduce stats over the 16 lr lanes, then one atomic pass per block
        #pragma unroll
        for (int d = 1; d < 16; d <<= 1)
            #pragma unroll
            for (int cf = 0; cf < 2; ++cf)
                #pragma unroll
                for (int j = 0; j < 4; ++j) {
                    st_s[cf][j] += __shfl_xor(st_s[cf][j], d);
                    st_q[cf][j] += __shfl_xor(st_q[cf][j], d);
                }
        if (lr == 0) {
            #pragma unroll
            for (int cf = 0; cf < 2; ++cf)
                #pragma unroll
                for (int j = 0; j < 4; ++j) {
                    red[0][cb + cf * 16 + colq + j] = st_s[cf][j];
                    red[1][cb + cf * 16 + colq + j] = st_q[cf][j];
                }
        }
        __syncthreads();
        if (tid < HD) {
            unsafeAtomicAdd(S.gsum + tid, red[0][tid]);
            unsafeAtomicAdd(S.gsumsq + tid, red[1][tid]);
        }
    }
}

// BN stats -> scale/shift for BOTH sides; re-zeros accumulators
__global__ void finalize2_k(float* gsP, float* gsqP, const float* gamP, const float* betP,
                            float* scP, float* shP, float invNP,
                            float* gsA, float* gsqA, const float* gamA, const float* betA,
                            float* scA, float* shA, float invNA)
{
    int c = threadIdx.x;
    float *gs, *gsq, *sc, *sh;
    const float *gm, *bt;
    float invN;
    if (c < HD) { gs = gsP; gsq = gsqP; gm = gamP; bt = betP; sc = scP; sh = shP; invN = invNP; }
    else { c -= HD; gs = gsA; gsq = gsqA; gm = gamA; bt = betA; sc = scA; sh = shA; invN = invNA; }
    float mu = gs[c] * invN;
    float var = gsq[c] * invN - mu * mu;
    float s = gm[c] * rsqrtf(var + BN_EPS);
    sc[c] = s;
    sh[c] = bt[c] - mu * s;
    gs[c] = 0.f;
    gsq[c] = 0.f;
}

// mean over runs + [128]x[128,4] matmul; one wave per author node
__global__ __launch_bounds__(256)
void final_k(const bf16r* __restrict__ ha, const float* __restrict__ fw,
             const float* __restrict__ fb, float* __restrict__ out)
{
    int g = blockIdx.x * 256 + threadIdx.x;
    int node = g >> 6, lane = g & 63;
    if (node >= NAU) return;
    float m0 = 0.f, m1 = 0.f;
    #pragma unroll
    for (int r = 0; r < NRUNS; ++r) {
        size_t base = ((size_t)r * NAU + node) * HD;
        m0 += bf2f(ha[base + lane]);
        m1 += bf2f(ha[base + 64 + lane]);
    }
    m0 *= 0.25f;
    m1 *= 0.25f;
    float p[4];
    #pragma unroll
    for (int c = 0; c < 4; ++c)
        p[c] = m0 * fw[lane * 4 + c] + m1 * fw[(lane + 64) * 4 + c];
    #pragma unroll
    for (int off = 32; off >= 1; off >>= 1)
        #pragma unroll
        for (int c = 0; c < 4; ++c) p[c] += __shfl_down(p[c], off);
    if (lane == 0) {
        #pragma unroll
        for (int c = 0; c < 4; ++c) out[(size_t)node * 4 + c] = p[c] + fb[c];
    }
}

#define CSR_INTS ((size_t)(NPP + 4) + NEDGE + (NAU + 4) + NEDGE)
#define WT_ELEMS ((size_t)10 * HD * HD)

template<bool GATHER>
static void run_all(void* const* d_in, void* d_out, void* d_ws, hipStream_t stream)
{
    const float* x_author = (const float*)d_in[0];
    const float* x_paper  = (const float*)d_in[1];
    const int*   ei_ap    = (const int*)d_in[2];
    const int*   ei_pa    = (const int*)d_in[3];
    const float* drop_a   = (const float*)d_in[4];
    const float* drop_p   = (const float*)d_in[5];
    const float* lin_a_w  = (const float*)d_in[6];
    const float* lin_a_b  = (const float*)d_in[7];
    const float* lin_p_w  = (const float*)d_in[8];
    const float* lin_p_b  = (const float*)d_in[9];
    const float* W1       = (const float*)d_in[10];
    const float* B1       = (const float*)d_in[11];
    const float* G        = (const float*)d_in[12];
    const float* BT       = (const float*)d_in[13];
    const float* W2       = (const float*)d_in[14];
    const float* B2       = (const float*)d_in[15];
    const float* EPS      = (const float*)d_in[16];
    const float* fw       = (const float*)d_in[17];
    const float* fb       = (const float*)d_in[18];

    // ws: [stats 8*HD f32][Wt][CSR][agg_a][agg_p][h_a][h_p]
    float* gsumP   = (float*)d_ws;
    float* gsumsqP = gsumP + HD;
    float* gsumA   = gsumP + 2 * HD;
    float* gsumsqA = gsumP + 3 * HD;
    float* scP     = gsumP + 4 * HD;
    float* shP     = gsumP + 5 * HD;
    float* scA     = gsumP + 6 * HD;
    float* shA     = gsumP + 7 * HD;
    bf16r* wt = (bf16r*)(gsumP + 8 * HD);
    int* ip = (int*)(wt + WT_ELEMS);

    int *off_ap = nullptr, *bkt_ap = nullptr, *off_pa = nullptr, *bkt_pa = nullptr;
    if (GATHER) {
        off_ap = ip;  ip += NPP + 4;
        bkt_ap = ip;  ip += NEDGE;
        off_pa = ip;  ip += NAU + 4;
        bkt_pa = ip;  ip += NEDGE;
    }
    float* agg_a = (float*)ip;
    float* agg_p = agg_a + (size_t)NAU * HD;
    bf16r* h_a = (bf16r*)(agg_p + (size_t)NPP * HD);
    bf16r* h_p = h_a + (size_t)NRUNS * NAU * HD;

    const bf16r* wt_lin_a = wt;
    const bf16r* wt_lin_p = wt + (size_t)1 * HD * HD;
    const bf16r* wt_W1    = wt + (size_t)2 * HD * HD;
    const bf16r* wt_W2    = wt + (size_t)6 * HD * HD;

    convw_k<<<640, 256, 0, stream>>>(lin_a_w, lin_p_w, W1, W2, wt);
    zero_k<<<1, 256, 0, stream>>>(gsumP, (4 * HD) / 4);

    if (GATHER) {
        int* cur_ap  = (int*)agg_a;
        int* cur_pa  = cur_ap + NPP;
        int* partial = cur_pa + NAU;
        {
            int nchunk = (NPP + 1023) / 1024;
            zero_k<<<64, 256, 0, stream>>>((float*)cur_ap, NPP / 4);
            count_k<<<(NEDGE + 255) / 256, 256, 0, stream>>>(ei_ap, NEDGE, cur_ap);
            scan1_k<<<nchunk, 256, 0, stream>>>(cur_ap, off_ap, partial, NPP);
            scan2_k<<<1, 256, 0, stream>>>(partial, nchunk);
            scan3_k<<<nchunk, 256, 0, stream>>>(off_ap, cur_ap, partial, NPP, NEDGE);
            fill_k<<<(NEDGE + 255) / 256, 256, 0, stream>>>(ei_ap, NEDGE, cur_ap, bkt_ap);
        }
        {
            int nchunk = (NAU + 1023) / 1024;
            zero_k<<<64, 256, 0, stream>>>((float*)cur_pa, NAU / 4);
            count_k<<<(NEDGE + 255) / 256, 256, 0, stream>>>(ei_pa, NEDGE, cur_pa);
            scan1_k<<<nchunk, 256, 0, stream>>>(cur_pa, off_pa, partial, NAU);
            scan2_k<<<1, 256, 0, stream>>>(partial, nchunk);
            scan3_k<<<nchunk, 256, 0, stream>>>(off_pa, cur_pa, partial, NAU, NEDGE);
            fill_k<<<(NEDGE + 255) / 256, 256, 0, stream>>>(ei_pa, NEDGE, cur_pa, bkt_pa);
        }
    }

    // ---- combined PROJ (paper side P, author side A) ----
    SideP Pp = {};
    Pp.in = x_paper; Pp.out = h_p; Pp.wt = wt_lin_p; Pp.bias = lin_p_b;
    Pp.mask = drop_p; Pp.M = NPP; Pp.Nn = NPP; Pp.tiles = (NPP + 63) / 64;
    SideP Pa = {};
    Pa.in = x_author; Pa.out = h_a; Pa.wt = wt_lin_a; Pa.bias = lin_a_b;
    Pa.mask = drop_a; Pa.M = NAU; Pa.Nn = NAU; Pa.tiles = (NAU + 63) / 64;
    int BPproj = (int)((long)NB_GEMM * Pp.tiles / (Pp.tiles + Pa.tiles));
    mfma_gemm<M_PROJ, float><<<NB_GEMM, 256, 0, stream>>>(Pp, Pa, BPproj);

    const int TP = NRUNS * NPP / 64, TA = NRUNS * NAU / 64;
    const int BPgin = (int)((long)NB_GEMM * TP / (TP + TA));

    for (int l = 0; l < 2; ++l) {
        int t0 = l * 2 + 0, t1 = l * 2 + 1;

        if (GATHER) {
            gather2_k<<<((NPP + NAU) * 64) / 256, 256, 0, stream>>>(
                h_a, h_p, agg_p, agg_a, off_ap, bkt_ap, off_pa, bkt_pa);
        } else {
            zero_k<<<2048, 256, 0, stream>>>(agg_a, ((size_t)(NAU + NPP) * HD) / 4);
            scatter_k<<<(NEDGE * 32) / 256, 256, 0, stream>>>(h_a, agg_p, ei_ap, NEDGE);
            scatter_k<<<(NEDGE * 32) / 256, 256, 0, stream>>>(h_p, agg_a, ei_pa, NEDGE);
        }

        // combined GIN1
        SideP G1p = {};
        G1p.in = h_p; G1p.out = h_p; G1p.wt = wt_W1 + (size_t)t0 * HD * HD;
        G1p.bias = B1 + (size_t)t0 * HD; G1p.agg = agg_p; G1p.epsp = EPS + t0;
        G1p.gsum = gsumP; G1p.gsumsq = gsumsqP;
        G1p.M = NRUNS * NPP; G1p.Nn = NPP; G1p.tiles = TP;
        SideP G1a = {};
        G1a.in = h_a; G1a.out = h_a; G1a.wt = wt_W1 + (size_t)t1 * HD * HD;
        G1a.bias = B1 + (size_t)t1 * HD; G1a.agg = agg_a; G1a.epsp = EPS + t1;
        G1a.gsum = gsumA; G1a.gsumsq = gsumsqA;
        G1a.M = NRUNS * NAU; G1a.Nn = NAU; G1a.tiles = TA;
        mfma_gemm<M_GIN1, bf16r><<<NB_GEMM, 256, 0, stream>>>(G1p, G1a, BPgin);

        finalize2_k<<<1, 256, 0, stream>>>(
            gsumP, gsumsqP, G + (size_t)t0 * HD, BT + (size_t)t0 * HD, scP, shP,
            1.0f / (NRUNS * NPP),
            gsumA, gsumsqA, G + (size_t)t1 * HD, BT + (size_t)t1 * HD, scA, shA,
            1.0f / (NRUNS * NAU));

        // combined GIN2
        SideP G2p = {};
        G2p.in = h_p; G2p.out = h_p; G2p.wt = wt_W2 + (size_t)t0 * HD * HD;
        G2p.bias = B2 + (size_t)t0 * HD; G2p.scale = scP; G2p.shift = shP;
        G2p.M = NRUNS * NPP; G2p.Nn = NPP; G2p.tiles = TP;
        SideP G2a = {};
        G2a.in = h_a; G2a.out = h_a; G2a.wt = wt_W2 + (size_t)t1 * HD * HD;
        G2a.bias = B2 + (size_t)t1 * HD; G2a.scale = scA; G2a.shift = shA;
        G2a.M = NRUNS * NAU; G2a.Nn = NAU; G2a.tiles = TA;
        mfma_gemm<M_GIN2, bf16r><<<NB_GEMM, 256, 0, stream>>>(G2p, G2a, BPgin);
    }

    final_k<<<(NAU * 64) / 256, 256, 0, stream>>>(h_a, fw, fb, (float*)d_out);
}

extern "C" void kernel_launch(void* const* d_in, const int* in_sizes, int n_in,
                              void* d_out, int out_size, void* d_ws, size_t ws_size,
                              hipStream_t stream)
{
    const size_t hB    = (size_t)NRUNS * (NAU + NPP) * HD * sizeof(bf16r);
    const size_t aggB  = (size_t)(NAU + NPP) * HD * sizeof(float);
    const size_t statB = 8 * HD * sizeof(float);
    const size_t wtB   = WT_ELEMS * sizeof(bf16r);
    const size_t csrB  = CSR_INTS * sizeof(int);

    const size_t need_gather = statB + wtB + csrB + aggB + hB;   // ~235.4 MB
    if (ws_size >= need_gather) {
        run_all<true>(d_in, d_out, d_ws, stream);
    } else {
        run_all<false>(d_in, d_out, d_ws, stream);               // atomic fallback
    }
}

// Round 7
// 687.859 us; speedup vs baseline: 7.0934x; 1.0314x over previous
//
#include <hip/hip_runtime.h>

#define NRUNS 4
#define NAU 50000
#define NPP 100000
#define NEDGE 500000
#define HD 128
#define INV_KEEP 1.25f
#define BN_EPS 1e-5f
#define LDA 136      // padded LDS row (bf16 elems), 272B
#define NB_GEMM 1024 // persistent GEMM grid (4 blocks/CU)

#define M_PROJ 0
#define M_GIN1 1
#define M_GIN2 2

typedef unsigned short bf16r;
typedef __attribute__((ext_vector_type(8))) short v8s;   // 8 bf16 (4 VGPR)
typedef __attribute__((ext_vector_type(4))) float v4f;   // 4 f32 acc

__device__ inline float bf2f(bf16r u) {
    return __uint_as_float(((unsigned)u) << 16);
}
// native RNE f32->bf16 (v_cvt_pk_bf16_f32 on gfx950) — was a 3-op bit-twiddle
__device__ inline bf16r f2bf(float f) {
    __bf16 b = (__bf16)f;
    return __builtin_bit_cast(bf16r, b);
}

// grid-stride float4 zero fill
__global__ __launch_bounds__(256)
void zero_k(float* p, long n4) {
    long i = (long)blockIdx.x * 256 + threadIdx.x;
    long stride = (long)gridDim.x * 256;
    float4 z = make_float4(0.f, 0.f, 0.f, 0.f);
    for (; i < n4; i += stride) ((float4*)p)[i] = z;
}

// ============ weight convert: f32 [k][n] -> bf16 transposed [n][k] ============
__global__ __launch_bounds__(256)
void convw_k(const float* __restrict__ lin_a_w, const float* __restrict__ lin_p_w,
             const float* __restrict__ W1, const float* __restrict__ W2,
             bf16r* __restrict__ wt)
{
    int t = blockIdx.x >> 6;
    int e = (blockIdx.x & 63) * 256 + threadIdx.x;   // 0..16383
    const float* src;
    if (t == 0) src = lin_a_w;
    else if (t == 1) src = lin_p_w;
    else if (t < 6) src = W1 + (size_t)(t - 2) * HD * HD;
    else src = W2 + (size_t)(t - 6) * HD * HD;
    int n = e >> 7, k = e & 127;
    wt[(size_t)t * HD * HD + e] = f2bf(src[(size_t)k * HD + n]);
}

// ================= CSR build (counting sort by dst) =================
__global__ __launch_bounds__(256)
void count_k(const int* __restrict__ ei, int E, int* cnt) {
    int e = blockIdx.x * 256 + threadIdx.x;
    if (e < E) atomicAdd(&cnt[ei[E + e]], 1);
}

__global__ __launch_bounds__(256)
void scan1_k(const int* __restrict__ in, int* out, int* partial, int n) {
    __shared__ int lds[256];
    int b = blockIdx.x, t = threadIdx.x;
    int base = b * 1024 + t * 4;
    int v0 = 0, v1 = 0, v2 = 0, v3 = 0;
    if (base + 3 < n) {
        int4 x = *(const int4*)(in + base);
        v0 = x.x; v1 = x.y; v2 = x.z; v3 = x.w;
    } else {
        if (base + 0 < n) v0 = in[base + 0];
        if (base + 1 < n) v1 = in[base + 1];
        if (base + 2 < n) v2 = in[base + 2];
        if (base + 3 < n) v3 = in[base + 3];
    }
    int s = v0 + v1 + v2 + v3;
    lds[t] = s;
    __syncthreads();
    for (int d = 1; d < 256; d <<= 1) {
        int x = (t >= d) ? lds[t - d] : 0;
        __syncthreads();
        lds[t] += x;
        __syncthreads();
    }
    int excl = lds[t] - s;
    if (base + 0 < n) out[base + 0] = excl;
    if (base + 1 < n) out[base + 1] = excl + v0;
    if (base + 2 < n) out[base + 2] = excl + v0 + v1;
    if (base + 3 < n) out[base + 3] = excl + v0 + v1 + v2;
    if (t == 255) partial[b] = lds[255];
}

__global__ __launch_bounds__(256)
void scan2_k(int* partial, int n) {
    __shared__ int lds[256];
    int t = threadIdx.x;
    int s = (t < n) ? partial[t] : 0;
    lds[t] = s;
    __syncthreads();
    for (int d = 1; d < 256; d <<= 1) {
        int x = (t >= d) ? lds[t - d] : 0;
        __syncthreads();
        lds[t] += x;
        __syncthreads();
    }
    if (t < n) partial[t] = lds[t] - s;
}

__global__ __launch_bounds__(256)
void scan3_k(int* off, int* cur, const int* __restrict__ partial, int n, int total) {
    int b = blockIdx.x, t = threadIdx.x;
    int add = partial[b];
    int base = b * 1024 + t * 4;
    #pragma unroll
    for (int j = 0; j < 4; ++j) {
        int i = base + j;
        if (i < n) {
            int v = off[i] + add;
            off[i] = v;
            cur[i] = v;
        }
    }
    if (b == 0 && t == 0) off[n] = total;
}

__global__ __launch_bounds__(256)
void fill_k(const int* __restrict__ ei, int E, int* cur, int* bucket) {
    int e = blockIdx.x * 256 + threadIdx.x;
    if (e < E) {
        int d = ei[E + e];
        int p = atomicAdd(&cur[d], 1);
        bucket[p] = ei[e];
    }
}

// combined gather for both graphs: f32 accumulate, bf16 store.
__global__ __launch_bounds__(256)
void gather2_k(const bf16r* __restrict__ hA, const bf16r* __restrict__ hP,
               bf16r* __restrict__ aggP, bf16r* __restrict__ aggA,
               const int* __restrict__ offAP, const int* __restrict__ bktAP,
               const int* __restrict__ offPA, const int* __restrict__ bktPA)
{
    int gw = (blockIdx.x * 256 + threadIdx.x) >> 6;
    int lane = threadIdx.x & 63;
    const bf16r* src; bf16r* agg; const int* off; const int* bkt; int w;
    if (gw < NPP) { src = hA; agg = aggP; off = offAP; bkt = bktAP; w = gw; }
    else          { src = hP; agg = aggA; off = offPA; bkt = bktPA; w = gw - NPP; }
    int s0 = off[w], s1 = off[w + 1];
    float a0 = 0.f, a1 = 0.f;
    int e = s0;
    for (; e + 1 < s1; e += 2) {
        int i0 = bkt[e], i1 = bkt[e + 1];
        ushort2 u = *(const ushort2*)(src + (size_t)i0 * HD + lane * 2);
        ushort2 v = *(const ushort2*)(src + (size_t)i1 * HD + lane * 2);
        a0 += bf2f(u.x) + bf2f(v.x);
        a1 += bf2f(u.y) + bf2f(v.y);
    }
    if (e < s1) {
        ushort2 u = *(const ushort2*)(src + (size_t)bkt[e] * HD + lane * 2);
        a0 += bf2f(u.x);
        a1 += bf2f(u.y);
    }
    ushort2 o;
    o.x = f2bf(a0);
    o.y = f2bf(a1);
    *(ushort2*)(agg + (size_t)w * HD + lane * 2) = o;
}

// fallback scatter (atomics, f32 agg) for tight workspaces
__global__ __launch_bounds__(256)
void scatter_k(const bf16r* __restrict__ src, float* dst,
               const int* __restrict__ ei, int E)
{
    int g = blockIdx.x * 256 + threadIdx.x;
    int e = g >> 5, lane = g & 31;
    if (e >= E) return;
    int s = ei[e], d = ei[E + e];
    ushort4 u = *(const ushort4*)(src + (size_t)s * HD + lane * 4);
    float* dp = dst + (size_t)d * HD + lane * 4;
    unsafeAtomicAdd(dp + 0, bf2f(u.x));
    unsafeAtomicAdd(dp + 1, bf2f(u.y));
    unsafeAtomicAdd(dp + 2, bf2f(u.z));
    unsafeAtomicAdd(dp + 3, bf2f(u.w));
}

// ================= persistent pipelined MFMA GEMM =================
struct SideP {
    const void* in;
    bf16r* out;
    const bf16r* wt;
    const float* bias;
    const void* agg;      // AT-typed (bf16 main path, f32 fallback)
    const float* epsp;
    float* gsum;
    float* gsumsq;
    const float* scale;
    const float* shift;
    const float* mask;
    int M, Nn, tiles;
};

// Per block: weights reg-resident once; loop over tiles with double-buffered
// LDS A-tile, 2-phase pipeline: stage(cur) / barrier / prefetch(t+1)->regs /
// compute(cur). h AND agg both prefetched to regs. GIN1 stats accumulate in
// regs across tiles, one atomic pass per block.
template<int MODE, typename IT, typename AT>
__global__ __launch_bounds__(256, 4)
void mfma_gemm(SideP P, SideP A, int BP)
{
    __shared__ bf16r za[2][64][LDA];
    __shared__ float red[2][HD];
    const int tid = threadIdx.x;

    SideP S;
    int t, tstride;
    if ((int)blockIdx.x < BP) { S = P; t = blockIdx.x; tstride = BP; }
    else { S = A; t = (int)blockIdx.x - BP; tstride = NB_GEMM - BP; }
    if (t >= S.tiles) return;   // block-uniform exit

    const int wid = tid >> 6, lane = tid & 63;
    const int lr = lane & 15, lk = (lane >> 4) * 8;
    const int colq = (lane >> 4) * 4, cb = wid * 32;
    const int srow = tid >> 4;          // staging row base (chunk i adds 16*i)
    const int scol = (tid & 15) * 8;    // staging col (same for all chunks)

    float epsv = 1.0f;
    if (MODE == M_GIN1) epsv = 1.0f + S.epsp[0];

    // weights reg-resident (once per block)
    v8s w[2][4];
    #pragma unroll
    for (int cf = 0; cf < 2; ++cf)
        #pragma unroll
        for (int ks = 0; ks < 4; ++ks)
            w[cf][ks] = *(const v8s*)(S.wt + (size_t)(cb + cf * 16 + lr) * HD + ks * 32 + lk);

    const float4 bb0 = *(const float4*)(S.bias + cb + colq);
    const float4 bb1 = *(const float4*)(S.bias + cb + 16 + colq);

    // GIN2: hoist per-thread scale/shift (staging col is tid-invariant)
    float4 sc0h, sc1h, sh0h, sh1h;
    if (MODE == M_GIN2) {
        sc0h = *(const float4*)(S.scale + scol);
        sc1h = *(const float4*)(S.scale + scol + 4);
        sh0h = *(const float4*)(S.shift + scol);
        sh1h = *(const float4*)(S.shift + scol + 4);
    }

    float st_s[2][4], st_q[2][4];
    if (MODE == M_GIN1) {
        #pragma unroll
        for (int cf = 0; cf < 2; ++cf)
            #pragma unroll
            for (int j = 0; j < 4; ++j) { st_s[cf][j] = 0.f; st_q[cf][j] = 0.f; }
    }

    constexpr int NVH = (MODE == M_PROJ) ? 2 : 1;   // int4 words for h row-chunk
    constexpr bool PAGG = (MODE == M_GIN1);
    constexpr int NVA = (PAGG && sizeof(AT) == 4) ? 2 : 1;
    int4 pre[4][NVH];
    int4 preA[4][NVA];

    auto prefetch = [&](int tt) {
        int m0n = tt * 64;
        #pragma unroll
        for (int i = 0; i < 4; ++i) {
            int gr = m0n + srow + 16 * i;
            if (gr < S.M) {
                const int4* p = (const int4*)((const IT*)S.in + (size_t)gr * HD + scol);
                pre[i][0] = p[0];
                if constexpr (NVH == 2) pre[i][1] = p[1];
            } else {
                pre[i][0] = make_int4(0, 0, 0, 0);
                if constexpr (NVH == 2) pre[i][1] = make_int4(0, 0, 0, 0);
            }
            if constexpr (PAGG) {
                if (gr < S.Nn) {
                    const int4* pa = (const int4*)((const AT*)S.agg + (size_t)gr * HD + scol);
                    preA[i][0] = pa[0];
                    if constexpr (NVA == 2) preA[i][1] = pa[1];
                } else {
                    preA[i][0] = make_int4(0, 0, 0, 0);
                    if constexpr (NVA == 2) preA[i][1] = make_int4(0, 0, 0, 0);
                }
            }
        }
    };

    prefetch(t);

    int cur = 0;
    for (;;) {
        const int m0 = t * 64;
        // ---- stage: transform pre -> za[cur] ----
        #pragma unroll
        for (int i = 0; i < 4; ++i) {
            int row = srow + 16 * i;
            float v[8];
            if constexpr (NVH == 2) {
                const float* pf = (const float*)&pre[i][0];
                #pragma unroll
                for (int j = 0; j < 8; ++j) v[j] = pf[j];
            } else {
                const bf16r* pu = (const bf16r*)&pre[i][0];
                #pragma unroll
                for (int j = 0; j < 8; ++j) v[j] = bf2f(pu[j]);
            }
            if constexpr (MODE == M_GIN1) {
                float av[8];
                if constexpr (sizeof(AT) == 4) {
                    const float* pa = (const float*)&preA[i][0];
                    #pragma unroll
                    for (int j = 0; j < 8; ++j) av[j] = pa[j];
                } else {
                    const bf16r* pa = (const bf16r*)&preA[i][0];
                    #pragma unroll
                    for (int j = 0; j < 8; ++j) av[j] = bf2f(pa[j]);
                }
                #pragma unroll
                for (int j = 0; j < 8; ++j) v[j] = v[j] * epsv + av[j];
            } else if constexpr (MODE == M_GIN2) {
                v[0] = fmaxf(v[0] * sc0h.x + sh0h.x, 0.f);
                v[1] = fmaxf(v[1] * sc0h.y + sh0h.y, 0.f);
                v[2] = fmaxf(v[2] * sc0h.z + sh0h.z, 0.f);
                v[3] = fmaxf(v[3] * sc0h.w + sh0h.w, 0.f);
                v[4] = fmaxf(v[4] * sc1h.x + sh1h.x, 0.f);
                v[5] = fmaxf(v[5] * sc1h.y + sh1h.y, 0.f);
                v[6] = fmaxf(v[6] * sc1h.z + sh1h.z, 0.f);
                v[7] = fmaxf(v[7] * sc1h.w + sh1h.w, 0.f);
            }
            union { v8s w8; bf16r u[8]; } pk;
            #pragma unroll
            for (int j = 0; j < 8; ++j) pk.u[j] = f2bf(v[j]);
            *(v8s*)&za[cur][row][scol] = pk.w8;
        }
        __syncthreads();

        // ---- prefetch next tile (after barrier -> stays in flight) ----
        const int tn = t + tstride;
        const bool more = tn < S.tiles;
        if (more) prefetch(tn);

        // ---- compute ----
        v4f acc[2][4];
        #pragma unroll
        for (int cf = 0; cf < 2; ++cf)
            #pragma unroll
            for (int rf = 0; rf < 4; ++rf) acc[cf][rf] = (v4f){0.f, 0.f, 0.f, 0.f};

        #pragma unroll
        for (int ks = 0; ks < 4; ++ks)
            #pragma unroll
            for (int rf = 0; rf < 4; ++rf) {
                v8s a = *(const v8s*)&za[cur][rf * 16 + lr][ks * 32 + lk];
                acc[0][rf] = __builtin_amdgcn_mfma_f32_16x16x32_bf16(w[0][ks], a, acc[0][rf], 0, 0, 0);
                acc[1][rf] = __builtin_amdgcn_mfma_f32_16x16x32_bf16(w[1][ks], a, acc[1][rf], 0, 0, 0);
            }

        #pragma unroll
        for (int rf = 0; rf < 4; ++rf) {
            acc[0][rf][0] += bb0.x; acc[0][rf][1] += bb0.y;
            acc[0][rf][2] += bb0.z; acc[0][rf][3] += bb0.w;
            acc[1][rf][0] += bb1.x; acc[1][rf][1] += bb1.y;
            acc[1][rf][2] += bb1.z; acc[1][rf][3] += bb1.w;
        }

        if constexpr (MODE == M_PROJ) {
            #pragma unroll
            for (int rf = 0; rf < 4; ++rf) {
                int grow = m0 + rf * 16 + lr;
                if (grow < S.M) {
                    #pragma unroll
                    for (int run = 0; run < NRUNS; ++run) {
                        float wm = S.mask[(size_t)run * S.Nn + grow] * INV_KEEP;
                        #pragma unroll
                        for (int cf = 0; cf < 2; ++cf) {
                            ushort4 o;
                            o.x = f2bf(acc[cf][rf][0] * wm);
                            o.y = f2bf(acc[cf][rf][1] * wm);
                            o.z = f2bf(acc[cf][rf][2] * wm);
                            o.w = f2bf(acc[cf][rf][3] * wm);
                            *(ushort4*)(S.out + ((size_t)run * S.Nn + grow) * HD + cb + cf * 16 + colq) = o;
                        }
                    }
                }
            }
        } else if constexpr (MODE == M_GIN1) {
            #pragma unroll
            for (int rf = 0; rf < 4; ++rf) {
                int grow = m0 + rf * 16 + lr;
                #pragma unroll
                for (int cf = 0; cf < 2; ++cf) {
                    ushort4 o;
                    o.x = f2bf(acc[cf][rf][0]);
                    o.y = f2bf(acc[cf][rf][1]);
                    o.z = f2bf(acc[cf][rf][2]);
                    o.w = f2bf(acc[cf][rf][3]);
                    *(ushort4*)(S.out + (size_t)grow * HD + cb + cf * 16 + colq) = o;
                }
            }
            #pragma unroll
            for (int cf = 0; cf < 2; ++cf)
                #pragma unroll
                for (int j = 0; j < 4; ++j)
                    #pragma unroll
                    for (int rf = 0; rf < 4; ++rf) {
                        float vv = acc[cf][rf][j];
                        st_s[cf][j] += vv;
                        st_q[cf][j] += vv * vv;
                    }
        } else {  // M_GIN2
            #pragma unroll
            for (int rf = 0; rf < 4; ++rf) {
                int grow = m0 + rf * 16 + lr;
                #pragma unroll
                for (int cf = 0; cf < 2; ++cf) {
                    ushort4 o;
                    o.x = f2bf(fmaxf(acc[cf][rf][0], 0.f));
                    o.y = f2bf(fmaxf(acc[cf][rf][1], 0.f));
                    o.z = f2bf(fmaxf(acc[cf][rf][2], 0.f));
                    o.w = f2bf(fmaxf(acc[cf][rf][3], 0.f));
                    *(ushort4*)(S.out + (size_t)grow * HD + cb + cf * 16 + colq) = o;
                }
            }
        }

        if (!more) break;
        t = tn;
        cur ^= 1;
    }

    if constexpr (MODE == M_GIN1) {
        #pragma unroll
        for (int d = 1; d < 16; d <<= 1)
            #pragma unroll
            for (int cf = 0; cf < 2; ++cf)
                #pragma unroll
                for (int j = 0; j < 4; ++j) {
                    st_s[cf][j] += __shfl_xor(st_s[cf][j], d);
                    st_q[cf][j] += __shfl_xor(st_q[cf][j], d);
                }
        if (lr == 0) {
            #pragma unroll
            for (int cf = 0; cf < 2; ++cf)
                #pragma unroll
                for (int j = 0; j < 4; ++j) {
                    red[0][cb + cf * 16 + colq + j] = st_s[cf][j];
                    red[1][cb + cf * 16 + colq + j] = st_q[cf][j];
                }
        }
        __syncthreads();
        if (tid < HD) {
            unsafeAtomicAdd(S.gsum + tid, red[0][tid]);
            unsafeAtomicAdd(S.gsumsq + tid, red[1][tid]);
        }
    }
}

// BN stats -> scale/shift for BOTH sides; re-zeros accumulators
__global__ void finalize2_k(float* gsP, float* gsqP, const float* gamP, const float* betP,
                            float* scP, float* shP, float invNP,
                            float* gsA, float* gsqA, const float* gamA, const float* betA,
                            float* scA, float* shA, float invNA)
{
    int c = threadIdx.x;
    float *gs, *gsq, *sc, *sh;
    const float *gm, *bt;
    float invN;
    if (c < HD) { gs = gsP; gsq = gsqP; gm = gamP; bt = betP; sc = scP; sh = shP; invN = invNP; }
    else { c -= HD; gs = gsA; gsq = gsqA; gm = gamA; bt = betA; sc = scA; sh = shA; invN = invNA; }
    float mu = gs[c] * invN;
    float var = gsq[c] * invN - mu * mu;
    float s = gm[c] * rsqrtf(var + BN_EPS);
    sc[c] = s;
    sh[c] = bt[c] - mu * s;
    gs[c] = 0.f;
    gsq[c] = 0.f;
}

// mean over runs + [128]x[128,4] matmul; one wave per author node
__global__ __launch_bounds__(256)
void final_k(const bf16r* __restrict__ ha, const float* __restrict__ fw,
             const float* __restrict__ fb, float* __restrict__ out)
{
    int g = blockIdx.x * 256 + threadIdx.x;
    int node = g >> 6, lane = g & 63;
    if (node >= NAU) return;
    float m0 = 0.f, m1 = 0.f;
    #pragma unroll
    for (int r = 0; r < NRUNS; ++r) {
        size_t base = ((size_t)r * NAU + node) * HD;
        m0 += bf2f(ha[base + lane]);
        m1 += bf2f(ha[base + 64 + lane]);
    }
    m0 *= 0.25f;
    m1 *= 0.25f;
    float p[4];
    #pragma unroll
    for (int c = 0; c < 4; ++c)
        p[c] = m0 * fw[lane * 4 + c] + m1 * fw[(lane + 64) * 4 + c];
    #pragma unroll
    for (int off = 32; off >= 1; off >>= 1)
        #pragma unroll
        for (int c = 0; c < 4; ++c) p[c] += __shfl_down(p[c], off);
    if (lane == 0) {
        #pragma unroll
        for (int c = 0; c < 4; ++c) out[(size_t)node * 4 + c] = p[c] + fb[c];
    }
}

#define CSR_INTS ((size_t)(NPP + 4) + NEDGE + (NAU + 4) + NEDGE)
#define WT_ELEMS ((size_t)10 * HD * HD)

template<bool GATHER>
static void run_all(void* const* d_in, void* d_out, void* d_ws, hipStream_t stream)
{
    const float* x_author = (const float*)d_in[0];
    const float* x_paper  = (const float*)d_in[1];
    const int*   ei_ap    = (const int*)d_in[2];
    const int*   ei_pa    = (const int*)d_in[3];
    const float* drop_a   = (const float*)d_in[4];
    const float* drop_p   = (const float*)d_in[5];
    const float* lin_a_w  = (const float*)d_in[6];
    const float* lin_a_b  = (const float*)d_in[7];
    const float* lin_p_w  = (const float*)d_in[8];
    const float* lin_p_b  = (const float*)d_in[9];
    const float* W1       = (const float*)d_in[10];
    const float* B1       = (const float*)d_in[11];
    const float* G        = (const float*)d_in[12];
    const float* BT       = (const float*)d_in[13];
    const float* W2       = (const float*)d_in[14];
    const float* B2       = (const float*)d_in[15];
    const float* EPS      = (const float*)d_in[16];
    const float* fw       = (const float*)d_in[17];
    const float* fb       = (const float*)d_in[18];

    // ws: [stats 8*HD f32][Wt][CSR (gather only)][agg][h_a][h_p]
    float* gsumP   = (float*)d_ws;
    float* gsumsqP = gsumP + HD;
    float* gsumA   = gsumP + 2 * HD;
    float* gsumsqA = gsumP + 3 * HD;
    float* scP     = gsumP + 4 * HD;
    float* shP     = gsumP + 5 * HD;
    float* scA     = gsumP + 6 * HD;
    float* shA     = gsumP + 7 * HD;
    bf16r* wt = (bf16r*)(gsumP + 8 * HD);
    char* cp = (char*)(wt + WT_ELEMS);

    int *off_ap = nullptr, *bkt_ap = nullptr, *off_pa = nullptr, *bkt_pa = nullptr;
    if (GATHER) {
        int* ip = (int*)cp;
        off_ap = ip;  ip += NPP + 4;
        bkt_ap = ip;  ip += NEDGE;
        off_pa = ip;  ip += NAU + 4;
        bkt_pa = ip;  ip += NEDGE;
        cp = (char*)ip;
    }
    // agg: bf16 on gather path, f32 on fallback
    void* agg_a_v = cp;
    size_t aggElem = GATHER ? sizeof(bf16r) : sizeof(float);
    void* agg_p_v = cp + (size_t)NAU * HD * aggElem;
    bf16r* h_a = (bf16r*)(cp + (size_t)(NAU + NPP) * HD * aggElem);
    bf16r* h_p = h_a + (size_t)NRUNS * NAU * HD;

    const bf16r* wt_lin_a = wt;
    const bf16r* wt_lin_p = wt + (size_t)1 * HD * HD;
    const bf16r* wt_W1    = wt + (size_t)2 * HD * HD;
    const bf16r* wt_W2    = wt + (size_t)6 * HD * HD;

    convw_k<<<640, 256, 0, stream>>>(lin_a_w, lin_p_w, W1, W2, wt);
    zero_k<<<1, 256, 0, stream>>>(gsumP, (4 * HD) / 4);

    if (GATHER) {
        int* cur_ap  = (int*)agg_a_v;   // alias agg area pre-gather
        int* cur_pa  = cur_ap + NPP;
        int* partial = cur_pa + NAU;
        {
            int nchunk = (NPP + 1023) / 1024;
            zero_k<<<64, 256, 0, stream>>>((float*)cur_ap, NPP / 4);
            count_k<<<(NEDGE + 255) / 256, 256, 0, stream>>>(ei_ap, NEDGE, cur_ap);
            scan1_k<<<nchunk, 256, 0, stream>>>(cur_ap, off_ap, partial, NPP);
            scan2_k<<<1, 256, 0, stream>>>(partial, nchunk);
            scan3_k<<<nchunk, 256, 0, stream>>>(off_ap, cur_ap, partial, NPP, NEDGE);
            fill_k<<<(NEDGE + 255) / 256, 256, 0, stream>>>(ei_ap, NEDGE, cur_ap, bkt_ap);
        }
        {
            int nchunk = (NAU + 1023) / 1024;
            zero_k<<<64, 256, 0, stream>>>((float*)cur_pa, NAU / 4);
            count_k<<<(NEDGE + 255) / 256, 256, 0, stream>>>(ei_pa, NEDGE, cur_pa);
            scan1_k<<<nchunk, 256, 0, stream>>>(cur_pa, off_pa, partial, NAU);
            scan2_k<<<1, 256, 0, stream>>>(partial, nchunk);
            scan3_k<<<nchunk, 256, 0, stream>>>(off_pa, cur_pa, partial, NAU, NEDGE);
            fill_k<<<(NEDGE + 255) / 256, 256, 0, stream>>>(ei_pa, NEDGE, cur_pa, bkt_pa);
        }
    }

    // ---- combined PROJ ----
    SideP Pp = {};
    Pp.in = x_paper; Pp.out = h_p; Pp.wt = wt_lin_p; Pp.bias = lin_p_b;
    Pp.mask = drop_p; Pp.M = NPP; Pp.Nn = NPP; Pp.tiles = (NPP + 63) / 64;
    SideP Pa = {};
    Pa.in = x_author; Pa.out = h_a; Pa.wt = wt_lin_a; Pa.bias = lin_a_b;
    Pa.mask = drop_a; Pa.M = NAU; Pa.Nn = NAU; Pa.tiles = (NAU + 63) / 64;
    int BPproj = (int)((long)NB_GEMM * Pp.tiles / (Pp.tiles + Pa.tiles));
    mfma_gemm<M_PROJ, float, bf16r><<<NB_GEMM, 256, 0, stream>>>(Pp, Pa, BPproj);

    const int TP = NRUNS * NPP / 64, TA = NRUNS * NAU / 64;
    const int BPgin = (int)((long)NB_GEMM * TP / (TP + TA));

    for (int l = 0; l < 2; ++l) {
        int t0 = l * 2 + 0, t1 = l * 2 + 1;

        if (GATHER) {
            gather2_k<<<((NPP + NAU) * 64) / 256, 256, 0, stream>>>(
                h_a, h_p, (bf16r*)agg_p_v, (bf16r*)agg_a_v,
                off_ap, bkt_ap, off_pa, bkt_pa);
        } else {
            zero_k<<<2048, 256, 0, stream>>>((float*)agg_a_v, ((size_t)(NAU + NPP) * HD) / 4);
            scatter_k<<<(NEDGE * 32) / 256, 256, 0, stream>>>(h_a, (float*)agg_p_v, ei_ap, NEDGE);
            scatter_k<<<(NEDGE * 32) / 256, 256, 0, stream>>>(h_p, (float*)agg_a_v, ei_pa, NEDGE);
        }

        // combined GIN1
        SideP G1p = {};
        G1p.in = h_p; G1p.out = h_p; G1p.wt = wt_W1 + (size_t)t0 * HD * HD;
        G1p.bias = B1 + (size_t)t0 * HD; G1p.agg = agg_p_v; G1p.epsp = EPS + t0;
        G1p.gsum = gsumP; G1p.gsumsq = gsumsqP;
        G1p.M = NRUNS * NPP; G1p.Nn = NPP; G1p.tiles = TP;
        SideP G1a = {};
        G1a.in = h_a; G1a.out = h_a; G1a.wt = wt_W1 + (size_t)t1 * HD * HD;
        G1a.bias = B1 + (size_t)t1 * HD; G1a.agg = agg_a_v; G1a.epsp = EPS + t1;
        G1a.gsum = gsumA; G1a.gsumsq = gsumsqA;
        G1a.M = NRUNS * NAU; G1a.Nn = NAU; G1a.tiles = TA;
        if (GATHER)
            mfma_gemm<M_GIN1, bf16r, bf16r><<<NB_GEMM, 256, 0, stream>>>(G1p, G1a, BPgin);
        else
            mfma_gemm<M_GIN1, bf16r, float><<<NB_GEMM, 256, 0, stream>>>(G1p, G1a, BPgin);

        finalize2_k<<<1, 256, 0, stream>>>(
            gsumP, gsumsqP, G + (size_t)t0 * HD, BT + (size_t)t0 * HD, scP, shP,
            1.0f / (NRUNS * NPP),
            gsumA, gsumsqA, G + (size_t)t1 * HD, BT + (size_t)t1 * HD, scA, shA,
            1.0f / (NRUNS * NAU));

        // combined GIN2
        SideP G2p = {};
        G2p.in = h_p; G2p.out = h_p; G2p.wt = wt_W2 + (size_t)t0 * HD * HD;
        G2p.bias = B2 + (size_t)t0 * HD; G2p.scale = scP; G2p.shift = shP;
        G2p.M = NRUNS * NPP; G2p.Nn = NPP; G2p.tiles = TP;
        SideP G2a = {};
        G2a.in = h_a; G2a.out = h_a; G2a.wt = wt_W2 + (size_t)t1 * HD * HD;
        G2a.bias = B2 + (size_t)t1 * HD; G2a.scale = scA; G2a.shift = shA;
        G2a.M = NRUNS * NAU; G2a.Nn = NAU; G2a.tiles = TA;
        mfma_gemm<M_GIN2, bf16r, bf16r><<<NB_GEMM, 256, 0, stream>>>(G2p, G2a, BPgin);
    }

    final_k<<<(NAU * 64) / 256, 256, 0, stream>>>(h_a, fw, fb, (float*)d_out);
}

extern "C" void kernel_launch(void* const* d_in, const int* in_sizes, int n_in,
                              void* d_out, int out_size, void* d_ws, size_t ws_size,
                              hipStream_t stream)
{
    const size_t hB    = (size_t)NRUNS * (NAU + NPP) * HD * sizeof(bf16r);
    const size_t statB = 8 * HD * sizeof(float);
    const size_t wtB   = WT_ELEMS * sizeof(bf16r);
    const size_t csrB  = CSR_INTS * sizeof(int);
    const size_t aggBF = (size_t)(NAU + NPP) * HD * sizeof(bf16r);

    const size_t need_gather = statB + wtB + csrB + aggBF + hB;   // ~197 MB
    if (ws_size >= need_gather) {
        run_all<true>(d_in, d_out, d_ws, stream);
    } else {
        run_all<false>(d_in, d_out, d_ws, stream);                // atomic fallback
    }
}

// Round 8
// 668.600 us; speedup vs baseline: 7.2978x; 1.0288x over previous
//
#include <hip/hip_runtime.h>

#define NRUNS 4
#define NAU 50000
#define NPP 100000
#define NEDGE 500000
#define HD 128
#define INV_KEEP 1.25f
#define BN_EPS 1e-5f
#define LDA 136      // padded LDS row (bf16 elems), 272B
#define NB_GEMM 1024 // persistent GEMM grid (4 blocks/CU)

#define M_PROJ 0
#define M_GIN1 1
#define M_GIN2 2

typedef unsigned short bf16r;
typedef __attribute__((ext_vector_type(8))) short v8s;   // 8 bf16 (4 VGPR)
typedef __attribute__((ext_vector_type(4))) float v4f;   // 4 f32 acc

__device__ inline float bf2f(bf16r u) {
    return __uint_as_float(((unsigned)u) << 16);
}
// native RNE f32->bf16 (v_cvt on gfx950)
__device__ inline bf16r f2bf(float f) {
    __bf16 b = (__bf16)f;
    return __builtin_bit_cast(bf16r, b);
}

// grid-stride float4 zero fill
__global__ __launch_bounds__(256)
void zero_k(float* p, long n4) {
    long i = (long)blockIdx.x * 256 + threadIdx.x;
    long stride = (long)gridDim.x * 256;
    float4 z = make_float4(0.f, 0.f, 0.f, 0.f);
    for (; i < n4; i += stride) ((float4*)p)[i] = z;
}

// ============ weight convert: f32 [k][n] -> bf16 transposed [n][k] ============
__global__ __launch_bounds__(256)
void convw_k(const float* __restrict__ lin_a_w, const float* __restrict__ lin_p_w,
             const float* __restrict__ W1, const float* __restrict__ W2,
             bf16r* __restrict__ wt)
{
    int t = blockIdx.x >> 6;
    int e = (blockIdx.x & 63) * 256 + threadIdx.x;   // 0..16383
    const float* src;
    if (t == 0) src = lin_a_w;
    else if (t == 1) src = lin_p_w;
    else if (t < 6) src = W1 + (size_t)(t - 2) * HD * HD;
    else src = W2 + (size_t)(t - 6) * HD * HD;
    int n = e >> 7, k = e & 127;
    wt[(size_t)t * HD * HD + e] = f2bf(src[(size_t)k * HD + n]);
}

// ================= CSR build (counting sort by dst) =================
__global__ __launch_bounds__(256)
void count_k(const int* __restrict__ ei, int E, int* cnt) {
    int e = blockIdx.x * 256 + threadIdx.x;
    if (e < E) atomicAdd(&cnt[ei[E + e]], 1);
}

__global__ __launch_bounds__(256)
void scan1_k(const int* __restrict__ in, int* out, int* partial, int n) {
    __shared__ int lds[256];
    int b = blockIdx.x, t = threadIdx.x;
    int base = b * 1024 + t * 4;
    int v0 = 0, v1 = 0, v2 = 0, v3 = 0;
    if (base + 3 < n) {
        int4 x = *(const int4*)(in + base);
        v0 = x.x; v1 = x.y; v2 = x.z; v3 = x.w;
    } else {
        if (base + 0 < n) v0 = in[base + 0];
        if (base + 1 < n) v1 = in[base + 1];
        if (base + 2 < n) v2 = in[base + 2];
        if (base + 3 < n) v3 = in[base + 3];
    }
    int s = v0 + v1 + v2 + v3;
    lds[t] = s;
    __syncthreads();
    for (int d = 1; d < 256; d <<= 1) {
        int x = (t >= d) ? lds[t - d] : 0;
        __syncthreads();
        lds[t] += x;
        __syncthreads();
    }
    int excl = lds[t] - s;
    if (base + 0 < n) out[base + 0] = excl;
    if (base + 1 < n) out[base + 1] = excl + v0;
    if (base + 2 < n) out[base + 2] = excl + v0 + v1;
    if (base + 3 < n) out[base + 3] = excl + v0 + v1 + v2;
    if (t == 255) partial[b] = lds[255];
}

__global__ __launch_bounds__(256)
void scan2_k(int* partial, int n) {
    __shared__ int lds[256];
    int t = threadIdx.x;
    int s = (t < n) ? partial[t] : 0;
    lds[t] = s;
    __syncthreads();
    for (int d = 1; d < 256; d <<= 1) {
        int x = (t >= d) ? lds[t - d] : 0;
        __syncthreads();
        lds[t] += x;
        __syncthreads();
    }
    if (t < n) partial[t] = lds[t] - s;
}

__global__ __launch_bounds__(256)
void scan3_k(int* off, int* cur, const int* __restrict__ partial, int n, int total) {
    int b = blockIdx.x, t = threadIdx.x;
    int add = partial[b];
    int base = b * 1024 + t * 4;
    #pragma unroll
    for (int j = 0; j < 4; ++j) {
        int i = base + j;
        if (i < n) {
            int v = off[i] + add;
            off[i] = v;
            cur[i] = v;
        }
    }
    if (b == 0 && t == 0) off[n] = total;
}

__global__ __launch_bounds__(256)
void fill_k(const int* __restrict__ ei, int E, int* cur, int* bucket) {
    int e = blockIdx.x * 256 + threadIdx.x;
    if (e < E) {
        int d = ei[E + e];
        int p = atomicAdd(&cur[d], 1);
        bucket[p] = ei[e];
    }
}

// combined gather for both graphs: f32 accumulate, bf16 store.
__global__ __launch_bounds__(256)
void gather2_k(const bf16r* __restrict__ hA, const bf16r* __restrict__ hP,
               bf16r* __restrict__ aggP, bf16r* __restrict__ aggA,
               const int* __restrict__ offAP, const int* __restrict__ bktAP,
               const int* __restrict__ offPA, const int* __restrict__ bktPA)
{
    int gw = (blockIdx.x * 256 + threadIdx.x) >> 6;
    int lane = threadIdx.x & 63;
    const bf16r* src; bf16r* agg; const int* off; const int* bkt; int w;
    if (gw < NPP) { src = hA; agg = aggP; off = offAP; bkt = bktAP; w = gw; }
    else          { src = hP; agg = aggA; off = offPA; bkt = bktPA; w = gw - NPP; }
    int s0 = off[w], s1 = off[w + 1];
    float a0 = 0.f, a1 = 0.f;
    int e = s0;
    for (; e + 1 < s1; e += 2) {
        int i0 = bkt[e], i1 = bkt[e + 1];
        ushort2 u = *(const ushort2*)(src + (size_t)i0 * HD + lane * 2);
        ushort2 v = *(const ushort2*)(src + (size_t)i1 * HD + lane * 2);
        a0 += bf2f(u.x) + bf2f(v.x);
        a1 += bf2f(u.y) + bf2f(v.y);
    }
    if (e < s1) {
        ushort2 u = *(const ushort2*)(src + (size_t)bkt[e] * HD + lane * 2);
        a0 += bf2f(u.x);
        a1 += bf2f(u.y);
    }
    ushort2 o;
    o.x = f2bf(a0);
    o.y = f2bf(a1);
    *(ushort2*)(agg + (size_t)w * HD + lane * 2) = o;
}

// fallback scatter (atomics, f32 agg) for tight workspaces
__global__ __launch_bounds__(256)
void scatter_k(const bf16r* __restrict__ src, float* dst,
               const int* __restrict__ ei, int E)
{
    int g = blockIdx.x * 256 + threadIdx.x;
    int e = g >> 5, lane = g & 31;
    if (e >= E) return;
    int s = ei[e], d = ei[E + e];
    ushort4 u = *(const ushort4*)(src + (size_t)s * HD + lane * 4);
    float* dp = dst + (size_t)d * HD + lane * 4;
    unsafeAtomicAdd(dp + 0, bf2f(u.x));
    unsafeAtomicAdd(dp + 1, bf2f(u.y));
    unsafeAtomicAdd(dp + 2, bf2f(u.z));
    unsafeAtomicAdd(dp + 3, bf2f(u.w));
}

// ================= persistent pipelined MFMA GEMM =================
struct SideP {
    const void* in;
    bf16r* out;
    const bf16r* wt;
    const float* bias;
    const void* agg;      // AT-typed (bf16 main path, f32 fallback)
    const float* epsp;
    float* gsum;
    float* gsumsq;
    const float* scale;
    const float* shift;
    const float* mask;
    int M, Nn, tiles;
};

// Per block: weights reg-resident once; loop over tiles with double-buffered
// LDS A-tile, 2-phase pipeline: stage(cur) / barrier / prefetch(t+1)->regs /
// compute(cur). h AND agg both prefetched to regs. GIN1 stats accumulate in
// regs across tiles, one atomic pass per block.
// NOTE: plain __launch_bounds__(256) — forcing min-waves=4 capped VGPR at 64
// and spilled (R7: PROJ 185us @ 5% occupancy). Let the allocator breathe.
template<int MODE, typename IT, typename AT>
__global__ __launch_bounds__(256)
void mfma_gemm(SideP P, SideP A, int BP)
{
    __shared__ bf16r za[2][64][LDA];
    __shared__ float red[2][HD];
    const int tid = threadIdx.x;

    SideP S;
    int t, tstride;
    if ((int)blockIdx.x < BP) { S = P; t = blockIdx.x; tstride = BP; }
    else { S = A; t = (int)blockIdx.x - BP; tstride = NB_GEMM - BP; }
    if (t >= S.tiles) return;   // block-uniform exit

    const int wid = tid >> 6, lane = tid & 63;
    const int lr = lane & 15, lk = (lane >> 4) * 8;
    const int colq = (lane >> 4) * 4, cb = wid * 32;
    const int srow = tid >> 4;          // staging row base (chunk i adds 16*i)
    const int scol = (tid & 15) * 8;    // staging col (same for all chunks)

    float epsv = 1.0f;
    if (MODE == M_GIN1) epsv = 1.0f + S.epsp[0];

    // weights reg-resident (once per block)
    v8s w[2][4];
    #pragma unroll
    for (int cf = 0; cf < 2; ++cf)
        #pragma unroll
        for (int ks = 0; ks < 4; ++ks)
            w[cf][ks] = *(const v8s*)(S.wt + (size_t)(cb + cf * 16 + lr) * HD + ks * 32 + lk);

    const float4 bb0 = *(const float4*)(S.bias + cb + colq);
    const float4 bb1 = *(const float4*)(S.bias + cb + 16 + colq);

    // GIN2: hoist per-thread scale/shift (staging col is tid-invariant)
    float4 sc0h, sc1h, sh0h, sh1h;
    if (MODE == M_GIN2) {
        sc0h = *(const float4*)(S.scale + scol);
        sc1h = *(const float4*)(S.scale + scol + 4);
        sh0h = *(const float4*)(S.shift + scol);
        sh1h = *(const float4*)(S.shift + scol + 4);
    }

    float st_s[2][4], st_q[2][4];
    if (MODE == M_GIN1) {
        #pragma unroll
        for (int cf = 0; cf < 2; ++cf)
            #pragma unroll
            for (int j = 0; j < 4; ++j) { st_s[cf][j] = 0.f; st_q[cf][j] = 0.f; }
    }

    constexpr int NVH = (MODE == M_PROJ) ? 2 : 1;   // int4 words for h row-chunk
    constexpr bool PAGG = (MODE == M_GIN1);
    constexpr int NVA = (PAGG && sizeof(AT) == 4) ? 2 : 1;
    int4 pre[4][NVH];
    int4 preA[4][NVA];

    auto prefetch = [&](int tt) {
        int m0n = tt * 64;
        #pragma unroll
        for (int i = 0; i < 4; ++i) {
            int gr = m0n + srow + 16 * i;
            if (gr < S.M) {
                const int4* p = (const int4*)((const IT*)S.in + (size_t)gr * HD + scol);
                pre[i][0] = p[0];
                if constexpr (NVH == 2) pre[i][1] = p[1];
            } else {
                pre[i][0] = make_int4(0, 0, 0, 0);
                if constexpr (NVH == 2) pre[i][1] = make_int4(0, 0, 0, 0);
            }
            if constexpr (PAGG) {
                if (gr < S.Nn) {
                    const int4* pa = (const int4*)((const AT*)S.agg + (size_t)gr * HD + scol);
                    preA[i][0] = pa[0];
                    if constexpr (NVA == 2) preA[i][1] = pa[1];
                } else {
                    preA[i][0] = make_int4(0, 0, 0, 0);
                    if constexpr (NVA == 2) preA[i][1] = make_int4(0, 0, 0, 0);
                }
            }
        }
    };

    prefetch(t);

    int cur = 0;
    for (;;) {
        const int m0 = t * 64;
        // ---- stage: transform pre -> za[cur] ----
        #pragma unroll
        for (int i = 0; i < 4; ++i) {
            int row = srow + 16 * i;
            float v[8];
            if constexpr (NVH == 2) {
                const float* pf = (const float*)&pre[i][0];
                #pragma unroll
                for (int j = 0; j < 8; ++j) v[j] = pf[j];
            } else {
                const bf16r* pu = (const bf16r*)&pre[i][0];
                #pragma unroll
                for (int j = 0; j < 8; ++j) v[j] = bf2f(pu[j]);
            }
            if constexpr (MODE == M_GIN1) {
                float av[8];
                if constexpr (sizeof(AT) == 4) {
                    const float* pa = (const float*)&preA[i][0];
                    #pragma unroll
                    for (int j = 0; j < 8; ++j) av[j] = pa[j];
                } else {
                    const bf16r* pa = (const bf16r*)&preA[i][0];
                    #pragma unroll
                    for (int j = 0; j < 8; ++j) av[j] = bf2f(pa[j]);
                }
                #pragma unroll
                for (int j = 0; j < 8; ++j) v[j] = v[j] * epsv + av[j];
            } else if constexpr (MODE == M_GIN2) {
                v[0] = fmaxf(v[0] * sc0h.x + sh0h.x, 0.f);
                v[1] = fmaxf(v[1] * sc0h.y + sh0h.y, 0.f);
                v[2] = fmaxf(v[2] * sc0h.z + sh0h.z, 0.f);
                v[3] = fmaxf(v[3] * sc0h.w + sh0h.w, 0.f);
                v[4] = fmaxf(v[4] * sc1h.x + sh1h.x, 0.f);
                v[5] = fmaxf(v[5] * sc1h.y + sh1h.y, 0.f);
                v[6] = fmaxf(v[6] * sc1h.z + sh1h.z, 0.f);
                v[7] = fmaxf(v[7] * sc1h.w + sh1h.w, 0.f);
            }
            union { v8s w8; bf16r u[8]; } pk;
            #pragma unroll
            for (int j = 0; j < 8; ++j) pk.u[j] = f2bf(v[j]);
            *(v8s*)&za[cur][row][scol] = pk.w8;
        }
        __syncthreads();

        // ---- prefetch next tile (after barrier -> stays in flight) ----
        const int tn = t + tstride;
        const bool more = tn < S.tiles;
        if (more) prefetch(tn);

        // ---- compute ----
        v4f acc[2][4];
        #pragma unroll
        for (int cf = 0; cf < 2; ++cf)
            #pragma unroll
            for (int rf = 0; rf < 4; ++rf) acc[cf][rf] = (v4f){0.f, 0.f, 0.f, 0.f};

        #pragma unroll
        for (int ks = 0; ks < 4; ++ks)
            #pragma unroll
            for (int rf = 0; rf < 4; ++rf) {
                v8s a = *(const v8s*)&za[cur][rf * 16 + lr][ks * 32 + lk];
                acc[0][rf] = __builtin_amdgcn_mfma_f32_16x16x32_bf16(w[0][ks], a, acc[0][rf], 0, 0, 0);
                acc[1][rf] = __builtin_amdgcn_mfma_f32_16x16x32_bf16(w[1][ks], a, acc[1][rf], 0, 0, 0);
            }

        #pragma unroll
        for (int rf = 0; rf < 4; ++rf) {
            acc[0][rf][0] += bb0.x; acc[0][rf][1] += bb0.y;
            acc[0][rf][2] += bb0.z; acc[0][rf][3] += bb0.w;
            acc[1][rf][0] += bb1.x; acc[1][rf][1] += bb1.y;
            acc[1][rf][2] += bb1.z; acc[1][rf][3] += bb1.w;
        }

        if constexpr (MODE == M_PROJ) {
            #pragma unroll
            for (int rf = 0; rf < 4; ++rf) {
                int grow = m0 + rf * 16 + lr;
                if (grow < S.M) {
                    #pragma unroll
                    for (int run = 0; run < NRUNS; ++run) {
                        float wm = S.mask[(size_t)run * S.Nn + grow] * INV_KEEP;
                        #pragma unroll
                        for (int cf = 0; cf < 2; ++cf) {
                            ushort4 o;
                            o.x = f2bf(acc[cf][rf][0] * wm);
                            o.y = f2bf(acc[cf][rf][1] * wm);
                            o.z = f2bf(acc[cf][rf][2] * wm);
                            o.w = f2bf(acc[cf][rf][3] * wm);
                            *(ushort4*)(S.out + ((size_t)run * S.Nn + grow) * HD + cb + cf * 16 + colq) = o;
                        }
                    }
                }
            }
        } else if constexpr (MODE == M_GIN1) {
            #pragma unroll
            for (int rf = 0; rf < 4; ++rf) {
                int grow = m0 + rf * 16 + lr;
                #pragma unroll
                for (int cf = 0; cf < 2; ++cf) {
                    ushort4 o;
                    o.x = f2bf(acc[cf][rf][0]);
                    o.y = f2bf(acc[cf][rf][1]);
                    o.z = f2bf(acc[cf][rf][2]);
                    o.w = f2bf(acc[cf][rf][3]);
                    *(ushort4*)(S.out + (size_t)grow * HD + cb + cf * 16 + colq) = o;
                }
            }
            #pragma unroll
            for (int cf = 0; cf < 2; ++cf)
                #pragma unroll
                for (int j = 0; j < 4; ++j)
                    #pragma unroll
                    for (int rf = 0; rf < 4; ++rf) {
                        float vv = acc[cf][rf][j];
                        st_s[cf][j] += vv;
                        st_q[cf][j] += vv * vv;
                    }
        } else {  // M_GIN2
            #pragma unroll
            for (int rf = 0; rf < 4; ++rf) {
                int grow = m0 + rf * 16 + lr;
                #pragma unroll
                for (int cf = 0; cf < 2; ++cf) {
                    ushort4 o;
                    o.x = f2bf(fmaxf(acc[cf][rf][0], 0.f));
                    o.y = f2bf(fmaxf(acc[cf][rf][1], 0.f));
                    o.z = f2bf(fmaxf(acc[cf][rf][2], 0.f));
                    o.w = f2bf(fmaxf(acc[cf][rf][3], 0.f));
                    *(ushort4*)(S.out + (size_t)grow * HD + cb + cf * 16 + colq) = o;
                }
            }
        }

        if (!more) break;
        t = tn;
        cur ^= 1;
    }

    if constexpr (MODE == M_GIN1) {
        #pragma unroll
        for (int d = 1; d < 16; d <<= 1)
            #pragma unroll
            for (int cf = 0; cf < 2; ++cf)
                #pragma unroll
                for (int j = 0; j < 4; ++j) {
                    st_s[cf][j] += __shfl_xor(st_s[cf][j], d);
                    st_q[cf][j] += __shfl_xor(st_q[cf][j], d);
                }
        if (lr == 0) {
            #pragma unroll
            for (int cf = 0; cf < 2; ++cf)
                #pragma unroll
                for (int j = 0; j < 4; ++j) {
                    red[0][cb + cf * 16 + colq + j] = st_s[cf][j];
                    red[1][cb + cf * 16 + colq + j] = st_q[cf][j];
                }
        }
        __syncthreads();
        if (tid < HD) {
            unsafeAtomicAdd(S.gsum + tid, red[0][tid]);
            unsafeAtomicAdd(S.gsumsq + tid, red[1][tid]);
        }
    }
}

// BN stats -> scale/shift for BOTH sides; re-zeros accumulators
__global__ void finalize2_k(float* gsP, float* gsqP, const float* gamP, const float* betP,
                            float* scP, float* shP, float invNP,
                            float* gsA, float* gsqA, const float* gamA, const float* betA,
                            float* scA, float* shA, float invNA)
{
    int c = threadIdx.x;
    float *gs, *gsq, *sc, *sh;
    const float *gm, *bt;
    float invN;
    if (c < HD) { gs = gsP; gsq = gsqP; gm = gamP; bt = betP; sc = scP; sh = shP; invN = invNP; }
    else { c -= HD; gs = gsA; gsq = gsqA; gm = gamA; bt = betA; sc = scA; sh = shA; invN = invNA; }
    float mu = gs[c] * invN;
    float var = gsq[c] * invN - mu * mu;
    float s = gm[c] * rsqrtf(var + BN_EPS);
    sc[c] = s;
    sh[c] = bt[c] - mu * s;
    gs[c] = 0.f;
    gsq[c] = 0.f;
}

// mean over runs + [128]x[128,4] matmul; one wave per author node
__global__ __launch_bounds__(256)
void final_k(const bf16r* __restrict__ ha, const float* __restrict__ fw,
             const float* __restrict__ fb, float* __restrict__ out)
{
    int g = blockIdx.x * 256 + threadIdx.x;
    int node = g >> 6, lane = g & 63;
    if (node >= NAU) return;
    float m0 = 0.f, m1 = 0.f;
    #pragma unroll
    for (int r = 0; r < NRUNS; ++r) {
        size_t base = ((size_t)r * NAU + node) * HD;
        m0 += bf2f(ha[base + lane]);
        m1 += bf2f(ha[base + 64 + lane]);
    }
    m0 *= 0.25f;
    m1 *= 0.25f;
    float p[4];
    #pragma unroll
    for (int c = 0; c < 4; ++c)
        p[c] = m0 * fw[lane * 4 + c] + m1 * fw[(lane + 64) * 4 + c];
    #pragma unroll
    for (int off = 32; off >= 1; off >>= 1)
        #pragma unroll
        for (int c = 0; c < 4; ++c) p[c] += __shfl_down(p[c], off);
    if (lane == 0) {
        #pragma unroll
        for (int c = 0; c < 4; ++c) out[(size_t)node * 4 + c] = p[c] + fb[c];
    }
}

#define CSR_INTS ((size_t)(NPP + 4) + NEDGE + (NAU + 4) + NEDGE)
#define WT_ELEMS ((size_t)10 * HD * HD)

template<bool GATHER>
static void run_all(void* const* d_in, void* d_out, void* d_ws, hipStream_t stream)
{
    const float* x_author = (const float*)d_in[0];
    const float* x_paper  = (const float*)d_in[1];
    const int*   ei_ap    = (const int*)d_in[2];
    const int*   ei_pa    = (const int*)d_in[3];
    const float* drop_a   = (const float*)d_in[4];
    const float* drop_p   = (const float*)d_in[5];
    const float* lin_a_w  = (const float*)d_in[6];
    const float* lin_a_b  = (const float*)d_in[7];
    const float* lin_p_w  = (const float*)d_in[8];
    const float* lin_p_b  = (const float*)d_in[9];
    const float* W1       = (const float*)d_in[10];
    const float* B1       = (const float*)d_in[11];
    const float* G        = (const float*)d_in[12];
    const float* BT       = (const float*)d_in[13];
    const float* W2       = (const float*)d_in[14];
    const float* B2       = (const float*)d_in[15];
    const float* EPS      = (const float*)d_in[16];
    const float* fw       = (const float*)d_in[17];
    const float* fb       = (const float*)d_in[18];

    // ws: [stats 8*HD f32][Wt][CSR (gather only)][agg][h_a][h_p]
    float* gsumP   = (float*)d_ws;
    float* gsumsqP = gsumP + HD;
    float* gsumA   = gsumP + 2 * HD;
    float* gsumsqA = gsumP + 3 * HD;
    float* scP     = gsumP + 4 * HD;
    float* shP     = gsumP + 5 * HD;
    float* scA     = gsumP + 6 * HD;
    float* shA     = gsumP + 7 * HD;
    bf16r* wt = (bf16r*)(gsumP + 8 * HD);
    char* cp = (char*)(wt + WT_ELEMS);

    int *off_ap = nullptr, *bkt_ap = nullptr, *off_pa = nullptr, *bkt_pa = nullptr;
    if (GATHER) {
        int* ip = (int*)cp;
        off_ap = ip;  ip += NPP + 4;
        bkt_ap = ip;  ip += NEDGE;
        off_pa = ip;  ip += NAU + 4;
        bkt_pa = ip;  ip += NEDGE;
        cp = (char*)ip;
    }
    // agg: bf16 on gather path, f32 on fallback
    void* agg_a_v = cp;
    size_t aggElem = GATHER ? sizeof(bf16r) : sizeof(float);
    void* agg_p_v = cp + (size_t)NAU * HD * aggElem;
    bf16r* h_a = (bf16r*)(cp + (size_t)(NAU + NPP) * HD * aggElem);
    bf16r* h_p = h_a + (size_t)NRUNS * NAU * HD;

    const bf16r* wt_lin_a = wt;
    const bf16r* wt_lin_p = wt + (size_t)1 * HD * HD;
    const bf16r* wt_W1    = wt + (size_t)2 * HD * HD;
    const bf16r* wt_W2    = wt + (size_t)6 * HD * HD;

    convw_k<<<640, 256, 0, stream>>>(lin_a_w, lin_p_w, W1, W2, wt);
    zero_k<<<1, 256, 0, stream>>>(gsumP, (4 * HD) / 4);

    if (GATHER) {
        int* cur_ap  = (int*)agg_a_v;   // alias agg area pre-gather
        int* cur_pa  = cur_ap + NPP;
        int* partial = cur_pa + NAU;
        {
            int nchunk = (NPP + 1023) / 1024;
            zero_k<<<64, 256, 0, stream>>>((float*)cur_ap, NPP / 4);
            count_k<<<(NEDGE + 255) / 256, 256, 0, stream>>>(ei_ap, NEDGE, cur_ap);
            scan1_k<<<nchunk, 256, 0, stream>>>(cur_ap, off_ap, partial, NPP);
            scan2_k<<<1, 256, 0, stream>>>(partial, nchunk);
            scan3_k<<<nchunk, 256, 0, stream>>>(off_ap, cur_ap, partial, NPP, NEDGE);
            fill_k<<<(NEDGE + 255) / 256, 256, 0, stream>>>(ei_ap, NEDGE, cur_ap, bkt_ap);
        }
        {
            int nchunk = (NAU + 1023) / 1024;
            zero_k<<<64, 256, 0, stream>>>((float*)cur_pa, NAU / 4);
            count_k<<<(NEDGE + 255) / 256, 256, 0, stream>>>(ei_pa, NEDGE, cur_pa);
            scan1_k<<<nchunk, 256, 0, stream>>>(cur_pa, off_pa, partial, NAU);
            scan2_k<<<1, 256, 0, stream>>>(partial, nchunk);
            scan3_k<<<nchunk, 256, 0, stream>>>(off_pa, cur_pa, partial, NAU, NEDGE);
            fill_k<<<(NEDGE + 255) / 256, 256, 0, stream>>>(ei_pa, NEDGE, cur_pa, bkt_pa);
        }
    }

    // ---- combined PROJ ----
    SideP Pp = {};
    Pp.in = x_paper; Pp.out = h_p; Pp.wt = wt_lin_p; Pp.bias = lin_p_b;
    Pp.mask = drop_p; Pp.M = NPP; Pp.Nn = NPP; Pp.tiles = (NPP + 63) / 64;
    SideP Pa = {};
    Pa.in = x_author; Pa.out = h_a; Pa.wt = wt_lin_a; Pa.bias = lin_a_b;
    Pa.mask = drop_a; Pa.M = NAU; Pa.Nn = NAU; Pa.tiles = (NAU + 63) / 64;
    int BPproj = (int)((long)NB_GEMM * Pp.tiles / (Pp.tiles + Pa.tiles));
    mfma_gemm<M_PROJ, float, bf16r><<<NB_GEMM, 256, 0, stream>>>(Pp, Pa, BPproj);

    const int TP = NRUNS * NPP / 64, TA = NRUNS * NAU / 64;
    const int BPgin = (int)((long)NB_GEMM * TP / (TP + TA));

    for (int l = 0; l < 2; ++l) {
        int t0 = l * 2 + 0, t1 = l * 2 + 1;

        if (GATHER) {
            gather2_k<<<((NPP + NAU) * 64) / 256, 256, 0, stream>>>(
                h_a, h_p, (bf16r*)agg_p_v, (bf16r*)agg_a_v,
                off_ap, bkt_ap, off_pa, bkt_pa);
        } else {
            zero_k<<<2048, 256, 0, stream>>>((float*)agg_a_v, ((size_t)(NAU + NPP) * HD) / 4);
            scatter_k<<<(NEDGE * 32) / 256, 256, 0, stream>>>(h_a, (float*)agg_p_v, ei_ap, NEDGE);
            scatter_k<<<(NEDGE * 32) / 256, 256, 0, stream>>>(h_p, (float*)agg_a_v, ei_pa, NEDGE);
        }

        // combined GIN1
        SideP G1p = {};
        G1p.in = h_p; G1p.out = h_p; G1p.wt = wt_W1 + (size_t)t0 * HD * HD;
        G1p.bias = B1 + (size_t)t0 * HD; G1p.agg = agg_p_v; G1p.epsp = EPS + t0;
        G1p.gsum = gsumP; G1p.gsumsq = gsumsqP;
        G1p.M = NRUNS * NPP; G1p.Nn = NPP; G1p.tiles = TP;
        SideP G1a = {};
        G1a.in = h_a; G1a.out = h_a; G1a.wt = wt_W1 + (size_t)t1 * HD * HD;
        G1a.bias = B1 + (size_t)t1 * HD; G1a.agg = agg_a_v; G1a.epsp = EPS + t1;
        G1a.gsum = gsumA; G1a.gsumsq = gsumsqA;
        G1a.M = NRUNS * NAU; G1a.Nn = NAU; G1a.tiles = TA;
        if (GATHER)
            mfma_gemm<M_GIN1, bf16r, bf16r><<<NB_GEMM, 256, 0, stream>>>(G1p, G1a, BPgin);
        else
            mfma_gemm<M_GIN1, bf16r, float><<<NB_GEMM, 256, 0, stream>>>(G1p, G1a, BPgin);

        finalize2_k<<<1, 256, 0, stream>>>(
            gsumP, gsumsqP, G + (size_t)t0 * HD, BT + (size_t)t0 * HD, scP, shP,
            1.0f / (NRUNS * NPP),
            gsumA, gsumsqA, G + (size_t)t1 * HD, BT + (size_t)t1 * HD, scA, shA,
            1.0f / (NRUNS * NAU));

        // combined GIN2
        SideP G2p = {};
        G2p.in = h_p; G2p.out = h_p; G2p.wt = wt_W2 + (size_t)t0 * HD * HD;
        G2p.bias = B2 + (size_t)t0 * HD; G2p.scale = scP; G2p.shift = shP;
        G2p.M = NRUNS * NPP; G2p.Nn = NPP; G2p.tiles = TP;
        SideP G2a = {};
        G2a.in = h_a; G2a.out = h_a; G2a.wt = wt_W2 + (size_t)t1 * HD * HD;
        G2a.bias = B2 + (size_t)t1 * HD; G2a.scale = scA; G2a.shift = shA;
        G2a.M = NRUNS * NAU; G2a.Nn = NAU; G2a.tiles = TA;
        mfma_gemm<M_GIN2, bf16r, bf16r><<<NB_GEMM, 256, 0, stream>>>(G2p, G2a, BPgin);
    }

    final_k<<<(NAU * 64) / 256, 256, 0, stream>>>(h_a, fw, fb, (float*)d_out);
}

extern "C" void kernel_launch(void* const* d_in, const int* in_sizes, int n_in,
                              void* d_out, int out_size, void* d_ws, size_t ws_size,
                              hipStream_t stream)
{
    const size_t hB    = (size_t)NRUNS * (NAU + NPP) * HD * sizeof(bf16r);
    const size_t statB = 8 * HD * sizeof(float);
    const size_t wtB   = WT_ELEMS * sizeof(bf16r);
    const size_t csrB  = CSR_INTS * sizeof(int);
    const size_t aggBF = (size_t)(NAU + NPP) * HD * sizeof(bf16r);

    const size_t need_gather = statB + wtB + csrB + aggBF + hB;   // ~197 MB
    if (ws_size >= need_gather) {
        run_all<true>(d_in, d_out, d_ws, stream);
    } else {
        run_all<false>(d_in, d_out, d_ws, stream);                // atomic fallback
    }
}

// Round 9
// 649.981 us; speedup vs baseline: 7.5068x; 1.0286x over previous
//
#include <hip/hip_runtime.h>

#define NRUNS 4
#define NAU 50000
#define NPP 100000
#define NEDGE 500000
#define HD 128
#define INV_KEEP 1.25f
#define BN_EPS 1e-5f
#define LDA 136      // padded LDS row (bf16 elems), 272B
#define NB_GEMM 1536 // persistent GEMM grid (6 blocks/CU, VGPR-bound)

#define M_PROJ 0
#define M_GIN1 1
#define M_GIN2 2

typedef unsigned short bf16r;
typedef __attribute__((ext_vector_type(8))) short v8s;   // 8 bf16 (4 VGPR)
typedef __attribute__((ext_vector_type(4))) float v4f;   // 4 f32 acc

__device__ inline float bf2f(bf16r u) {
    return __uint_as_float(((unsigned)u) << 16);
}
// native RNE f32->bf16 (v_cvt on gfx950)
__device__ inline bf16r f2bf(float f) {
    __bf16 b = (__bf16)f;
    return __builtin_bit_cast(bf16r, b);
}

// grid-stride float4 zero fill
__global__ __launch_bounds__(256)
void zero_k(float* p, long n4) {
    long i = (long)blockIdx.x * 256 + threadIdx.x;
    long stride = (long)gridDim.x * 256;
    float4 z = make_float4(0.f, 0.f, 0.f, 0.f);
    for (; i < n4; i += stride) ((float4*)p)[i] = z;
}

// ============ weight convert: f32 [k][n] -> bf16 transposed [n][k] ============
__global__ __launch_bounds__(256)
void convw_k(const float* __restrict__ lin_a_w, const float* __restrict__ lin_p_w,
             const float* __restrict__ W1, const float* __restrict__ W2,
             bf16r* __restrict__ wt)
{
    int t = blockIdx.x >> 6;
    int e = (blockIdx.x & 63) * 256 + threadIdx.x;   // 0..16383
    const float* src;
    if (t == 0) src = lin_a_w;
    else if (t == 1) src = lin_p_w;
    else if (t < 6) src = W1 + (size_t)(t - 2) * HD * HD;
    else src = W2 + (size_t)(t - 6) * HD * HD;
    int n = e >> 7, k = e & 127;
    wt[(size_t)t * HD * HD + e] = f2bf(src[(size_t)k * HD + n]);
}

// ================= CSR build (counting sort by dst) =================
__global__ __launch_bounds__(256)
void count_k(const int* __restrict__ ei, int E, int* cnt) {
    int e = blockIdx.x * 256 + threadIdx.x;
    if (e < E) atomicAdd(&cnt[ei[E + e]], 1);
}

__global__ __launch_bounds__(256)
void scan1_k(const int* __restrict__ in, int* out, int* partial, int n) {
    __shared__ int lds[256];
    int b = blockIdx.x, t = threadIdx.x;
    int base = b * 1024 + t * 4;
    int v0 = 0, v1 = 0, v2 = 0, v3 = 0;
    if (base + 3 < n) {
        int4 x = *(const int4*)(in + base);
        v0 = x.x; v1 = x.y; v2 = x.z; v3 = x.w;
    } else {
        if (base + 0 < n) v0 = in[base + 0];
        if (base + 1 < n) v1 = in[base + 1];
        if (base + 2 < n) v2 = in[base + 2];
        if (base + 3 < n) v3 = in[base + 3];
    }
    int s = v0 + v1 + v2 + v3;
    lds[t] = s;
    __syncthreads();
    for (int d = 1; d < 256; d <<= 1) {
        int x = (t >= d) ? lds[t - d] : 0;
        __syncthreads();
        lds[t] += x;
        __syncthreads();
    }
    int excl = lds[t] - s;
    if (base + 0 < n) out[base + 0] = excl;
    if (base + 1 < n) out[base + 1] = excl + v0;
    if (base + 2 < n) out[base + 2] = excl + v0 + v1;
    if (base + 3 < n) out[base + 3] = excl + v0 + v1 + v2;
    if (t == 255) partial[b] = lds[255];
}

__global__ __launch_bounds__(256)
void scan2_k(int* partial, int n) {
    __shared__ int lds[256];
    int t = threadIdx.x;
    int s = (t < n) ? partial[t] : 0;
    lds[t] = s;
    __syncthreads();
    for (int d = 1; d < 256; d <<= 1) {
        int x = (t >= d) ? lds[t - d] : 0;
        __syncthreads();
        lds[t] += x;
        __syncthreads();
    }
    if (t < n) partial[t] = lds[t] - s;
}

__global__ __launch_bounds__(256)
void scan3_k(int* off, int* cur, const int* __restrict__ partial, int n, int total) {
    int b = blockIdx.x, t = threadIdx.x;
    int add = partial[b];
    int base = b * 1024 + t * 4;
    #pragma unroll
    for (int j = 0; j < 4; ++j) {
        int i = base + j;
        if (i < n) {
            int v = off[i] + add;
            off[i] = v;
            cur[i] = v;
        }
    }
    if (b == 0 && t == 0) off[n] = total;
}

__global__ __launch_bounds__(256)
void fill_k(const int* __restrict__ ei, int E, int* cur, int* bucket) {
    int e = blockIdx.x * 256 + threadIdx.x;
    if (e < E) {
        int d = ei[E + e];
        int p = atomicAdd(&cur[d], 1);
        bucket[p] = ei[e];
    }
}

// combined gather for both graphs: f32 accumulate, bf16 store.
__global__ __launch_bounds__(256)
void gather2_k(const bf16r* __restrict__ hA, const bf16r* __restrict__ hP,
               bf16r* __restrict__ aggP, bf16r* __restrict__ aggA,
               const int* __restrict__ offAP, const int* __restrict__ bktAP,
               const int* __restrict__ offPA, const int* __restrict__ bktPA)
{
    int gw = (blockIdx.x * 256 + threadIdx.x) >> 6;
    int lane = threadIdx.x & 63;
    const bf16r* src; bf16r* agg; const int* off; const int* bkt; int w;
    if (gw < NPP) { src = hA; agg = aggP; off = offAP; bkt = bktAP; w = gw; }
    else          { src = hP; agg = aggA; off = offPA; bkt = bktPA; w = gw - NPP; }
    int s0 = off[w], s1 = off[w + 1];
    float a0 = 0.f, a1 = 0.f;
    int e = s0;
    for (; e + 1 < s1; e += 2) {
        int i0 = bkt[e], i1 = bkt[e + 1];
        ushort2 u = *(const ushort2*)(src + (size_t)i0 * HD + lane * 2);
        ushort2 v = *(const ushort2*)(src + (size_t)i1 * HD + lane * 2);
        a0 += bf2f(u.x) + bf2f(v.x);
        a1 += bf2f(u.y) + bf2f(v.y);
    }
    if (e < s1) {
        ushort2 u = *(const ushort2*)(src + (size_t)bkt[e] * HD + lane * 2);
        a0 += bf2f(u.x);
        a1 += bf2f(u.y);
    }
    ushort2 o;
    o.x = f2bf(a0);
    o.y = f2bf(a1);
    *(ushort2*)(agg + (size_t)w * HD + lane * 2) = o;
}

// fallback scatter (atomics, f32 agg) for tight workspaces
__global__ __launch_bounds__(256)
void scatter_k(const bf16r* __restrict__ src, float* dst,
               const int* __restrict__ ei, int E)
{
    int g = blockIdx.x * 256 + threadIdx.x;
    int e = g >> 5, lane = g & 31;
    if (e >= E) return;
    int s = ei[e], d = ei[E + e];
    ushort4 u = *(const ushort4*)(src + (size_t)s * HD + lane * 4);
    float* dp = dst + (size_t)d * HD + lane * 4;
    unsafeAtomicAdd(dp + 0, bf2f(u.x));
    unsafeAtomicAdd(dp + 1, bf2f(u.y));
    unsafeAtomicAdd(dp + 2, bf2f(u.z));
    unsafeAtomicAdd(dp + 3, bf2f(u.w));
}

// ================= persistent pipelined MFMA GEMM =================
struct SideP {
    const void* in;
    bf16r* out;
    const bf16r* wt;
    const float* bias;
    const void* agg;      // AT-typed (bf16 main path, f32 fallback)
    const float* epsp;
    float* gsum;
    float* gsumsq;
    const float* scale;
    const float* shift;
    const float* mask;
    int M, Nn, tiles;
};

// Per block: weights reg-resident once; loop over tiles with SINGLE-buffered
// LDS A-tile (17.4KB -> 6 blocks/CU at VGPR=80, was 4 with double-buffer) and
// 2-barrier schedule: stage / barrier / prefetch(t+1)->regs / compute /
// barrier. Register prefetch still hides HBM under compute; cross-block
// overlap (6/CU) covers the barrier stalls.
template<int MODE, typename IT, typename AT>
__global__ __launch_bounds__(256)
void mfma_gemm(SideP P, SideP A, int BP)
{
    __shared__ bf16r za[64][LDA];
    __shared__ float red[2][HD];
    const int tid = threadIdx.x;

    SideP S;
    int t, tstride;
    if ((int)blockIdx.x < BP) { S = P; t = blockIdx.x; tstride = BP; }
    else { S = A; t = (int)blockIdx.x - BP; tstride = NB_GEMM - BP; }
    if (t >= S.tiles) return;   // block-uniform exit

    const int wid = tid >> 6, lane = tid & 63;
    const int lr = lane & 15, lk = (lane >> 4) * 8;
    const int colq = (lane >> 4) * 4, cb = wid * 32;
    const int srow = tid >> 4;          // staging row base (chunk i adds 16*i)
    const int scol = (tid & 15) * 8;    // staging col (same for all chunks)

    float epsv = 1.0f;
    if (MODE == M_GIN1) epsv = 1.0f + S.epsp[0];

    // weights reg-resident (once per block)
    v8s w[2][4];
    #pragma unroll
    for (int cf = 0; cf < 2; ++cf)
        #pragma unroll
        for (int ks = 0; ks < 4; ++ks)
            w[cf][ks] = *(const v8s*)(S.wt + (size_t)(cb + cf * 16 + lr) * HD + ks * 32 + lk);

    const float4 bb0 = *(const float4*)(S.bias + cb + colq);
    const float4 bb1 = *(const float4*)(S.bias + cb + 16 + colq);

    // GIN2: hoist per-thread scale/shift (staging col is tid-invariant)
    float4 sc0h, sc1h, sh0h, sh1h;
    if (MODE == M_GIN2) {
        sc0h = *(const float4*)(S.scale + scol);
        sc1h = *(const float4*)(S.scale + scol + 4);
        sh0h = *(const float4*)(S.shift + scol);
        sh1h = *(const float4*)(S.shift + scol + 4);
    }

    float st_s[2][4], st_q[2][4];
    if (MODE == M_GIN1) {
        #pragma unroll
        for (int cf = 0; cf < 2; ++cf)
            #pragma unroll
            for (int j = 0; j < 4; ++j) { st_s[cf][j] = 0.f; st_q[cf][j] = 0.f; }
    }

    constexpr int NVH = (MODE == M_PROJ) ? 2 : 1;   // int4 words for h row-chunk
    constexpr bool PAGG = (MODE == M_GIN1);
    constexpr int NVA = (PAGG && sizeof(AT) == 4) ? 2 : 1;
    int4 pre[4][NVH];
    int4 preA[4][NVA];

    auto prefetch = [&](int tt) {
        int m0n = tt * 64;
        #pragma unroll
        for (int i = 0; i < 4; ++i) {
            int gr = m0n + srow + 16 * i;
            if (gr < S.M) {
                const int4* p = (const int4*)((const IT*)S.in + (size_t)gr * HD + scol);
                pre[i][0] = p[0];
                if constexpr (NVH == 2) pre[i][1] = p[1];
            } else {
                pre[i][0] = make_int4(0, 0, 0, 0);
                if constexpr (NVH == 2) pre[i][1] = make_int4(0, 0, 0, 0);
            }
            if constexpr (PAGG) {
                if (gr < S.Nn) {
                    const int4* pa = (const int4*)((const AT*)S.agg + (size_t)gr * HD + scol);
                    preA[i][0] = pa[0];
                    if constexpr (NVA == 2) preA[i][1] = pa[1];
                } else {
                    preA[i][0] = make_int4(0, 0, 0, 0);
                    if constexpr (NVA == 2) preA[i][1] = make_int4(0, 0, 0, 0);
                }
            }
        }
    };

    prefetch(t);

    for (;;) {
        const int m0 = t * 64;
        // ---- stage: transform pre -> za ----
        #pragma unroll
        for (int i = 0; i < 4; ++i) {
            int row = srow + 16 * i;
            float v[8];
            if constexpr (NVH == 2) {
                const float* pf = (const float*)&pre[i][0];
                #pragma unroll
                for (int j = 0; j < 8; ++j) v[j] = pf[j];
            } else {
                const bf16r* pu = (const bf16r*)&pre[i][0];
                #pragma unroll
                for (int j = 0; j < 8; ++j) v[j] = bf2f(pu[j]);
            }
            if constexpr (MODE == M_GIN1) {
                float av[8];
                if constexpr (sizeof(AT) == 4) {
                    const float* pa = (const float*)&preA[i][0];
                    #pragma unroll
                    for (int j = 0; j < 8; ++j) av[j] = pa[j];
                } else {
                    const bf16r* pa = (const bf16r*)&preA[i][0];
                    #pragma unroll
                    for (int j = 0; j < 8; ++j) av[j] = bf2f(pa[j]);
                }
                #pragma unroll
                for (int j = 0; j < 8; ++j) v[j] = v[j] * epsv + av[j];
            } else if constexpr (MODE == M_GIN2) {
                v[0] = fmaxf(v[0] * sc0h.x + sh0h.x, 0.f);
                v[1] = fmaxf(v[1] * sc0h.y + sh0h.y, 0.f);
                v[2] = fmaxf(v[2] * sc0h.z + sh0h.z, 0.f);
                v[3] = fmaxf(v[3] * sc0h.w + sh0h.w, 0.f);
                v[4] = fmaxf(v[4] * sc1h.x + sh1h.x, 0.f);
                v[5] = fmaxf(v[5] * sc1h.y + sh1h.y, 0.f);
                v[6] = fmaxf(v[6] * sc1h.z + sh1h.z, 0.f);
                v[7] = fmaxf(v[7] * sc1h.w + sh1h.w, 0.f);
            }
            union { v8s w8; bf16r u[8]; } pk;
            #pragma unroll
            for (int j = 0; j < 8; ++j) pk.u[j] = f2bf(v[j]);
            *(v8s*)&za[row][scol] = pk.w8;
        }
        __syncthreads();

        // ---- prefetch next tile (after barrier -> stays in flight) ----
        const int tn = t + tstride;
        const bool more = tn < S.tiles;
        if (more) prefetch(tn);

        // ---- compute ----
        v4f acc[2][4];
        #pragma unroll
        for (int cf = 0; cf < 2; ++cf)
            #pragma unroll
            for (int rf = 0; rf < 4; ++rf) acc[cf][rf] = (v4f){0.f, 0.f, 0.f, 0.f};

        #pragma unroll
        for (int ks = 0; ks < 4; ++ks)
            #pragma unroll
            for (int rf = 0; rf < 4; ++rf) {
                v8s a = *(const v8s*)&za[rf * 16 + lr][ks * 32 + lk];
                acc[0][rf] = __builtin_amdgcn_mfma_f32_16x16x32_bf16(w[0][ks], a, acc[0][rf], 0, 0, 0);
                acc[1][rf] = __builtin_amdgcn_mfma_f32_16x16x32_bf16(w[1][ks], a, acc[1][rf], 0, 0, 0);
            }

        #pragma unroll
        for (int rf = 0; rf < 4; ++rf) {
            acc[0][rf][0] += bb0.x; acc[0][rf][1] += bb0.y;
            acc[0][rf][2] += bb0.z; acc[0][rf][3] += bb0.w;
            acc[1][rf][0] += bb1.x; acc[1][rf][1] += bb1.y;
            acc[1][rf][2] += bb1.z; acc[1][rf][3] += bb1.w;
        }

        if constexpr (MODE == M_PROJ) {
            #pragma unroll
            for (int rf = 0; rf < 4; ++rf) {
                int grow = m0 + rf * 16 + lr;
                if (grow < S.M) {
                    #pragma unroll
                    for (int run = 0; run < NRUNS; ++run) {
                        float wm = S.mask[(size_t)run * S.Nn + grow] * INV_KEEP;
                        #pragma unroll
                        for (int cf = 0; cf < 2; ++cf) {
                            ushort4 o;
                            o.x = f2bf(acc[cf][rf][0] * wm);
                            o.y = f2bf(acc[cf][rf][1] * wm);
                            o.z = f2bf(acc[cf][rf][2] * wm);
                            o.w = f2bf(acc[cf][rf][3] * wm);
                            *(ushort4*)(S.out + ((size_t)run * S.Nn + grow) * HD + cb + cf * 16 + colq) = o;
                        }
                    }
                }
            }
        } else if constexpr (MODE == M_GIN1) {
            #pragma unroll
            for (int rf = 0; rf < 4; ++rf) {
                int grow = m0 + rf * 16 + lr;
                #pragma unroll
                for (int cf = 0; cf < 2; ++cf) {
                    ushort4 o;
                    o.x = f2bf(acc[cf][rf][0]);
                    o.y = f2bf(acc[cf][rf][1]);
                    o.z = f2bf(acc[cf][rf][2]);
                    o.w = f2bf(acc[cf][rf][3]);
                    *(ushort4*)(S.out + (size_t)grow * HD + cb + cf * 16 + colq) = o;
                }
            }
            #pragma unroll
            for (int cf = 0; cf < 2; ++cf)
                #pragma unroll
                for (int j = 0; j < 4; ++j)
                    #pragma unroll
                    for (int rf = 0; rf < 4; ++rf) {
                        float vv = acc[cf][rf][j];
                        st_s[cf][j] += vv;
                        st_q[cf][j] += vv * vv;
                    }
        } else {  // M_GIN2
            #pragma unroll
            for (int rf = 0; rf < 4; ++rf) {
                int grow = m0 + rf * 16 + lr;
                #pragma unroll
                for (int cf = 0; cf < 2; ++cf) {
                    ushort4 o;
                    o.x = f2bf(fmaxf(acc[cf][rf][0], 0.f));
                    o.y = f2bf(fmaxf(acc[cf][rf][1], 0.f));
                    o.z = f2bf(fmaxf(acc[cf][rf][2], 0.f));
                    o.w = f2bf(fmaxf(acc[cf][rf][3], 0.f));
                    *(ushort4*)(S.out + (size_t)grow * HD + cb + cf * 16 + colq) = o;
                }
            }
        }

        if (!more) break;
        t = tn;
        __syncthreads();   // all reads of za done before next stage overwrites
    }

    if constexpr (MODE == M_GIN1) {
        #pragma unroll
        for (int d = 1; d < 16; d <<= 1)
            #pragma unroll
            for (int cf = 0; cf < 2; ++cf)
                #pragma unroll
                for (int j = 0; j < 4; ++j) {
                    st_s[cf][j] += __shfl_xor(st_s[cf][j], d);
                    st_q[cf][j] += __shfl_xor(st_q[cf][j], d);
                }
        if (lr == 0) {
            #pragma unroll
            for (int cf = 0; cf < 2; ++cf)
                #pragma unroll
                for (int j = 0; j < 4; ++j) {
                    red[0][cb + cf * 16 + colq + j] = st_s[cf][j];
                    red[1][cb + cf * 16 + colq + j] = st_q[cf][j];
                }
        }
        __syncthreads();
        if (tid < HD) {
            unsafeAtomicAdd(S.gsum + tid, red[0][tid]);
            unsafeAtomicAdd(S.gsumsq + tid, red[1][tid]);
        }
    }
}

// BN stats -> scale/shift for BOTH sides; re-zeros accumulators
__global__ void finalize2_k(float* gsP, float* gsqP, const float* gamP, const float* betP,
                            float* scP, float* shP, float invNP,
                            float* gsA, float* gsqA, const float* gamA, const float* betA,
                            float* scA, float* shA, float invNA)
{
    int c = threadIdx.x;
    float *gs, *gsq, *sc, *sh;
    const float *gm, *bt;
    float invN;
    if (c < HD) { gs = gsP; gsq = gsqP; gm = gamP; bt = betP; sc = scP; sh = shP; invN = invNP; }
    else { c -= HD; gs = gsA; gsq = gsqA; gm = gamA; bt = betA; sc = scA; sh = shA; invN = invNA; }
    float mu = gs[c] * invN;
    float var = gsq[c] * invN - mu * mu;
    float s = gm[c] * rsqrtf(var + BN_EPS);
    sc[c] = s;
    sh[c] = bt[c] - mu * s;
    gs[c] = 0.f;
    gsq[c] = 0.f;
}

// mean over runs + [128]x[128,4] matmul; one wave per author node
__global__ __launch_bounds__(256)
void final_k(const bf16r* __restrict__ ha, const float* __restrict__ fw,
             const float* __restrict__ fb, float* __restrict__ out)
{
    int g = blockIdx.x * 256 + threadIdx.x;
    int node = g >> 6, lane = g & 63;
    if (node >= NAU) return;
    float m0 = 0.f, m1 = 0.f;
    #pragma unroll
    for (int r = 0; r < NRUNS; ++r) {
        size_t base = ((size_t)r * NAU + node) * HD;
        m0 += bf2f(ha[base + lane]);
        m1 += bf2f(ha[base + 64 + lane]);
    }
    m0 *= 0.25f;
    m1 *= 0.25f;
    float p[4];
    #pragma unroll
    for (int c = 0; c < 4; ++c)
        p[c] = m0 * fw[lane * 4 + c] + m1 * fw[(lane + 64) * 4 + c];
    #pragma unroll
    for (int off = 32; off >= 1; off >>= 1)
        #pragma unroll
        for (int c = 0; c < 4; ++c) p[c] += __shfl_down(p[c], off);
    if (lane == 0) {
        #pragma unroll
        for (int c = 0; c < 4; ++c) out[(size_t)node * 4 + c] = p[c] + fb[c];
    }
}

#define CSR_INTS ((size_t)(NPP + 4) + NEDGE + (NAU + 4) + NEDGE)
#define WT_ELEMS ((size_t)10 * HD * HD)

template<bool GATHER>
static void run_all(void* const* d_in, void* d_out, void* d_ws, hipStream_t stream)
{
    const float* x_author = (const float*)d_in[0];
    const float* x_paper  = (const float*)d_in[1];
    const int*   ei_ap    = (const int*)d_in[2];
    const int*   ei_pa    = (const int*)d_in[3];
    const float* drop_a   = (const float*)d_in[4];
    const float* drop_p   = (const float*)d_in[5];
    const float* lin_a_w  = (const float*)d_in[6];
    const float* lin_a_b  = (const float*)d_in[7];
    const float* lin_p_w  = (const float*)d_in[8];
    const float* lin_p_b  = (const float*)d_in[9];
    const float* W1       = (const float*)d_in[10];
    const float* B1       = (const float*)d_in[11];
    const float* G        = (const float*)d_in[12];
    const float* BT       = (const float*)d_in[13];
    const float* W2       = (const float*)d_in[14];
    const float* B2       = (const float*)d_in[15];
    const float* EPS      = (const float*)d_in[16];
    const float* fw       = (const float*)d_in[17];
    const float* fb       = (const float*)d_in[18];

    // ws: [stats 8*HD f32][Wt][CSR (gather only)][agg][h_a][h_p]
    float* gsumP   = (float*)d_ws;
    float* gsumsqP = gsumP + HD;
    float* gsumA   = gsumP + 2 * HD;
    float* gsumsqA = gsumP + 3 * HD;
    float* scP     = gsumP + 4 * HD;
    float* shP     = gsumP + 5 * HD;
    float* scA     = gsumP + 6 * HD;
    float* shA     = gsumP + 7 * HD;
    bf16r* wt = (bf16r*)(gsumP + 8 * HD);
    char* cp = (char*)(wt + WT_ELEMS);

    int *off_ap = nullptr, *bkt_ap = nullptr, *off_pa = nullptr, *bkt_pa = nullptr;
    if (GATHER) {
        int* ip = (int*)cp;
        off_ap = ip;  ip += NPP + 4;
        bkt_ap = ip;  ip += NEDGE;
        off_pa = ip;  ip += NAU + 4;
        bkt_pa = ip;  ip += NEDGE;
        cp = (char*)ip;
    }
    // agg: bf16 on gather path, f32 on fallback
    void* agg_a_v = cp;
    size_t aggElem = GATHER ? sizeof(bf16r) : sizeof(float);
    void* agg_p_v = cp + (size_t)NAU * HD * aggElem;
    bf16r* h_a = (bf16r*)(cp + (size_t)(NAU + NPP) * HD * aggElem);
    bf16r* h_p = h_a + (size_t)NRUNS * NAU * HD;

    const bf16r* wt_lin_a = wt;
    const bf16r* wt_lin_p = wt + (size_t)1 * HD * HD;
    const bf16r* wt_W1    = wt + (size_t)2 * HD * HD;
    const bf16r* wt_W2    = wt + (size_t)6 * HD * HD;

    convw_k<<<640, 256, 0, stream>>>(lin_a_w, lin_p_w, W1, W2, wt);
    zero_k<<<1, 256, 0, stream>>>(gsumP, (4 * HD) / 4);

    if (GATHER) {
        int* cur_ap  = (int*)agg_a_v;   // alias agg area pre-gather
        int* cur_pa  = cur_ap + NPP;
        int* partial = cur_pa + NAU;
        {
            int nchunk = (NPP + 1023) / 1024;
            zero_k<<<64, 256, 0, stream>>>((float*)cur_ap, NPP / 4);
            count_k<<<(NEDGE + 255) / 256, 256, 0, stream>>>(ei_ap, NEDGE, cur_ap);
            scan1_k<<<nchunk, 256, 0, stream>>>(cur_ap, off_ap, partial, NPP);
            scan2_k<<<1, 256, 0, stream>>>(partial, nchunk);
            scan3_k<<<nchunk, 256, 0, stream>>>(off_ap, cur_ap, partial, NPP, NEDGE);
            fill_k<<<(NEDGE + 255) / 256, 256, 0, stream>>>(ei_ap, NEDGE, cur_ap, bkt_ap);
        }
        {
            int nchunk = (NAU + 1023) / 1024;
            zero_k<<<64, 256, 0, stream>>>((float*)cur_pa, NAU / 4);
            count_k<<<(NEDGE + 255) / 256, 256, 0, stream>>>(ei_pa, NEDGE, cur_pa);
            scan1_k<<<nchunk, 256, 0, stream>>>(cur_pa, off_pa, partial, NAU);
            scan2_k<<<1, 256, 0, stream>>>(partial, nchunk);
            scan3_k<<<nchunk, 256, 0, stream>>>(off_pa, cur_pa, partial, NAU, NEDGE);
            fill_k<<<(NEDGE + 255) / 256, 256, 0, stream>>>(ei_pa, NEDGE, cur_pa, bkt_pa);
        }
    }

    // ---- combined PROJ ----
    SideP Pp = {};
    Pp.in = x_paper; Pp.out = h_p; Pp.wt = wt_lin_p; Pp.bias = lin_p_b;
    Pp.mask = drop_p; Pp.M = NPP; Pp.Nn = NPP; Pp.tiles = (NPP + 63) / 64;
    SideP Pa = {};
    Pa.in = x_author; Pa.out = h_a; Pa.wt = wt_lin_a; Pa.bias = lin_a_b;
    Pa.mask = drop_a; Pa.M = NAU; Pa.Nn = NAU; Pa.tiles = (NAU + 63) / 64;
    int BPproj = (int)((long)NB_GEMM * Pp.tiles / (Pp.tiles + Pa.tiles));
    mfma_gemm<M_PROJ, float, bf16r><<<NB_GEMM, 256, 0, stream>>>(Pp, Pa, BPproj);

    const int TP = NRUNS * NPP / 64, TA = NRUNS * NAU / 64;
    const int BPgin = (int)((long)NB_GEMM * TP / (TP + TA));

    for (int l = 0; l < 2; ++l) {
        int t0 = l * 2 + 0, t1 = l * 2 + 1;

        if (GATHER) {
            gather2_k<<<((NPP + NAU) * 64) / 256, 256, 0, stream>>>(
                h_a, h_p, (bf16r*)agg_p_v, (bf16r*)agg_a_v,
                off_ap, bkt_ap, off_pa, bkt_pa);
        } else {
            zero_k<<<2048, 256, 0, stream>>>((float*)agg_a_v, ((size_t)(NAU + NPP) * HD) / 4);
            scatter_k<<<(NEDGE * 32) / 256, 256, 0, stream>>>(h_a, (float*)agg_p_v, ei_ap, NEDGE);
            scatter_k<<<(NEDGE * 32) / 256, 256, 0, stream>>>(h_p, (float*)agg_a_v, ei_pa, NEDGE);
        }

        // combined GIN1
        SideP G1p = {};
        G1p.in = h_p; G1p.out = h_p; G1p.wt = wt_W1 + (size_t)t0 * HD * HD;
        G1p.bias = B1 + (size_t)t0 * HD; G1p.agg = agg_p_v; G1p.epsp = EPS + t0;
        G1p.gsum = gsumP; G1p.gsumsq = gsumsqP;
        G1p.M = NRUNS * NPP; G1p.Nn = NPP; G1p.tiles = TP;
        SideP G1a = {};
        G1a.in = h_a; G1a.out = h_a; G1a.wt = wt_W1 + (size_t)t1 * HD * HD;
        G1a.bias = B1 + (size_t)t1 * HD; G1a.agg = agg_a_v; G1a.epsp = EPS + t1;
        G1a.gsum = gsumA; G1a.gsumsq = gsumsqA;
        G1a.M = NRUNS * NAU; G1a.Nn = NAU; G1a.tiles = TA;
        if (GATHER)
            mfma_gemm<M_GIN1, bf16r, bf16r><<<NB_GEMM, 256, 0, stream>>>(G1p, G1a, BPgin);
        else
            mfma_gemm<M_GIN1, bf16r, float><<<NB_GEMM, 256, 0, stream>>>(G1p, G1a, BPgin);

        finalize2_k<<<1, 256, 0, stream>>>(
            gsumP, gsumsqP, G + (size_t)t0 * HD, BT + (size_t)t0 * HD, scP, shP,
            1.0f / (NRUNS * NPP),
            gsumA, gsumsqA, G + (size_t)t1 * HD, BT + (size_t)t1 * HD, scA, shA,
            1.0f / (NRUNS * NAU));

        // combined GIN2
        SideP G2p = {};
        G2p.in = h_p; G2p.out = h_p; G2p.wt = wt_W2 + (size_t)t0 * HD * HD;
        G2p.bias = B2 + (size_t)t0 * HD; G2p.scale = scP; G2p.shift = shP;
        G2p.M = NRUNS * NPP; G2p.Nn = NPP; G2p.tiles = TP;
        SideP G2a = {};
        G2a.in = h_a; G2a.out = h_a; G2a.wt = wt_W2 + (size_t)t1 * HD * HD;
        G2a.bias = B2 + (size_t)t1 * HD; G2a.scale = scA; G2a.shift = shA;
        G2a.M = NRUNS * NAU; G2a.Nn = NAU; G2a.tiles = TA;
        mfma_gemm<M_GIN2, bf16r, bf16r><<<NB_GEMM, 256, 0, stream>>>(G2p, G2a, BPgin);
    }

    final_k<<<(NAU * 64) / 256, 256, 0, stream>>>(h_a, fw, fb, (float*)d_out);
}

extern "C" void kernel_launch(void* const* d_in, const int* in_sizes, int n_in,
                              void* d_out, int out_size, void* d_ws, size_t ws_size,
                              hipStream_t stream)
{
    const size_t hB    = (size_t)NRUNS * (NAU + NPP) * HD * sizeof(bf16r);
    const size_t statB = 8 * HD * sizeof(float);
    const size_t wtB   = WT_ELEMS * sizeof(bf16r);
    const size_t csrB  = CSR_INTS * sizeof(int);
    const size_t aggBF = (size_t)(NAU + NPP) * HD * sizeof(bf16r);

    const size_t need_gather = statB + wtB + csrB + aggBF + hB;   // ~197 MB
    if (ws_size >= need_gather) {
        run_all<true>(d_in, d_out, d_ws, stream);
    } else {
        run_all<false>(d_in, d_out, d_ws, stream);                // atomic fallback
    }
}

// Round 10
// 626.892 us; speedup vs baseline: 7.7833x; 1.0368x over previous
//
#include <hip/hip_runtime.h>

#define NRUNS 4
#define NAU 50000
#define NPP 100000
#define NEDGE 500000
#define HD 128
#define INV_KEEP 1.25f
#define BN_EPS 1e-5f
#define LDA 136      // padded LDS row (bf16 elems), 272B
#define NB_GEMM 1280 // persistent GEMM grid (5 blocks/CU = VGPR-92 residency)

#define M_PROJ  0    // masked 4-copy projection (fallback path)
#define M_GIN1  1    // GIN stage-1 reading h (layer >= 1)
#define M_GIN2  2    // BN+relu + W2 + relu, in place
#define M_PROJ1 3    // single-copy unmasked projection (main path)
#define M_GIN1M 4    // layer-0 GIN stage-1: input = mask*1.25*proj

typedef unsigned short bf16r;
typedef __attribute__((ext_vector_type(8))) short v8s;   // 8 bf16 (4 VGPR)
typedef __attribute__((ext_vector_type(4))) float v4f;   // 4 f32 acc

__device__ inline float bf2f(bf16r u) {
    return __uint_as_float(((unsigned)u) << 16);
}
__device__ inline bf16r f2bf(float f) {
    __bf16 b = (__bf16)f;
    return __builtin_bit_cast(bf16r, b);
}

__global__ __launch_bounds__(256)
void zero_k(float* p, long n4) {
    long i = (long)blockIdx.x * 256 + threadIdx.x;
    long stride = (long)gridDim.x * 256;
    float4 z = make_float4(0.f, 0.f, 0.f, 0.f);
    for (; i < n4; i += stride) ((float4*)p)[i] = z;
}

// weight convert: f32 [k][n] -> bf16 transposed [n][k]
__global__ __launch_bounds__(256)
void convw_k(const float* __restrict__ lin_a_w, const float* __restrict__ lin_p_w,
             const float* __restrict__ W1, const float* __restrict__ W2,
             bf16r* __restrict__ wt)
{
    int t = blockIdx.x >> 6;
    int e = (blockIdx.x & 63) * 256 + threadIdx.x;
    const float* src;
    if (t == 0) src = lin_a_w;
    else if (t == 1) src = lin_p_w;
    else if (t < 6) src = W1 + (size_t)(t - 2) * HD * HD;
    else src = W2 + (size_t)(t - 6) * HD * HD;
    int n = e >> 7, k = e & 127;
    wt[(size_t)t * HD * HD + e] = f2bf(src[(size_t)k * HD + n]);
}

// ================= CSR build =================
__global__ __launch_bounds__(256)
void count_k(const int* __restrict__ ei, int E, int* cnt) {
    int e = blockIdx.x * 256 + threadIdx.x;
    if (e < E) atomicAdd(&cnt[ei[E + e]], 1);
}

__global__ __launch_bounds__(256)
void scan1_k(const int* __restrict__ in, int* out, int* partial, int n) {
    __shared__ int lds[256];
    int b = blockIdx.x, t = threadIdx.x;
    int base = b * 1024 + t * 4;
    int v0 = 0, v1 = 0, v2 = 0, v3 = 0;
    if (base + 3 < n) {
        int4 x = *(const int4*)(in + base);
        v0 = x.x; v1 = x.y; v2 = x.z; v3 = x.w;
    } else {
        if (base + 0 < n) v0 = in[base + 0];
        if (base + 1 < n) v1 = in[base + 1];
        if (base + 2 < n) v2 = in[base + 2];
        if (base + 3 < n) v3 = in[base + 3];
    }
    int s = v0 + v1 + v2 + v3;
    lds[t] = s;
    __syncthreads();
    for (int d = 1; d < 256; d <<= 1) {
        int x = (t >= d) ? lds[t - d] : 0;
        __syncthreads();
        lds[t] += x;
        __syncthreads();
    }
    int excl = lds[t] - s;
    if (base + 0 < n) out[base + 0] = excl;
    if (base + 1 < n) out[base + 1] = excl + v0;
    if (base + 2 < n) out[base + 2] = excl + v0 + v1;
    if (base + 3 < n) out[base + 3] = excl + v0 + v1 + v2;
    if (t == 255) partial[b] = lds[255];
}

__global__ __launch_bounds__(256)
void scan2_k(int* partial, int n) {
    __shared__ int lds[256];
    int t = threadIdx.x;
    int s = (t < n) ? partial[t] : 0;
    lds[t] = s;
    __syncthreads();
    for (int d = 1; d < 256; d <<= 1) {
        int x = (t >= d) ? lds[t - d] : 0;
        __syncthreads();
        lds[t] += x;
        __syncthreads();
    }
    if (t < n) partial[t] = lds[t] - s;
}

__global__ __launch_bounds__(256)
void scan3_k(int* off, int* cur, const int* __restrict__ partial, int n, int total) {
    int b = blockIdx.x, t = threadIdx.x;
    int add = partial[b];
    int base = b * 1024 + t * 4;
    #pragma unroll
    for (int j = 0; j < 4; ++j) {
        int i = base + j;
        if (i < n) {
            int v = off[i] + add;
            off[i] = v;
            cur[i] = v;
        }
    }
    if (b == 0 && t == 0) off[n] = total;
}

__global__ __launch_bounds__(256)
void fill_k(const int* __restrict__ ei, int E, int* cur, int* bucket) {
    int e = blockIdx.x * 256 + threadIdx.x;
    if (e < E) {
        int d = ei[E + e];
        int p = atomicAdd(&cur[d], 1);
        bucket[p] = ei[e];
    }
}

// combined gather (both graphs). MASKED: src value = mask0[src]*1.25*src_row
// (layer 0, reading unmasked proj). Unmasked: plain sum (layer>=1, reading h).
template<bool MASKED>
__global__ __launch_bounds__(256)
void gather2_k(const bf16r* __restrict__ hA, const bf16r* __restrict__ hP,
               bf16r* __restrict__ aggP, bf16r* __restrict__ aggA,
               const int* __restrict__ offAP, const int* __restrict__ bktAP,
               const int* __restrict__ offPA, const int* __restrict__ bktPA,
               const float* __restrict__ mA0, const float* __restrict__ mP0)
{
    int gw = (blockIdx.x * 256 + threadIdx.x) >> 6;
    int lane = threadIdx.x & 63;
    const bf16r* src; bf16r* agg; const int* off; const int* bkt;
    const float* msk; int w;
    if (gw < NPP) { src = hA; agg = aggP; off = offAP; bkt = bktAP; msk = mA0; w = gw; }
    else          { src = hP; agg = aggA; off = offPA; bkt = bktPA; msk = mP0; w = gw - NPP; }
    int s0 = off[w], s1 = off[w + 1];
    float a0 = 0.f, a1 = 0.f;
    int e = s0;
    for (; e + 1 < s1; e += 2) {
        int i0 = bkt[e], i1 = bkt[e + 1];
        ushort2 u = *(const ushort2*)(src + (size_t)i0 * HD + lane * 2);
        ushort2 v = *(const ushort2*)(src + (size_t)i1 * HD + lane * 2);
        if constexpr (MASKED) {
            float m0 = msk[i0] * INV_KEEP, m1 = msk[i1] * INV_KEEP;
            a0 += m0 * bf2f(u.x) + m1 * bf2f(v.x);
            a1 += m0 * bf2f(u.y) + m1 * bf2f(v.y);
        } else {
            a0 += bf2f(u.x) + bf2f(v.x);
            a1 += bf2f(u.y) + bf2f(v.y);
        }
    }
    if (e < s1) {
        int i0 = bkt[e];
        ushort2 u = *(const ushort2*)(src + (size_t)i0 * HD + lane * 2);
        float m0 = MASKED ? msk[i0] * INV_KEEP : 1.0f;
        a0 += m0 * bf2f(u.x);
        a1 += m0 * bf2f(u.y);
    }
    ushort2 o;
    o.x = f2bf(a0);
    o.y = f2bf(a1);
    *(ushort2*)(agg + (size_t)w * HD + lane * 2) = o;
}

// fallback scatter (atomics, f32 agg)
__global__ __launch_bounds__(256)
void scatter_k(const bf16r* __restrict__ src, float* dst,
               const int* __restrict__ ei, int E)
{
    int g = blockIdx.x * 256 + threadIdx.x;
    int e = g >> 5, lane = g & 31;
    if (e >= E) return;
    int s = ei[e], d = ei[E + e];
    ushort4 u = *(const ushort4*)(src + (size_t)s * HD + lane * 4);
    float* dp = dst + (size_t)d * HD + lane * 4;
    unsafeAtomicAdd(dp + 0, bf2f(u.x));
    unsafeAtomicAdd(dp + 1, bf2f(u.y));
    unsafeAtomicAdd(dp + 2, bf2f(u.z));
    unsafeAtomicAdd(dp + 3, bf2f(u.w));
}

// ================= persistent pipelined MFMA GEMM =================
struct SideP {
    const void* in;
    bf16r* out;
    const bf16r* wt;
    const float* bias;
    const void* agg;      // AT-typed
    const float* epsp;
    float* gsum;
    float* gsumsq;
    const float* scale;
    const float* shift;
    const float* mask;    // PROJ: [R][Nn]; GIN1M: flat [R*Nn] dropout mask
    int M, Nn, tiles;
};

template<int MODE, typename IT, typename AT>
__global__ __launch_bounds__(256)
void mfma_gemm(SideP P, SideP A, int BP)
{
    __shared__ bf16r za[64][LDA];
    __shared__ float red[2][HD];
    const int tid = threadIdx.x;

    SideP S;
    int t, tstride;
    if ((int)blockIdx.x < BP) { S = P; t = blockIdx.x; tstride = BP; }
    else { S = A; t = (int)blockIdx.x - BP; tstride = NB_GEMM - BP; }
    if (t >= S.tiles) return;

    const int wid = tid >> 6, lane = tid & 63;
    const int lr = lane & 15, lk = (lane >> 4) * 8;
    const int colq = (lane >> 4) * 4, cb = wid * 32;
    const int srow = tid >> 4;
    const int scol = (tid & 15) * 8;

    constexpr bool GIN1ANY = (MODE == M_GIN1 || MODE == M_GIN1M);

    float epsv = 1.0f;
    if (GIN1ANY) epsv = 1.0f + S.epsp[0];

    v8s w[2][4];
    #pragma unroll
    for (int cf = 0; cf < 2; ++cf)
        #pragma unroll
        for (int ks = 0; ks < 4; ++ks)
            w[cf][ks] = *(const v8s*)(S.wt + (size_t)(cb + cf * 16 + lr) * HD + ks * 32 + lk);

    const float4 bb0 = *(const float4*)(S.bias + cb + colq);
    const float4 bb1 = *(const float4*)(S.bias + cb + 16 + colq);

    float4 sc0h, sc1h, sh0h, sh1h;
    if (MODE == M_GIN2) {
        sc0h = *(const float4*)(S.scale + scol);
        sc1h = *(const float4*)(S.scale + scol + 4);
        sh0h = *(const float4*)(S.shift + scol);
        sh1h = *(const float4*)(S.shift + scol + 4);
    }

    float st_s[2][4], st_q[2][4];
    if (GIN1ANY) {
        #pragma unroll
        for (int cf = 0; cf < 2; ++cf)
            #pragma unroll
            for (int j = 0; j < 4; ++j) { st_s[cf][j] = 0.f; st_q[cf][j] = 0.f; }
    }

    constexpr int NVH = (MODE == M_PROJ || MODE == M_PROJ1) ? 2 : 1;
    constexpr bool PAGG = GIN1ANY;
    constexpr bool PMSK = (MODE == M_GIN1M);
    constexpr int NVA = (PAGG && sizeof(AT) == 4) ? 2 : 1;
    int4 pre[4][NVH];
    int4 preA[4][NVA];
    float mpre[PMSK ? 4 : 1];

    auto prefetch = [&](int tt) {
        int m0n = tt * 64;
        #pragma unroll
        for (int i = 0; i < 4; ++i) {
            int gr = m0n + srow + 16 * i;
            if constexpr (PMSK) {
                // input row = mask[gr]*1.25*proj[node], node = gr - run*Nn
                int run = (gr >= S.Nn) + (gr >= 2 * S.Nn) + (gr >= 3 * S.Nn);
                int node = gr - run * S.Nn;
                mpre[i] = S.mask[gr];
                const int4* p = (const int4*)((const IT*)S.in + (size_t)node * HD + scol);
                pre[i][0] = p[0];
            } else if (gr < S.M) {
                const int4* p = (const int4*)((const IT*)S.in + (size_t)gr * HD + scol);
                pre[i][0] = p[0];
                if constexpr (NVH == 2) pre[i][1] = p[1];
            } else {
                pre[i][0] = make_int4(0, 0, 0, 0);
                if constexpr (NVH == 2) pre[i][1] = make_int4(0, 0, 0, 0);
            }
            if constexpr (PAGG) {
                if (gr < S.Nn) {
                    const int4* pa = (const int4*)((const AT*)S.agg + (size_t)gr * HD + scol);
                    preA[i][0] = pa[0];
                    if constexpr (NVA == 2) preA[i][1] = pa[1];
                } else {
                    preA[i][0] = make_int4(0, 0, 0, 0);
                    if constexpr (NVA == 2) preA[i][1] = make_int4(0, 0, 0, 0);
                }
            }
        }
    };

    prefetch(t);

    for (;;) {
        const int m0 = t * 64;
        // ---- stage ----
        #pragma unroll
        for (int i = 0; i < 4; ++i) {
            int row = srow + 16 * i;
            float v[8];
            if constexpr (NVH == 2) {
                const float* pf = (const float*)&pre[i][0];
                #pragma unroll
                for (int j = 0; j < 8; ++j) v[j] = pf[j];
            } else {
                const bf16r* pu = (const bf16r*)&pre[i][0];
                #pragma unroll
                for (int j = 0; j < 8; ++j) v[j] = bf2f(pu[j]);
            }
            if constexpr (MODE == M_GIN1 || MODE == M_GIN1M) {
                float av[8];
                if constexpr (sizeof(AT) == 4) {
                    const float* pa = (const float*)&preA[i][0];
                    #pragma unroll
                    for (int j = 0; j < 8; ++j) av[j] = pa[j];
                } else {
                    const bf16r* pa = (const bf16r*)&preA[i][0];
                    #pragma unroll
                    for (int j = 0; j < 8; ++j) av[j] = bf2f(pa[j]);
                }
                float coef = epsv;
                if constexpr (PMSK) coef = mpre[i] * (INV_KEEP)*epsv;
                #pragma unroll
                for (int j = 0; j < 8; ++j) v[j] = v[j] * coef + av[j];
            } else if constexpr (MODE == M_GIN2) {
                v[0] = fmaxf(v[0] * sc0h.x + sh0h.x, 0.f);
                v[1] = fmaxf(v[1] * sc0h.y + sh0h.y, 0.f);
                v[2] = fmaxf(v[2] * sc0h.z + sh0h.z, 0.f);
                v[3] = fmaxf(v[3] * sc0h.w + sh0h.w, 0.f);
                v[4] = fmaxf(v[4] * sc1h.x + sh1h.x, 0.f);
                v[5] = fmaxf(v[5] * sc1h.y + sh1h.y, 0.f);
                v[6] = fmaxf(v[6] * sc1h.z + sh1h.z, 0.f);
                v[7] = fmaxf(v[7] * sc1h.w + sh1h.w, 0.f);
            }
            union { v8s w8; bf16r u[8]; } pk;
            #pragma unroll
            for (int j = 0; j < 8; ++j) pk.u[j] = f2bf(v[j]);
            *(v8s*)&za[row][scol] = pk.w8;
        }
        __syncthreads();

        // ---- prefetch next tile ----
        const int tn = t + tstride;
        const bool more = tn < S.tiles;
        if (more) prefetch(tn);

        // ---- compute ----
        v4f acc[2][4];
        #pragma unroll
        for (int cf = 0; cf < 2; ++cf)
            #pragma unroll
            for (int rf = 0; rf < 4; ++rf) acc[cf][rf] = (v4f){0.f, 0.f, 0.f, 0.f};

        #pragma unroll
        for (int ks = 0; ks < 4; ++ks)
            #pragma unroll
            for (int rf = 0; rf < 4; ++rf) {
                v8s a = *(const v8s*)&za[rf * 16 + lr][ks * 32 + lk];
                acc[0][rf] = __builtin_amdgcn_mfma_f32_16x16x32_bf16(w[0][ks], a, acc[0][rf], 0, 0, 0);
                acc[1][rf] = __builtin_amdgcn_mfma_f32_16x16x32_bf16(w[1][ks], a, acc[1][rf], 0, 0, 0);
            }

        #pragma unroll
        for (int rf = 0; rf < 4; ++rf) {
            acc[0][rf][0] += bb0.x; acc[0][rf][1] += bb0.y;
            acc[0][rf][2] += bb0.z; acc[0][rf][3] += bb0.w;
            acc[1][rf][0] += bb1.x; acc[1][rf][1] += bb1.y;
            acc[1][rf][2] += bb1.z; acc[1][rf][3] += bb1.w;
        }

        if constexpr (MODE == M_PROJ) {
            #pragma unroll
            for (int rf = 0; rf < 4; ++rf) {
                int grow = m0 + rf * 16 + lr;
                if (grow < S.M) {
                    #pragma unroll
                    for (int run = 0; run < NRUNS; ++run) {
                        float wm = S.mask[(size_t)run * S.Nn + grow] * INV_KEEP;
                        #pragma unroll
                        for (int cf = 0; cf < 2; ++cf) {
                            ushort4 o;
                            o.x = f2bf(acc[cf][rf][0] * wm);
                            o.y = f2bf(acc[cf][rf][1] * wm);
                            o.z = f2bf(acc[cf][rf][2] * wm);
                            o.w = f2bf(acc[cf][rf][3] * wm);
                            *(ushort4*)(S.out + ((size_t)run * S.Nn + grow) * HD + cb + cf * 16 + colq) = o;
                        }
                    }
                }
            }
        } else if constexpr (MODE == M_PROJ1) {
            #pragma unroll
            for (int rf = 0; rf < 4; ++rf) {
                int grow = m0 + rf * 16 + lr;
                if (grow < S.M) {
                    #pragma unroll
                    for (int cf = 0; cf < 2; ++cf) {
                        ushort4 o;
                        o.x = f2bf(acc[cf][rf][0]);
                        o.y = f2bf(acc[cf][rf][1]);
                        o.z = f2bf(acc[cf][rf][2]);
                        o.w = f2bf(acc[cf][rf][3]);
                        *(ushort4*)(S.out + (size_t)grow * HD + cb + cf * 16 + colq) = o;
                    }
                }
            }
        } else if constexpr (GIN1ANY) {
            #pragma unroll
            for (int rf = 0; rf < 4; ++rf) {
                int grow = m0 + rf * 16 + lr;
                #pragma unroll
                for (int cf = 0; cf < 2; ++cf) {
                    ushort4 o;
                    o.x = f2bf(acc[cf][rf][0]);
                    o.y = f2bf(acc[cf][rf][1]);
                    o.z = f2bf(acc[cf][rf][2]);
                    o.w = f2bf(acc[cf][rf][3]);
                    *(ushort4*)(S.out + (size_t)grow * HD + cb + cf * 16 + colq) = o;
                }
            }
            #pragma unroll
            for (int cf = 0; cf < 2; ++cf)
                #pragma unroll
                for (int j = 0; j < 4; ++j)
                    #pragma unroll
                    for (int rf = 0; rf < 4; ++rf) {
                        float vv = acc[cf][rf][j];
                        st_s[cf][j] += vv;
                        st_q[cf][j] += vv * vv;
                    }
        } else {  // M_GIN2
            #pragma unroll
            for (int rf = 0; rf < 4; ++rf) {
                int grow = m0 + rf * 16 + lr;
                #pragma unroll
                for (int cf = 0; cf < 2; ++cf) {
                    ushort4 o;
                    o.x = f2bf(fmaxf(acc[cf][rf][0], 0.f));
                    o.y = f2bf(fmaxf(acc[cf][rf][1], 0.f));
                    o.z = f2bf(fmaxf(acc[cf][rf][2], 0.f));
                    o.w = f2bf(fmaxf(acc[cf][rf][3], 0.f));
                    *(ushort4*)(S.out + (size_t)grow * HD + cb + cf * 16 + colq) = o;
                }
            }
        }

        if (!more) break;
        t = tn;
        __syncthreads();
    }

    if constexpr (GIN1ANY) {
        #pragma unroll
        for (int d = 1; d < 16; d <<= 1)
            #pragma unroll
            for (int cf = 0; cf < 2; ++cf)
                #pragma unroll
                for (int j = 0; j < 4; ++j) {
                    st_s[cf][j] += __shfl_xor(st_s[cf][j], d);
                    st_q[cf][j] += __shfl_xor(st_q[cf][j], d);
                }
        if (lr == 0) {
            #pragma unroll
            for (int cf = 0; cf < 2; ++cf)
                #pragma unroll
                for (int j = 0; j < 4; ++j) {
                    red[0][cb + cf * 16 + colq + j] = st_s[cf][j];
                    red[1][cb + cf * 16 + colq + j] = st_q[cf][j];
                }
        }
        __syncthreads();
        if (tid < HD) {
            unsafeAtomicAdd(S.gsum + tid, red[0][tid]);
            unsafeAtomicAdd(S.gsumsq + tid, red[1][tid]);
        }
    }
}

// BN stats -> scale/shift for both sides; re-zeros accumulators
__global__ void finalize2_k(float* gsP, float* gsqP, const float* gamP, const float* betP,
                            float* scP, float* shP, float invNP,
                            float* gsA, float* gsqA, const float* gamA, const float* betA,
                            float* scA, float* shA, float invNA)
{
    int c = threadIdx.x;
    float *gs, *gsq, *sc, *sh;
    const float *gm, *bt;
    float invN;
    if (c < HD) { gs = gsP; gsq = gsqP; gm = gamP; bt = betP; sc = scP; sh = shP; invN = invNP; }
    else { c -= HD; gs = gsA; gsq = gsqA; gm = gamA; bt = betA; sc = scA; sh = shA; invN = invNA; }
    float mu = gs[c] * invN;
    float var = gsq[c] * invN - mu * mu;
    float s = gm[c] * rsqrtf(var + BN_EPS);
    sc[c] = s;
    sh[c] = bt[c] - mu * s;
    gs[c] = 0.f;
    gsq[c] = 0.f;
}

// mean over runs + [128]x[128,4] matmul
__global__ __launch_bounds__(256)
void final_k(const bf16r* __restrict__ ha, const float* __restrict__ fw,
             const float* __restrict__ fb, float* __restrict__ out)
{
    int g = blockIdx.x * 256 + threadIdx.x;
    int node = g >> 6, lane = g & 63;
    if (node >= NAU) return;
    float m0 = 0.f, m1 = 0.f;
    #pragma unroll
    for (int r = 0; r < NRUNS; ++r) {
        size_t base = ((size_t)r * NAU + node) * HD;
        m0 += bf2f(ha[base + lane]);
        m1 += bf2f(ha[base + 64 + lane]);
    }
    m0 *= 0.25f;
    m1 *= 0.25f;
    float p[4];
    #pragma unroll
    for (int c = 0; c < 4; ++c)
        p[c] = m0 * fw[lane * 4 + c] + m1 * fw[(lane + 64) * 4 + c];
    #pragma unroll
    for (int off = 32; off >= 1; off >>= 1)
        #pragma unroll
        for (int c = 0; c < 4; ++c) p[c] += __shfl_down(p[c], off);
    if (lane == 0) {
        #pragma unroll
        for (int c = 0; c < 4; ++c) out[(size_t)node * 4 + c] = p[c] + fb[c];
    }
}

#define CSR_INTS ((size_t)(NPP + 4) + NEDGE + (NAU + 4) + NEDGE)
#define WT_ELEMS ((size_t)10 * HD * HD)

template<bool GATHER>
static void run_all(void* const* d_in, void* d_out, void* d_ws, hipStream_t stream)
{
    const float* x_author = (const float*)d_in[0];
    const float* x_paper  = (const float*)d_in[1];
    const int*   ei_ap    = (const int*)d_in[2];
    const int*   ei_pa    = (const int*)d_in[3];
    const float* drop_a   = (const float*)d_in[4];
    const float* drop_p   = (const float*)d_in[5];
    const float* lin_a_w  = (const float*)d_in[6];
    const float* lin_a_b  = (const float*)d_in[7];
    const float* lin_p_w  = (const float*)d_in[8];
    const float* lin_p_b  = (const float*)d_in[9];
    const float* W1       = (const float*)d_in[10];
    const float* B1       = (const float*)d_in[11];
    const float* G        = (const float*)d_in[12];
    const float* BT       = (const float*)d_in[13];
    const float* W2       = (const float*)d_in[14];
    const float* B2       = (const float*)d_in[15];
    const float* EPS      = (const float*)d_in[16];
    const float* fw       = (const float*)d_in[17];
    const float* fb       = (const float*)d_in[18];

    // ws: [stats 8*HD f32][Wt][CSR?][agg][proj?][h_a][h_p]
    float* gsumP   = (float*)d_ws;
    float* gsumsqP = gsumP + HD;
    float* gsumA   = gsumP + 2 * HD;
    float* gsumsqA = gsumP + 3 * HD;
    float* scP     = gsumP + 4 * HD;
    float* shP     = gsumP + 5 * HD;
    float* scA     = gsumP + 6 * HD;
    float* shA     = gsumP + 7 * HD;
    bf16r* wt = (bf16r*)(gsumP + 8 * HD);
    char* cp = (char*)(wt + WT_ELEMS);

    int *off_ap = nullptr, *bkt_ap = nullptr, *off_pa = nullptr, *bkt_pa = nullptr;
    if (GATHER) {
        int* ip = (int*)cp;
        off_ap = ip;  ip += NPP + 4;
        bkt_ap = ip;  ip += NEDGE;
        off_pa = ip;  ip += NAU + 4;
        bkt_pa = ip;  ip += NEDGE;
        cp = (char*)ip;
    }
    void* agg_a_v = cp;
    size_t aggElem = GATHER ? sizeof(bf16r) : sizeof(float);
    void* agg_p_v = cp + (size_t)NAU * HD * aggElem;
    cp += (size_t)(NAU + NPP) * HD * aggElem;
    bf16r* proj_a = nullptr; bf16r* proj_p = nullptr;
    if (GATHER) {
        proj_a = (bf16r*)cp;  cp += (size_t)NAU * HD * sizeof(bf16r);
        proj_p = (bf16r*)cp;  cp += (size_t)NPP * HD * sizeof(bf16r);
    }
    bf16r* h_a = (bf16r*)cp;
    bf16r* h_p = h_a + (size_t)NRUNS * NAU * HD;

    const bf16r* wt_lin_a = wt;
    const bf16r* wt_lin_p = wt + (size_t)1 * HD * HD;
    const bf16r* wt_W1    = wt + (size_t)2 * HD * HD;
    const bf16r* wt_W2    = wt + (size_t)6 * HD * HD;

    convw_k<<<640, 256, 0, stream>>>(lin_a_w, lin_p_w, W1, W2, wt);
    zero_k<<<1, 256, 0, stream>>>(gsumP, (4 * HD) / 4);

    if (GATHER) {
        int* cur_ap  = (int*)agg_a_v;   // alias agg area pre-gather
        int* cur_pa  = cur_ap + NPP;
        int* partial = cur_pa + NAU;
        {
            int nchunk = (NPP + 1023) / 1024;
            zero_k<<<64, 256, 0, stream>>>((float*)cur_ap, NPP / 4);
            count_k<<<(NEDGE + 255) / 256, 256, 0, stream>>>(ei_ap, NEDGE, cur_ap);
            scan1_k<<<nchunk, 256, 0, stream>>>(cur_ap, off_ap, partial, NPP);
            scan2_k<<<1, 256, 0, stream>>>(partial, nchunk);
            scan3_k<<<nchunk, 256, 0, stream>>>(off_ap, cur_ap, partial, NPP, NEDGE);
            fill_k<<<(NEDGE + 255) / 256, 256, 0, stream>>>(ei_ap, NEDGE, cur_ap, bkt_ap);
        }
        {
            int nchunk = (NAU + 1023) / 1024;
            zero_k<<<64, 256, 0, stream>>>((float*)cur_pa, NAU / 4);
            count_k<<<(NEDGE + 255) / 256, 256, 0, stream>>>(ei_pa, NEDGE, cur_pa);
            scan1_k<<<nchunk, 256, 0, stream>>>(cur_pa, off_pa, partial, NAU);
            scan2_k<<<1, 256, 0, stream>>>(partial, nchunk);
            scan3_k<<<nchunk, 256, 0, stream>>>(off_pa, cur_pa, partial, NAU, NEDGE);
            fill_k<<<(NEDGE + 255) / 256, 256, 0, stream>>>(ei_pa, NEDGE, cur_pa, bkt_pa);
        }
    }

    const int TP = NRUNS * NPP / 64, TA = NRUNS * NAU / 64;
    const int BPgin = (int)((long)NB_GEMM * TP / (TP + TA));

    if (GATHER) {
        // ---- single-copy PROJ ----
        SideP Pp = {};
        Pp.in = x_paper; Pp.out = proj_p; Pp.wt = wt_lin_p; Pp.bias = lin_p_b;
        Pp.M = NPP; Pp.Nn = NPP; Pp.tiles = (NPP + 63) / 64;
        SideP Pa = {};
        Pa.in = x_author; Pa.out = proj_a; Pa.wt = wt_lin_a; Pa.bias = lin_a_b;
        Pa.M = NAU; Pa.Nn = NAU; Pa.tiles = (NAU + 63) / 64;
        int BPproj = (int)((long)NB_GEMM * Pp.tiles / (Pp.tiles + Pa.tiles));
        mfma_gemm<M_PROJ1, float, bf16r><<<NB_GEMM, 256, 0, stream>>>(Pp, Pa, BPproj);

        for (int l = 0; l < 2; ++l) {
            int t0 = l * 2 + 0, t1 = l * 2 + 1;

            if (l == 0) {
                gather2_k<true><<<((NPP + NAU) * 64) / 256, 256, 0, stream>>>(
                    proj_a, proj_p, (bf16r*)agg_p_v, (bf16r*)agg_a_v,
                    off_ap, bkt_ap, off_pa, bkt_pa, drop_a, drop_p);
            } else {
                gather2_k<false><<<((NPP + NAU) * 64) / 256, 256, 0, stream>>>(
                    h_a, h_p, (bf16r*)agg_p_v, (bf16r*)agg_a_v,
                    off_ap, bkt_ap, off_pa, bkt_pa, nullptr, nullptr);
            }

            // GIN1 (layer0: masked proj input; layer1: h in-place)
            SideP G1p = {}, G1a = {};
            G1p.wt = wt_W1 + (size_t)t0 * HD * HD;
            G1p.bias = B1 + (size_t)t0 * HD; G1p.agg = agg_p_v; G1p.epsp = EPS + t0;
            G1p.gsum = gsumP; G1p.gsumsq = gsumsqP;
            G1p.M = NRUNS * NPP; G1p.Nn = NPP; G1p.tiles = TP; G1p.out = h_p;
            G1a.wt = wt_W1 + (size_t)t1 * HD * HD;
            G1a.bias = B1 + (size_t)t1 * HD; G1a.agg = agg_a_v; G1a.epsp = EPS + t1;
            G1a.gsum = gsumA; G1a.gsumsq = gsumsqA;
            G1a.M = NRUNS * NAU; G1a.Nn = NAU; G1a.tiles = TA; G1a.out = h_a;
            if (l == 0) {
                G1p.in = proj_p; G1p.mask = drop_p;
                G1a.in = proj_a; G1a.mask = drop_a;
                mfma_gemm<M_GIN1M, bf16r, bf16r><<<NB_GEMM, 256, 0, stream>>>(G1p, G1a, BPgin);
            } else {
                G1p.in = h_p;
                G1a.in = h_a;
                mfma_gemm<M_GIN1, bf16r, bf16r><<<NB_GEMM, 256, 0, stream>>>(G1p, G1a, BPgin);
            }

            finalize2_k<<<1, 256, 0, stream>>>(
                gsumP, gsumsqP, G + (size_t)t0 * HD, BT + (size_t)t0 * HD, scP, shP,
                1.0f / (NRUNS * NPP),
                gsumA, gsumsqA, G + (size_t)t1 * HD, BT + (size_t)t1 * HD, scA, shA,
                1.0f / (NRUNS * NAU));

            SideP G2p = {}, G2a = {};
            G2p.in = h_p; G2p.out = h_p; G2p.wt = wt_W2 + (size_t)t0 * HD * HD;
            G2p.bias = B2 + (size_t)t0 * HD; G2p.scale = scP; G2p.shift = shP;
            G2p.M = NRUNS * NPP; G2p.Nn = NPP; G2p.tiles = TP;
            G2a.in = h_a; G2a.out = h_a; G2a.wt = wt_W2 + (size_t)t1 * HD * HD;
            G2a.bias = B2 + (size_t)t1 * HD; G2a.scale = scA; G2a.shift = shA;
            G2a.M = NRUNS * NAU; G2a.Nn = NAU; G2a.tiles = TA;
            mfma_gemm<M_GIN2, bf16r, bf16r><<<NB_GEMM, 256, 0, stream>>>(G2p, G2a, BPgin);
        }
    } else {
        // fallback: masked 4-copy PROJ + atomic scatter (R9 structure)
        SideP Pp = {};
        Pp.in = x_paper; Pp.out = h_p; Pp.wt = wt_lin_p; Pp.bias = lin_p_b;
        Pp.mask = drop_p; Pp.M = NPP; Pp.Nn = NPP; Pp.tiles = (NPP + 63) / 64;
        SideP Pa = {};
        Pa.in = x_author; Pa.out = h_a; Pa.wt = wt_lin_a; Pa.bias = lin_a_b;
        Pa.mask = drop_a; Pa.M = NAU; Pa.Nn = NAU; Pa.tiles = (NAU + 63) / 64;
        int BPproj = (int)((long)NB_GEMM * Pp.tiles / (Pp.tiles + Pa.tiles));
        mfma_gemm<M_PROJ, float, float><<<NB_GEMM, 256, 0, stream>>>(Pp, Pa, BPproj);

        for (int l = 0; l < 2; ++l) {
            int t0 = l * 2 + 0, t1 = l * 2 + 1;
            zero_k<<<2048, 256, 0, stream>>>((float*)agg_a_v, ((size_t)(NAU + NPP) * HD) / 4);
            scatter_k<<<(NEDGE * 32) / 256, 256, 0, stream>>>(h_a, (float*)agg_p_v, ei_ap, NEDGE);
            scatter_k<<<(NEDGE * 32) / 256, 256, 0, stream>>>(h_p, (float*)agg_a_v, ei_pa, NEDGE);

            SideP G1p = {}, G1a = {};
            G1p.in = h_p; G1p.out = h_p; G1p.wt = wt_W1 + (size_t)t0 * HD * HD;
            G1p.bias = B1 + (size_t)t0 * HD; G1p.agg = agg_p_v; G1p.epsp = EPS + t0;
            G1p.gsum = gsumP; G1p.gsumsq = gsumsqP;
            G1p.M = NRUNS * NPP; G1p.Nn = NPP; G1p.tiles = TP;
            G1a.in = h_a; G1a.out = h_a; G1a.wt = wt_W1 + (size_t)t1 * HD * HD;
            G1a.bias = B1 + (size_t)t1 * HD; G1a.agg = agg_a_v; G1a.epsp = EPS + t1;
            G1a.gsum = gsumA; G1a.gsumsq = gsumsqA;
            G1a.M = NRUNS * NAU; G1a.Nn = NAU; G1a.tiles = TA;
            mfma_gemm<M_GIN1, bf16r, float><<<NB_GEMM, 256, 0, stream>>>(G1p, G1a, BPgin);

            finalize2_k<<<1, 256, 0, stream>>>(
                gsumP, gsumsqP, G + (size_t)t0 * HD, BT + (size_t)t0 * HD, scP, shP,
                1.0f / (NRUNS * NPP),
                gsumA, gsumsqA, G + (size_t)t1 * HD, BT + (size_t)t1 * HD, scA, shA,
                1.0f / (NRUNS * NAU));

            SideP G2p = {}, G2a = {};
            G2p.in = h_p; G2p.out = h_p; G2p.wt = wt_W2 + (size_t)t0 * HD * HD;
            G2p.bias = B2 + (size_t)t0 * HD; G2p.scale = scP; G2p.shift = shP;
            G2p.M = NRUNS * NPP; G2p.Nn = NPP; G2p.tiles = TP;
            G2a.in = h_a; G2a.out = h_a; G2a.wt = wt_W2 + (size_t)t1 * HD * HD;
            G2a.bias = B2 + (size_t)t1 * HD; G2a.scale = scA; G2a.shift = shA;
            G2a.M = NRUNS * NAU; G2a.Nn = NAU; G2a.tiles = TA;
            mfma_gemm<M_GIN2, bf16r, bf16r><<<NB_GEMM, 256, 0, stream>>>(G2p, G2a, BPgin);
        }
    }

    final_k<<<(NAU * 64) / 256, 256, 0, stream>>>(h_a, fw, fb, (float*)d_out);
}

extern "C" void kernel_launch(void* const* d_in, const int* in_sizes, int n_in,
                              void* d_out, int out_size, void* d_ws, size_t ws_size,
                              hipStream_t stream)
{
    const size_t hB    = (size_t)NRUNS * (NAU + NPP) * HD * sizeof(bf16r);
    const size_t statB = 8 * HD * sizeof(float);
    const size_t wtB   = WT_ELEMS * sizeof(bf16r);
    const size_t csrB  = CSR_INTS * sizeof(int);
    const size_t aggBF = (size_t)(NAU + NPP) * HD * sizeof(bf16r);
    const size_t projB = (size_t)(NAU + NPP) * HD * sizeof(bf16r);

    const size_t need_gather = statB + wtB + csrB + aggBF + projB + hB;  // ~235.3 MB
    if (ws_size >= need_gather) {
        run_all<true>(d_in, d_out, d_ws, stream);
    } else {
        run_all<false>(d_in, d_out, d_ws, stream);   // atomic fallback (~230.8 MB w/ f32 agg)
    }
}